// Round 2
// baseline (986.762 us; speedup 1.0000x reference)
//
#include <hip/hip_runtime.h>
#include <stdint.h>

#define N_PRO 60000
#define N_WAT 40000
#define NN    100000
#define NE    1000000
#define IN_DIM 21
#define HID    32
#define HEADS  4
#define HC     128
#define EDGE_K 32

// ---------------------------------------------------------------------------
// K1: tiny fused weights. V_l[d][h] = sum_c Wedge_l[d, h*32+c] * atte_l[h,c]
// U_l[32,4] = We @ V_l ; aeb_l[4] = be . V_l ; h0w[32] = Wf[20,:] + bf
// smallw floats: [0..127]=U1, [128..131]=aeb1, [132..259]=U2, [260..263]=aeb2,
// [264..295]=h0w
// ---------------------------------------------------------------------------
__global__ __launch_bounds__(256) void k_small(
    const float* We, const float* be,
    const float* Wedge1, const float* atte1,
    const float* Wedge2, const float* atte2,
    const float* Wf, const float* bfv, float* smallw)
{
    __shared__ float V[2][128];
    int t = threadIdx.x;
    {
        int l = t >> 7, dh = t & 127, d = dh >> 2, h = dh & 3;
        const float* Wg = l ? Wedge2 : Wedge1;
        const float* ae = l ? atte2 : atte1;
        float s = 0.f;
        for (int c = 0; c < HID; c++)
            s += Wg[d * HC + h * HID + c] * ae[h * HID + c];
        V[l][dh] = s;
    }
    __syncthreads();
    {
        int l = t >> 7, kh = t & 127, k = kh >> 2, h = kh & 3;
        float s = 0.f;
        for (int d = 0; d < 32; d++)
            s += We[k * 32 + d] * V[l][d * 4 + h];
        smallw[(l ? 132 : 0) + kh] = s;
    }
    if (t < 8) {
        int l = t >> 2, h = t & 3;
        float s = 0.f;
        for (int d = 0; d < 32; d++)
            s += be[d] * V[l][d * 4 + h];
        smallw[(l ? 260 : 128) + h] = s;
    }
    if (t >= 32 && t < 64) {
        int c = t - 32;
        smallw[264 + c] = Wf[20 * 32 + c] + bfv[c];
    }
}

// ---------------------------------------------------------------------------
// K2: h0 = feats @ Wf + bf  (water rows are the precomputed constant row)
// ---------------------------------------------------------------------------
__global__ __launch_bounds__(256) void k_h0(
    const float* __restrict__ pf, const float* __restrict__ Wf,
    const float* __restrict__ bfv, const float* __restrict__ smallw,
    float* __restrict__ h0)
{
    __shared__ float Wfs[IN_DIM * 32];
    __shared__ float bfs[32];
    __shared__ float h0w[32];
    int t = threadIdx.x;
    for (int i = t; i < IN_DIM * 32; i += 256) Wfs[i] = Wf[i];
    if (t < 32) { bfs[t] = bfv[t]; h0w[t] = smallw[264 + t]; }
    __syncthreads();
    int id = blockIdx.x * 256 + t;
    int n = id >> 5, c = id & 31;
    if (n >= NN) return;
    float v;
    if (n < N_PRO) {
        float s = bfs[c];
        for (int k = 0; k < IN_DIM; k++)
            s += pf[n * IN_DIM + k] * Wfs[k * 32 + c];
        v = s;
    } else {
        v = h0w[c];
    }
    h0[n * 32 + c] = v;
}

// ---------------------------------------------------------------------------
// CSR build over dst
// ---------------------------------------------------------------------------
__global__ __launch_bounds__(256) void k_count(const int* ei, int* deg) {
    int e = blockIdx.x * 256 + threadIdx.x;
    if (e >= NE) return;
    int d = ei[NE + e];
    if ((unsigned)d < (unsigned)NN) atomicAdd(&deg[d], 1);
}

__global__ __launch_bounds__(1024) void k_scan(const int* deg, int* off, int* cur) {
    __shared__ int s[1024];
    int t = threadIdx.x;
    const int chunk = (NN + 1023) / 1024;
    int lo = t * chunk, hi = lo + chunk; if (hi > NN) hi = NN; if (lo > NN) lo = NN;
    int sum = 0;
    for (int i = lo; i < hi; i++) sum += deg[i];
    s[t] = sum;
    __syncthreads();
    for (int o = 1; o < 1024; o <<= 1) {
        int v = (t >= o) ? s[t - o] : 0;
        __syncthreads();
        s[t] += v;
        __syncthreads();
    }
    int run = s[t] - sum;
    for (int i = lo; i < hi; i++) { off[i] = run; cur[i] = run; run += deg[i]; }
    if (t == 1023) off[NN] = s[1023];
}

__global__ __launch_bounds__(256) void k_fill(const int* ei, int* cur, int* eid, int* esrc) {
    int e = blockIdx.x * 256 + threadIdx.x;
    if (e >= NE) return;
    int d = ei[NE + e];
    int srcn = ei[e];
    if ((unsigned)d >= (unsigned)NN || (unsigned)srcn >= (unsigned)NN) return;
    int p = atomicAdd(&cur[d], 1);
    eid[p] = e;
    esrc[p] = srcn;
}

// ---------------------------------------------------------------------------
// K6: x = h @ W (+ attention logits a_s, a_d). COLS output columns per block
// (blockIdx.y selects the column slab). 8 nodes / 256-thread block per tile.
// ---------------------------------------------------------------------------
template <int DIN, int COLS>
__global__ __launch_bounds__(256) void k_x(
    const float* __restrict__ h, const float* __restrict__ Wg,
    const float* __restrict__ atts, const float* __restrict__ attd,
    float* __restrict__ x, float* __restrict__ asd)
{
    __shared__ float Ws[DIN * COLS];
    __shared__ float attS[COLS], attD[COLS];
    __shared__ float hs[8 * DIN];
    int t = threadIdx.x;
    int cbase = blockIdx.y * COLS;
    for (int i = t; i < DIN * COLS; i += 256)
        Ws[i] = Wg[(i / COLS) * 128 + cbase + (i % COLS)];
    if (t < COLS) { attS[t] = atts[cbase + t]; attD[t] = attd[cbase + t]; }
    constexpr int CPT = COLS / 32;      // cols per thread (4 or 2)
    constexpr int TPH = 32 / CPT;       // threads per head  (8 or 16)
    int nsub = t >> 5, q = t & 31, c0 = q * CPT;
    const int NT = NN / 8;
    for (int tile = blockIdx.x; tile < NT; tile += gridDim.x) {
        __syncthreads();
        for (int i = t; i < 8 * DIN; i += 256)
            hs[i] = h[(tile * 8 + i / DIN) * DIN + (i % DIN)];
        __syncthreads();
        float acc[CPT];
        #pragma unroll
        for (int j = 0; j < CPT; j++) acc[j] = 0.f;
        const float* hrow = &hs[nsub * DIN];
        #pragma unroll 8
        for (int d = 0; d < DIN; d++) {
            float hv = hrow[d];
            #pragma unroll
            for (int j = 0; j < CPT; j++)
                acc[j] += hv * Ws[d * COLS + c0 + j];
        }
        int n = tile * 8 + nsub;
        if (CPT == 4) {
            *(float4*)&x[n * 128 + cbase + c0] =
                make_float4(acc[0], acc[1], acc[2], acc[3]);
        } else {
            *(float2*)&x[n * 128 + cbase + c0] = make_float2(acc[0], acc[1]);
        }
        float ps = 0.f, pd = 0.f;
        #pragma unroll
        for (int j = 0; j < CPT; j++) {
            ps += acc[j] * attS[c0 + j];
            pd += acc[j] * attD[c0 + j];
        }
        #pragma unroll
        for (int mk = 1; mk < TPH; mk <<= 1) {
            ps += __shfl_xor(ps, mk, 64);
            pd += __shfl_xor(pd, mk, 64);
        }
        if ((q % TPH) == 0) {
            int hh = cbase / 32 + q / TPH;
            asd[n * 8 + hh] = ps;
            asd[n * 8 + 4 + hh] = pd;
        }
    }
}

// ---------------------------------------------------------------------------
// K7: per-edge attention logits alpha[E,4] = leaky(a_s[src]+a_d[dst]+RBF@U+aeb)
// ---------------------------------------------------------------------------
__global__ __launch_bounds__(256) void k_alpha(
    const int* __restrict__ ei, const float* __restrict__ ppos,
    const float* __restrict__ wpos, const float* __restrict__ gamma,
    const float* __restrict__ U, const float* __restrict__ aeb,
    const float* __restrict__ asd, float* __restrict__ alpha)
{
    __shared__ float Us[128];
    __shared__ float aebs[4];
    int t = threadIdx.x;
    if (t < 128) Us[t] = U[t];
    if (t < 4) aebs[t] = aeb[t];
    __syncthreads();
    int e = blockIdx.x * 256 + t;
    if (e >= NE) return;
    int sn = ei[e], dn = ei[NE + e];
    if ((unsigned)sn >= (unsigned)NN || (unsigned)dn >= (unsigned)NN) return;
    const float* ps = (sn < N_PRO) ? &ppos[sn * 3] : &wpos[(sn - N_PRO) * 3];
    const float* pd = (dn < N_PRO) ? &ppos[dn * 3] : &wpos[(dn - N_PRO) * 3];
    float dx = pd[0] - ps[0];
    float dy = pd[1] - ps[1];
    float dz = pd[2] - ps[2];
    float dist = sqrtf(dx * dx + dy * dy + dz * dz);
    float g = gamma[0];
    float ae0 = aebs[0], ae1 = aebs[1], ae2 = aebs[2], ae3 = aebs[3];
    const float step = 5.0f / 31.0f;
    #pragma unroll
    for (int k = 0; k < EDGE_K; k++) {
        float tt = dist - (float)k * step;
        float r = __expf(-g * tt * tt);
        ae0 += r * Us[k * 4 + 0];
        ae1 += r * Us[k * 4 + 1];
        ae2 += r * Us[k * 4 + 2];
        ae3 += r * Us[k * 4 + 3];
    }
    float4 as4 = *(const float4*)&asd[sn * 8];
    float4 ad4 = *(const float4*)&asd[dn * 8 + 4];
    float v0 = as4.x + ad4.x + ae0;
    float v1 = as4.y + ad4.y + ae1;
    float v2 = as4.z + ad4.z + ae2;
    float v3 = as4.w + ad4.w + ae3;
    v0 = v0 >= 0.f ? v0 : 0.2f * v0;
    v1 = v1 >= 0.f ? v1 : 0.2f * v1;
    v2 = v2 >= 0.f ? v2 : 0.2f * v2;
    v3 = v3 >= 0.f ? v3 : 0.2f * v3;
    *(float4*)&alpha[e * 4] = make_float4(v0, v1, v2, v3);
}

// ---------------------------------------------------------------------------
// K8: per-dst-node online-softmax aggregation. One wave per node; lane l owns
// channels 2l,2l+1 (head = l/16). Single pass, no float atomics.
// out = elu(acc/(l+1e-16) + b)
// ---------------------------------------------------------------------------
__global__ __launch_bounds__(256) void k_agg(
    const int* __restrict__ off, const int* __restrict__ eid,
    const int* __restrict__ esrc, const float* __restrict__ alpha,
    const float* __restrict__ x, const float* __restrict__ bias,
    float* __restrict__ hout)
{
    int t = threadIdx.x;
    int w = t >> 6, lane = t & 63;
    int n = blockIdx.x * 4 + w;
    if (n >= NN) return;
    int h = lane >> 4;
    int beg = off[n], end = off[n + 1];
    float m = -INFINITY, lsum = 0.f, acc0 = 0.f, acc1 = 0.f;
    const float2* x2 = (const float2*)x;
    for (int i = beg; i < end; i++) {
        int e = eid[i];
        int s = esrc[i];
        float a = alpha[e * 4 + h];
        float mn = fmaxf(m, a);
        float sc = __expf(m - mn);
        float we = __expf(a - mn);
        float2 xv = x2[s * 64 + lane];
        lsum = lsum * sc + we;
        acc0 = acc0 * sc + we * xv.x;
        acc1 = acc1 * sc + we * xv.y;
        m = mn;
    }
    float inv = 1.0f / (lsum + 1e-16f);
    float2 bb = *(const float2*)&bias[lane * 2];
    float o0 = acc0 * inv + bb.x;
    float o1 = acc1 * inv + bb.y;
    o0 = o0 > 0.f ? o0 : __expf(o0) - 1.0f;
    o1 = o1 > 0.f ? o1 : __expf(o1) - 1.0f;
    ((float2*)&hout[n * 128])[lane] = make_float2(o0, o1);
}

// ---------------------------------------------------------------------------
// K9: water MLP: out = relu(h@Wm1+bm1)@Wm2 + bm2. Wm1 staged in LDS in two
// 64-column halves per tile (32 KB buffer keeps block under the 64 KB cap).
// ---------------------------------------------------------------------------
__global__ __launch_bounds__(256) void k_mlp(
    const float* __restrict__ hh, const float* __restrict__ Wm1,
    const float* __restrict__ bm1, const float* __restrict__ Wm2,
    const float* __restrict__ bm2, float* __restrict__ out)
{
    __shared__ float W1s[128 * 64];
    __shared__ float hs[8 * 128];
    int t = threadIdx.x;
    int nsub = t >> 5, q = t & 31;
    float b1r[2][2], w2r[2][2][2];
    #pragma unroll
    for (int hf = 0; hf < 2; hf++)
        #pragma unroll
        for (int j = 0; j < 2; j++) {
            int c = hf * 64 + q * 2 + j;
            b1r[hf][j] = bm1[c];
            w2r[hf][j][0] = Wm2[c * 2 + 0];
            w2r[hf][j][1] = Wm2[c * 2 + 1];
        }
    float b20 = bm2[0], b21 = bm2[1];
    const int NT = N_WAT / 8;
    for (int tile = blockIdx.x; tile < NT; tile += gridDim.x) {
        __syncthreads();
        for (int i = t; i < 8 * 128; i += 256)
            hs[i] = hh[(N_PRO + tile * 8 + (i >> 7)) * 128 + (i & 127)];
        float p0 = 0.f, p1 = 0.f;
        const float* hrow = &hs[nsub * 128];
        #pragma unroll
        for (int hf = 0; hf < 2; hf++) {
            __syncthreads();
            for (int i = t; i < 128 * 64; i += 256)
                W1s[i] = Wm1[(i >> 6) * 128 + hf * 64 + (i & 63)];
            __syncthreads();
            float a0 = 0.f, a1 = 0.f;
            #pragma unroll 8
            for (int d = 0; d < 128; d++) {
                float hv = hrow[d];
                float2 w = *(const float2*)&W1s[d * 64 + q * 2];
                a0 += hv * w.x;
                a1 += hv * w.y;
            }
            a0 = fmaxf(a0 + b1r[hf][0], 0.f);
            a1 = fmaxf(a1 + b1r[hf][1], 0.f);
            p0 += a0 * w2r[hf][0][0] + a1 * w2r[hf][1][0];
            p1 += a0 * w2r[hf][0][1] + a1 * w2r[hf][1][1];
        }
        #pragma unroll
        for (int mk = 1; mk < 32; mk <<= 1) {
            p0 += __shfl_xor(p0, mk, 64);
            p1 += __shfl_xor(p1, mk, 64);
        }
        if (q == 0) {
            int r = tile * 8 + nsub;
            out[r * 2 + 0] = p0 + b20;
            out[r * 2 + 1] = p1 + b21;
        }
    }
}

// ---------------------------------------------------------------------------
extern "C" void kernel_launch(void* const* d_in, const int* in_sizes, int n_in,
                              void* d_out, int out_size, void* d_ws, size_t ws_size,
                              hipStream_t stream)
{
    const float* ppos   = (const float*)d_in[0];
    const float* wpos   = (const float*)d_in[1];
    const float* pfeat  = (const float*)d_in[2];
    const int*   ei     = (const int*)d_in[3];
    const float* gamma  = (const float*)d_in[4];
    const float* Wf     = (const float*)d_in[5];
    const float* bfv    = (const float*)d_in[6];
    const float* We     = (const float*)d_in[7];
    const float* be     = (const float*)d_in[8];
    const float* W1     = (const float*)d_in[9];
    const float* atts1  = (const float*)d_in[10];
    const float* attd1  = (const float*)d_in[11];
    const float* Wedge1 = (const float*)d_in[12];
    const float* atte1  = (const float*)d_in[13];
    const float* b1     = (const float*)d_in[14];
    const float* W2     = (const float*)d_in[15];
    const float* atts2  = (const float*)d_in[16];
    const float* attd2  = (const float*)d_in[17];
    const float* Wedge2 = (const float*)d_in[18];
    const float* atte2  = (const float*)d_in[19];
    const float* b2     = (const float*)d_in[20];
    const float* Wm1    = (const float*)d_in[21];
    const float* bm1    = (const float*)d_in[22];
    const float* Wm2    = (const float*)d_in[23];
    const float* bm2    = (const float*)d_in[24];
    float* out = (float*)d_out;

    char* ws = (char*)d_ws;
    size_t o = 0;
    auto alloc = [&](size_t bytes) -> char* {
        char* p = ws + o;
        o += (bytes + 255) & ~(size_t)255;
        return p;
    };
    float* h0     = (float*)alloc((size_t)NN * 32 * 4);
    float* x      = (float*)alloc((size_t)NN * 128 * 4);
    float* hbuf   = (float*)alloc((size_t)NN * 128 * 4);
    float* asd    = (float*)alloc((size_t)NN * 8 * 4);
    float* alpha  = (float*)alloc((size_t)NE * 4 * 4);
    int*   deg    = (int*)alloc((size_t)(NN + 1) * 4);
    int*   offp   = (int*)alloc((size_t)(NN + 1) * 4);
    int*   cur    = (int*)alloc((size_t)NN * 4);
    int*   eid    = (int*)alloc((size_t)NE * 4);
    int*   esrc   = (int*)alloc((size_t)NE * 4);
    float* smallw = (float*)alloc(4096);

    hipMemsetAsync(deg, 0, (NN + 1) * 4, stream);
    k_small<<<1, 256, 0, stream>>>(We, be, Wedge1, atte1, Wedge2, atte2, Wf, bfv, smallw);
    k_h0<<<(NN * 32) / 256, 256, 0, stream>>>(pfeat, Wf, bfv, smallw, h0);
    k_count<<<(NE + 255) / 256, 256, 0, stream>>>(ei, deg);
    k_scan<<<1, 1024, 0, stream>>>(deg, offp, cur);
    k_fill<<<(NE + 255) / 256, 256, 0, stream>>>(ei, cur, eid, esrc);
    // layer 1
    k_x<32, 128><<<dim3(2048, 1), 256, 0, stream>>>(h0, W1, atts1, attd1, x, asd);
    k_alpha<<<(NE + 255) / 256, 256, 0, stream>>>(ei, ppos, wpos, gamma, smallw + 0, smallw + 128, asd, alpha);
    k_agg<<<NN / 4, 256, 0, stream>>>(offp, eid, esrc, alpha, x, b1, hbuf);
    // layer 2
    k_x<128, 64><<<dim3(2048, 2), 256, 0, stream>>>(hbuf, W2, atts2, attd2, x, asd);
    k_alpha<<<(NE + 255) / 256, 256, 0, stream>>>(ei, ppos, wpos, gamma, smallw + 132, smallw + 260, asd, alpha);
    k_agg<<<NN / 4, 256, 0, stream>>>(offp, eid, esrc, alpha, x, b2, hbuf);
    // MLP on water nodes
    k_mlp<<<2048, 256, 0, stream>>>(hbuf, Wm1, bm1, Wm2, bm2, out);
}

// Round 3
// 781.811 us; speedup vs baseline: 1.2621x; 1.2621x over previous
//
#include <hip/hip_runtime.h>
#include <stdint.h>

#define N_PRO 60000
#define N_WAT 40000
#define NN    100000
#define NE    1000000
#define IN_DIM 21
#define HID    32
#define HEADS  4
#define HC     128
#define EDGE_K 32
#define NSEG   ((NN + 1023) / 1024)   // 98 segments for the hierarchical scan

// ---------------------------------------------------------------------------
// K1: tiny fused weights. V_l[d][h] = sum_c Wedge_l[d, h*32+c] * atte_l[h,c]
// U_l[32,4] = We @ V_l ; aeb_l[4] = be . V_l ; h0w[32] = Wf[20,:] + bf
// smallw floats: [0..127]=U1, [128..131]=aeb1, [132..259]=U2, [260..263]=aeb2,
// [264..295]=h0w
// ---------------------------------------------------------------------------
__global__ __launch_bounds__(256) void k_small(
    const float* We, const float* be,
    const float* Wedge1, const float* atte1,
    const float* Wedge2, const float* atte2,
    const float* Wf, const float* bfv, float* smallw)
{
    __shared__ float V[2][128];
    int t = threadIdx.x;
    {
        int l = t >> 7, dh = t & 127, d = dh >> 2, h = dh & 3;
        const float* Wg = l ? Wedge2 : Wedge1;
        const float* ae = l ? atte2 : atte1;
        float s = 0.f;
        for (int c = 0; c < HID; c++)
            s += Wg[d * HC + h * HID + c] * ae[h * HID + c];
        V[l][dh] = s;
    }
    __syncthreads();
    {
        int l = t >> 7, kh = t & 127, k = kh >> 2, h = kh & 3;
        float s = 0.f;
        for (int d = 0; d < 32; d++)
            s += We[k * 32 + d] * V[l][d * 4 + h];
        smallw[(l ? 132 : 0) + kh] = s;
    }
    if (t < 8) {
        int l = t >> 2, h = t & 3;
        float s = 0.f;
        for (int d = 0; d < 32; d++)
            s += be[d] * V[l][d * 4 + h];
        smallw[(l ? 260 : 128) + h] = s;
    }
    if (t >= 32 && t < 64) {
        int c = t - 32;
        smallw[264 + c] = Wf[20 * 32 + c] + bfv[c];
    }
}

// ---------------------------------------------------------------------------
// K2: h0 = feats @ Wf + bf  (water rows are the precomputed constant row)
// ---------------------------------------------------------------------------
__global__ __launch_bounds__(256) void k_h0(
    const float* __restrict__ pf, const float* __restrict__ Wf,
    const float* __restrict__ bfv, const float* __restrict__ smallw,
    float* __restrict__ h0)
{
    __shared__ float Wfs[IN_DIM * 32];
    __shared__ float bfs[32];
    __shared__ float h0w[32];
    int t = threadIdx.x;
    for (int i = t; i < IN_DIM * 32; i += 256) Wfs[i] = Wf[i];
    if (t < 32) { bfs[t] = bfv[t]; h0w[t] = smallw[264 + t]; }
    __syncthreads();
    int id = blockIdx.x * 256 + t;
    int n = id >> 5, c = id & 31;
    if (n >= NN) return;
    float v;
    if (n < N_PRO) {
        float s = bfs[c];
        for (int k = 0; k < IN_DIM; k++)
            s += pf[n * IN_DIM + k] * Wfs[k * 32 + c];
        v = s;
    } else {
        v = h0w[c];
    }
    h0[n * 32 + c] = v;
}

// ---------------------------------------------------------------------------
// CSR build over dst: count -> hierarchical scan (3 passes) -> fill
// ---------------------------------------------------------------------------
__global__ __launch_bounds__(256) void k_count(const int* ei, int* deg) {
    int e = blockIdx.x * 256 + threadIdx.x;
    if (e >= NE) return;
    int d = ei[NE + e];
    if ((unsigned)d < (unsigned)NN) atomicAdd(&deg[d], 1);
}

// pass 1: per-1024-segment local exclusive scan; segment total -> part[b]
__global__ __launch_bounds__(256) void k_scan1(
    const int* __restrict__ deg, int* __restrict__ off,
    int* __restrict__ cur, int* __restrict__ part)
{
    __shared__ int s[256];
    int t = threadIdx.x;
    int base = blockIdx.x * 1024 + t * 4;
    int d0 = 0, d1 = 0, d2 = 0, d3 = 0;
    if (base + 3 < NN) {
        int4 v = *(const int4*)&deg[base];
        d0 = v.x; d1 = v.y; d2 = v.z; d3 = v.w;
    } else {
        if (base + 0 < NN) d0 = deg[base + 0];
        if (base + 1 < NN) d1 = deg[base + 1];
        if (base + 2 < NN) d2 = deg[base + 2];
    }
    int tsum = d0 + d1 + d2 + d3;
    s[t] = tsum;
    __syncthreads();
    #pragma unroll
    for (int o = 1; o < 256; o <<= 1) {
        int v = (t >= o) ? s[t - o] : 0;
        __syncthreads();
        s[t] += v;
        __syncthreads();
    }
    int ex = s[t] - tsum;
    if (base + 0 < NN) { int v = ex;                 off[base + 0] = v; cur[base + 0] = v; }
    if (base + 1 < NN) { int v = ex + d0;            off[base + 1] = v; cur[base + 1] = v; }
    if (base + 2 < NN) { int v = ex + d0 + d1;       off[base + 2] = v; cur[base + 2] = v; }
    if (base + 3 < NN) { int v = ex + d0 + d1 + d2;  off[base + 3] = v; cur[base + 3] = v; }
    if (t == 255) part[blockIdx.x] = s[255];
}

// pass 2: scan the 98 segment totals (single small block); writes off[NN]
__global__ __launch_bounds__(128) void k_scan2(
    const int* __restrict__ part, int* __restrict__ partoff, int* __restrict__ off)
{
    __shared__ int s[128];
    int t = threadIdx.x;
    int v = (t < NSEG) ? part[t] : 0;
    s[t] = v;
    __syncthreads();
    #pragma unroll
    for (int o = 1; o < 128; o <<= 1) {
        int x = (t >= o) ? s[t - o] : 0;
        __syncthreads();
        s[t] += x;
        __syncthreads();
    }
    partoff[t] = s[t] - v;   // exclusive prefix
    if (t == 127) off[NN] = s[127];
}

// pass 3: add segment base to each element of off/cur
__global__ __launch_bounds__(256) void k_scan3(
    const int* __restrict__ partoff, int* __restrict__ off, int* __restrict__ cur)
{
    int b = blockIdx.x;
    int add = partoff[b];
    if (add == 0) return;   // first segment(s) unchanged
    int base = b * 1024 + threadIdx.x * 4;
    #pragma unroll
    for (int j = 0; j < 4; j++) {
        int i = base + j;
        if (i < NN) { off[i] += add; cur[i] += add; }
    }
}

__global__ __launch_bounds__(256) void k_fill(const int* ei, int* cur, int* eid, int* esrc) {
    int e = blockIdx.x * 256 + threadIdx.x;
    if (e >= NE) return;
    int d = ei[NE + e];
    int srcn = ei[e];
    if ((unsigned)d >= (unsigned)NN || (unsigned)srcn >= (unsigned)NN) return;
    int p = atomicAdd(&cur[d], 1);
    eid[p] = e;
    esrc[p] = srcn;
}

// ---------------------------------------------------------------------------
// K6: x = h @ W (+ attention logits a_s, a_d). COLS output columns per block
// (blockIdx.y selects the column slab). 8 nodes / 256-thread block per tile.
// ---------------------------------------------------------------------------
template <int DIN, int COLS>
__global__ __launch_bounds__(256) void k_x(
    const float* __restrict__ h, const float* __restrict__ Wg,
    const float* __restrict__ atts, const float* __restrict__ attd,
    float* __restrict__ x, float* __restrict__ asd)
{
    __shared__ float Ws[DIN * COLS];
    __shared__ float attS[COLS], attD[COLS];
    __shared__ float hs[8 * DIN];
    int t = threadIdx.x;
    int cbase = blockIdx.y * COLS;
    for (int i = t; i < DIN * COLS; i += 256)
        Ws[i] = Wg[(i / COLS) * 128 + cbase + (i % COLS)];
    if (t < COLS) { attS[t] = atts[cbase + t]; attD[t] = attd[cbase + t]; }
    constexpr int CPT = COLS / 32;      // cols per thread (4 or 2)
    constexpr int TPH = 32 / CPT;       // threads per head  (8 or 16)
    int nsub = t >> 5, q = t & 31, c0 = q * CPT;
    const int NT = NN / 8;
    for (int tile = blockIdx.x; tile < NT; tile += gridDim.x) {
        __syncthreads();
        for (int i = t; i < 8 * DIN; i += 256)
            hs[i] = h[(tile * 8 + i / DIN) * DIN + (i % DIN)];
        __syncthreads();
        float acc[CPT];
        #pragma unroll
        for (int j = 0; j < CPT; j++) acc[j] = 0.f;
        const float* hrow = &hs[nsub * DIN];
        #pragma unroll 8
        for (int d = 0; d < DIN; d++) {
            float hv = hrow[d];
            #pragma unroll
            for (int j = 0; j < CPT; j++)
                acc[j] += hv * Ws[d * COLS + c0 + j];
        }
        int n = tile * 8 + nsub;
        if (CPT == 4) {
            *(float4*)&x[n * 128 + cbase + c0] =
                make_float4(acc[0], acc[1], acc[2], acc[3]);
        } else {
            *(float2*)&x[n * 128 + cbase + c0] = make_float2(acc[0], acc[1]);
        }
        float ps = 0.f, pd = 0.f;
        #pragma unroll
        for (int j = 0; j < CPT; j++) {
            ps += acc[j] * attS[c0 + j];
            pd += acc[j] * attD[c0 + j];
        }
        #pragma unroll
        for (int mk = 1; mk < TPH; mk <<= 1) {
            ps += __shfl_xor(ps, mk, 64);
            pd += __shfl_xor(pd, mk, 64);
        }
        if ((q % TPH) == 0) {
            int hh = cbase / 32 + q / TPH;
            asd[n * 8 + hh] = ps;
            asd[n * 8 + 4 + hh] = pd;
        }
    }
}

// ---------------------------------------------------------------------------
// K7: per-edge attention logits alpha[E,4] = leaky(a_s[src]+a_d[dst]+RBF@U+aeb)
// ---------------------------------------------------------------------------
__global__ __launch_bounds__(256) void k_alpha(
    const int* __restrict__ ei, const float* __restrict__ ppos,
    const float* __restrict__ wpos, const float* __restrict__ gamma,
    const float* __restrict__ U, const float* __restrict__ aeb,
    const float* __restrict__ asd, float* __restrict__ alpha)
{
    __shared__ float Us[128];
    __shared__ float aebs[4];
    int t = threadIdx.x;
    if (t < 128) Us[t] = U[t];
    if (t < 4) aebs[t] = aeb[t];
    __syncthreads();
    int e = blockIdx.x * 256 + t;
    if (e >= NE) return;
    int sn = ei[e], dn = ei[NE + e];
    if ((unsigned)sn >= (unsigned)NN || (unsigned)dn >= (unsigned)NN) return;
    const float* ps = (sn < N_PRO) ? &ppos[sn * 3] : &wpos[(sn - N_PRO) * 3];
    const float* pd = (dn < N_PRO) ? &ppos[dn * 3] : &wpos[(dn - N_PRO) * 3];
    float dx = pd[0] - ps[0];
    float dy = pd[1] - ps[1];
    float dz = pd[2] - ps[2];
    float dist = sqrtf(dx * dx + dy * dy + dz * dz);
    float g = gamma[0];
    float ae0 = aebs[0], ae1 = aebs[1], ae2 = aebs[2], ae3 = aebs[3];
    const float step = 5.0f / 31.0f;
    #pragma unroll
    for (int k = 0; k < EDGE_K; k++) {
        float tt = dist - (float)k * step;
        float r = __expf(-g * tt * tt);
        ae0 += r * Us[k * 4 + 0];
        ae1 += r * Us[k * 4 + 1];
        ae2 += r * Us[k * 4 + 2];
        ae3 += r * Us[k * 4 + 3];
    }
    float4 as4 = *(const float4*)&asd[sn * 8];
    float4 ad4 = *(const float4*)&asd[dn * 8 + 4];
    float v0 = as4.x + ad4.x + ae0;
    float v1 = as4.y + ad4.y + ae1;
    float v2 = as4.z + ad4.z + ae2;
    float v3 = as4.w + ad4.w + ae3;
    v0 = v0 >= 0.f ? v0 : 0.2f * v0;
    v1 = v1 >= 0.f ? v1 : 0.2f * v1;
    v2 = v2 >= 0.f ? v2 : 0.2f * v2;
    v3 = v3 >= 0.f ? v3 : 0.2f * v3;
    *(float4*)&alpha[e * 4] = make_float4(v0, v1, v2, v3);
}

// ---------------------------------------------------------------------------
// K8: per-dst-node online-softmax aggregation. One wave per node; lane l owns
// channels 2l,2l+1 (head = l/16). Single pass, no float atomics.
// out = elu(acc/(l+1e-16) + b)
// ---------------------------------------------------------------------------
__global__ __launch_bounds__(256) void k_agg(
    const int* __restrict__ off, const int* __restrict__ eid,
    const int* __restrict__ esrc, const float* __restrict__ alpha,
    const float* __restrict__ x, const float* __restrict__ bias,
    float* __restrict__ hout)
{
    int t = threadIdx.x;
    int w = t >> 6, lane = t & 63;
    int n = blockIdx.x * 4 + w;
    if (n >= NN) return;
    int h = lane >> 4;
    int beg = off[n], end = off[n + 1];
    float m = -INFINITY, lsum = 0.f, acc0 = 0.f, acc1 = 0.f;
    const float2* x2 = (const float2*)x;
    for (int i = beg; i < end; i++) {
        int e = eid[i];
        int s = esrc[i];
        float a = alpha[e * 4 + h];
        float mn = fmaxf(m, a);
        float sc = __expf(m - mn);
        float we = __expf(a - mn);
        float2 xv = x2[s * 64 + lane];
        lsum = lsum * sc + we;
        acc0 = acc0 * sc + we * xv.x;
        acc1 = acc1 * sc + we * xv.y;
        m = mn;
    }
    float inv = 1.0f / (lsum + 1e-16f);
    float2 bb = *(const float2*)&bias[lane * 2];
    float o0 = acc0 * inv + bb.x;
    float o1 = acc1 * inv + bb.y;
    o0 = o0 > 0.f ? o0 : __expf(o0) - 1.0f;
    o1 = o1 > 0.f ? o1 : __expf(o1) - 1.0f;
    ((float2*)&hout[n * 128])[lane] = make_float2(o0, o1);
}

// ---------------------------------------------------------------------------
// K9: water MLP: out = relu(h@Wm1+bm1)@Wm2 + bm2. Wm1 staged in LDS in two
// 64-column halves per tile (32 KB buffer keeps block under the 64 KB cap).
// ---------------------------------------------------------------------------
__global__ __launch_bounds__(256) void k_mlp(
    const float* __restrict__ hh, const float* __restrict__ Wm1,
    const float* __restrict__ bm1, const float* __restrict__ Wm2,
    const float* __restrict__ bm2, float* __restrict__ out)
{
    __shared__ float W1s[128 * 64];
    __shared__ float hs[8 * 128];
    int t = threadIdx.x;
    int nsub = t >> 5, q = t & 31;
    float b1r[2][2], w2r[2][2][2];
    #pragma unroll
    for (int hf = 0; hf < 2; hf++)
        #pragma unroll
        for (int j = 0; j < 2; j++) {
            int c = hf * 64 + q * 2 + j;
            b1r[hf][j] = bm1[c];
            w2r[hf][j][0] = Wm2[c * 2 + 0];
            w2r[hf][j][1] = Wm2[c * 2 + 1];
        }
    float b20 = bm2[0], b21 = bm2[1];
    const int NT = N_WAT / 8;
    for (int tile = blockIdx.x; tile < NT; tile += gridDim.x) {
        __syncthreads();
        for (int i = t; i < 8 * 128; i += 256)
            hs[i] = hh[(N_PRO + tile * 8 + (i >> 7)) * 128 + (i & 127)];
        float p0 = 0.f, p1 = 0.f;
        const float* hrow = &hs[nsub * 128];
        #pragma unroll
        for (int hf = 0; hf < 2; hf++) {
            __syncthreads();
            for (int i = t; i < 128 * 64; i += 256)
                W1s[i] = Wm1[(i >> 6) * 128 + hf * 64 + (i & 63)];
            __syncthreads();
            float a0 = 0.f, a1 = 0.f;
            #pragma unroll 8
            for (int d = 0; d < 128; d++) {
                float hv = hrow[d];
                float2 w = *(const float2*)&W1s[d * 64 + q * 2];
                a0 += hv * w.x;
                a1 += hv * w.y;
            }
            a0 = fmaxf(a0 + b1r[hf][0], 0.f);
            a1 = fmaxf(a1 + b1r[hf][1], 0.f);
            p0 += a0 * w2r[hf][0][0] + a1 * w2r[hf][1][0];
            p1 += a0 * w2r[hf][0][1] + a1 * w2r[hf][1][1];
        }
        #pragma unroll
        for (int mk = 1; mk < 32; mk <<= 1) {
            p0 += __shfl_xor(p0, mk, 64);
            p1 += __shfl_xor(p1, mk, 64);
        }
        if (q == 0) {
            int r = tile * 8 + nsub;
            out[r * 2 + 0] = p0 + b20;
            out[r * 2 + 1] = p1 + b21;
        }
    }
}

// ---------------------------------------------------------------------------
extern "C" void kernel_launch(void* const* d_in, const int* in_sizes, int n_in,
                              void* d_out, int out_size, void* d_ws, size_t ws_size,
                              hipStream_t stream)
{
    const float* ppos   = (const float*)d_in[0];
    const float* wpos   = (const float*)d_in[1];
    const float* pfeat  = (const float*)d_in[2];
    const int*   ei     = (const int*)d_in[3];
    const float* gamma  = (const float*)d_in[4];
    const float* Wf     = (const float*)d_in[5];
    const float* bfv    = (const float*)d_in[6];
    const float* We     = (const float*)d_in[7];
    const float* be     = (const float*)d_in[8];
    const float* W1     = (const float*)d_in[9];
    const float* atts1  = (const float*)d_in[10];
    const float* attd1  = (const float*)d_in[11];
    const float* Wedge1 = (const float*)d_in[12];
    const float* atte1  = (const float*)d_in[13];
    const float* b1     = (const float*)d_in[14];
    const float* W2     = (const float*)d_in[15];
    const float* atts2  = (const float*)d_in[16];
    const float* attd2  = (const float*)d_in[17];
    const float* Wedge2 = (const float*)d_in[18];
    const float* atte2  = (const float*)d_in[19];
    const float* b2     = (const float*)d_in[20];
    const float* Wm1    = (const float*)d_in[21];
    const float* bm1    = (const float*)d_in[22];
    const float* Wm2    = (const float*)d_in[23];
    const float* bm2    = (const float*)d_in[24];
    float* out = (float*)d_out;

    char* ws = (char*)d_ws;
    size_t o = 0;
    auto alloc = [&](size_t bytes) -> char* {
        char* p = ws + o;
        o += (bytes + 255) & ~(size_t)255;
        return p;
    };
    float* h0      = (float*)alloc((size_t)NN * 32 * 4);
    float* x       = (float*)alloc((size_t)NN * 128 * 4);
    float* hbuf    = (float*)alloc((size_t)NN * 128 * 4);
    float* asd     = (float*)alloc((size_t)NN * 8 * 4);
    float* alpha   = (float*)alloc((size_t)NE * 4 * 4);
    int*   deg     = (int*)alloc((size_t)(NN + 1) * 4);
    int*   offp    = (int*)alloc((size_t)(NN + 1) * 4);
    int*   cur     = (int*)alloc((size_t)NN * 4);
    int*   eid     = (int*)alloc((size_t)NE * 4);
    int*   esrc    = (int*)alloc((size_t)NE * 4);
    int*   part    = (int*)alloc((size_t)NSEG * 4);
    int*   partoff = (int*)alloc((size_t)(128 + 1) * 4);
    float* smallw  = (float*)alloc(4096);

    hipMemsetAsync(deg, 0, (NN + 1) * 4, stream);
    k_small<<<1, 256, 0, stream>>>(We, be, Wedge1, atte1, Wedge2, atte2, Wf, bfv, smallw);
    k_h0<<<(NN * 32) / 256, 256, 0, stream>>>(pfeat, Wf, bfv, smallw, h0);
    k_count<<<(NE + 255) / 256, 256, 0, stream>>>(ei, deg);
    k_scan1<<<NSEG, 256, 0, stream>>>(deg, offp, cur, part);
    k_scan2<<<1, 128, 0, stream>>>(part, partoff, offp);
    k_scan3<<<NSEG, 256, 0, stream>>>(partoff, offp, cur);
    k_fill<<<(NE + 255) / 256, 256, 0, stream>>>(ei, cur, eid, esrc);
    // layer 1
    k_x<32, 128><<<dim3(2048, 1), 256, 0, stream>>>(h0, W1, atts1, attd1, x, asd);
    k_alpha<<<(NE + 255) / 256, 256, 0, stream>>>(ei, ppos, wpos, gamma, smallw + 0, smallw + 128, asd, alpha);
    k_agg<<<NN / 4, 256, 0, stream>>>(offp, eid, esrc, alpha, x, b1, hbuf);
    // layer 2
    k_x<128, 64><<<dim3(2048, 2), 256, 0, stream>>>(hbuf, W2, atts2, attd2, x, asd);
    k_alpha<<<(NE + 255) / 256, 256, 0, stream>>>(ei, ppos, wpos, gamma, smallw + 132, smallw + 260, asd, alpha);
    k_agg<<<NN / 4, 256, 0, stream>>>(offp, eid, esrc, alpha, x, b2, hbuf);
    // MLP on water nodes
    k_mlp<<<2048, 256, 0, stream>>>(hbuf, Wm1, bm1, Wm2, bm2, out);
}

// Round 4
// 720.169 us; speedup vs baseline: 1.3702x; 1.0856x over previous
//
#include <hip/hip_runtime.h>
#include <stdint.h>

#define N_PRO 60000
#define N_WAT 40000
#define NN    100000
#define NE    1000000
#define IN_DIM 21
#define HID    32
#define HEADS  4
#define HC     128
#define EDGE_K 32
#define NSEG   ((NN + 1023) / 1024)   // 98 segments for the hierarchical scan

// ---------------------------------------------------------------------------
// K1: tiny fused weights. V_l[d][h] = sum_c Wedge_l[d, h*32+c] * atte_l[h,c]
// U_l[32,4] = We @ V_l ; aeb_l[4] = be . V_l ; h0w[32] = Wf[20,:] + bf
// smallw floats: [0..127]=U1, [128..131]=aeb1, [132..259]=U2, [260..263]=aeb2,
// [264..295]=h0w
// ---------------------------------------------------------------------------
__global__ __launch_bounds__(256) void k_small(
    const float* We, const float* be,
    const float* Wedge1, const float* atte1,
    const float* Wedge2, const float* atte2,
    const float* Wf, const float* bfv, float* smallw)
{
    __shared__ float V[2][128];
    int t = threadIdx.x;
    {
        int l = t >> 7, dh = t & 127, d = dh >> 2, h = dh & 3;
        const float* Wg = l ? Wedge2 : Wedge1;
        const float* ae = l ? atte2 : atte1;
        float s = 0.f;
        for (int c = 0; c < HID; c++)
            s += Wg[d * HC + h * HID + c] * ae[h * HID + c];
        V[l][dh] = s;
    }
    __syncthreads();
    {
        int l = t >> 7, kh = t & 127, k = kh >> 2, h = kh & 3;
        float s = 0.f;
        for (int d = 0; d < 32; d++)
            s += We[k * 32 + d] * V[l][d * 4 + h];
        smallw[(l ? 132 : 0) + kh] = s;
    }
    if (t < 8) {
        int l = t >> 2, h = t & 3;
        float s = 0.f;
        for (int d = 0; d < 32; d++)
            s += be[d] * V[l][d * 4 + h];
        smallw[(l ? 260 : 128) + h] = s;
    }
    if (t >= 32 && t < 64) {
        int c = t - 32;
        smallw[264 + c] = Wf[20 * 32 + c] + bfv[c];
    }
}

// ---------------------------------------------------------------------------
// K2: h0 = feats @ Wf + bf  (water rows are the precomputed constant row)
// ---------------------------------------------------------------------------
__global__ __launch_bounds__(256) void k_h0(
    const float* __restrict__ pf, const float* __restrict__ Wf,
    const float* __restrict__ bfv, const float* __restrict__ smallw,
    float* __restrict__ h0)
{
    __shared__ float Wfs[IN_DIM * 32];
    __shared__ float bfs[32];
    __shared__ float h0w[32];
    int t = threadIdx.x;
    for (int i = t; i < IN_DIM * 32; i += 256) Wfs[i] = Wf[i];
    if (t < 32) { bfs[t] = bfv[t]; h0w[t] = smallw[264 + t]; }
    __syncthreads();
    int id = blockIdx.x * 256 + t;
    int n = id >> 5, c = id & 31;
    if (n >= NN) return;
    float v;
    if (n < N_PRO) {
        float s = bfs[c];
        for (int k = 0; k < IN_DIM; k++)
            s += pf[n * IN_DIM + k] * Wfs[k * 32 + c];
        v = s;
    } else {
        v = h0w[c];
    }
    h0[n * 32 + c] = v;
}

// ---------------------------------------------------------------------------
// CSR build over dst: count -> hierarchical scan (3 passes) -> fill
// ---------------------------------------------------------------------------
__global__ __launch_bounds__(256) void k_count(const int* ei, int* deg) {
    int e = blockIdx.x * 256 + threadIdx.x;
    if (e >= NE) return;
    int d = ei[NE + e];
    if ((unsigned)d < (unsigned)NN) atomicAdd(&deg[d], 1);
}

// pass 1: per-1024-segment local exclusive scan; segment total -> part[b]
__global__ __launch_bounds__(256) void k_scan1(
    const int* __restrict__ deg, int* __restrict__ off,
    int* __restrict__ cur, int* __restrict__ part)
{
    __shared__ int s[256];
    int t = threadIdx.x;
    int base = blockIdx.x * 1024 + t * 4;
    int d0 = 0, d1 = 0, d2 = 0, d3 = 0;
    if (base + 3 < NN) {
        int4 v = *(const int4*)&deg[base];
        d0 = v.x; d1 = v.y; d2 = v.z; d3 = v.w;
    } else {
        if (base + 0 < NN) d0 = deg[base + 0];
        if (base + 1 < NN) d1 = deg[base + 1];
        if (base + 2 < NN) d2 = deg[base + 2];
    }
    int tsum = d0 + d1 + d2 + d3;
    s[t] = tsum;
    __syncthreads();
    #pragma unroll
    for (int o = 1; o < 256; o <<= 1) {
        int v = (t >= o) ? s[t - o] : 0;
        __syncthreads();
        s[t] += v;
        __syncthreads();
    }
    int ex = s[t] - tsum;
    if (base + 0 < NN) { int v = ex;                 off[base + 0] = v; cur[base + 0] = v; }
    if (base + 1 < NN) { int v = ex + d0;            off[base + 1] = v; cur[base + 1] = v; }
    if (base + 2 < NN) { int v = ex + d0 + d1;       off[base + 2] = v; cur[base + 2] = v; }
    if (base + 3 < NN) { int v = ex + d0 + d1 + d2;  off[base + 3] = v; cur[base + 3] = v; }
    if (t == 255) part[blockIdx.x] = s[255];
}

// pass 2: scan the 98 segment totals (single small block); writes off[NN]
__global__ __launch_bounds__(128) void k_scan2(
    const int* __restrict__ part, int* __restrict__ partoff, int* __restrict__ off)
{
    __shared__ int s[128];
    int t = threadIdx.x;
    int v = (t < NSEG) ? part[t] : 0;
    s[t] = v;
    __syncthreads();
    #pragma unroll
    for (int o = 1; o < 128; o <<= 1) {
        int x = (t >= o) ? s[t - o] : 0;
        __syncthreads();
        s[t] += x;
        __syncthreads();
    }
    partoff[t] = s[t] - v;   // exclusive prefix
    if (t == 127) off[NN] = s[127];
}

// pass 3: add segment base to each element of off/cur
__global__ __launch_bounds__(256) void k_scan3(
    const int* __restrict__ partoff, int* __restrict__ off, int* __restrict__ cur)
{
    int b = blockIdx.x;
    int add = partoff[b];
    if (add == 0) return;   // first segment(s) unchanged
    int base = b * 1024 + threadIdx.x * 4;
    #pragma unroll
    for (int j = 0; j < 4; j++) {
        int i = base + j;
        if (i < NN) { off[i] += add; cur[i] += add; }
    }
}

__global__ __launch_bounds__(256) void k_fill(const int* ei, int* cur, int* eid, int* esrc) {
    int e = blockIdx.x * 256 + threadIdx.x;
    if (e >= NE) return;
    int d = ei[NE + e];
    int srcn = ei[e];
    if ((unsigned)d >= (unsigned)NN || (unsigned)srcn >= (unsigned)NN) return;
    int p = atomicAdd(&cur[d], 1);
    eid[p] = e;
    esrc[p] = srcn;
}

// ---------------------------------------------------------------------------
// K6: x = h @ W (+ attention logits a_s, a_d).
// One 32-node tile per block, single barrier. Thread t: node = t>>3 (within
// tile), col block cq = t&7 owning CPT = COLS/8 columns. h tile in LDS with
// +4 padded row stride (kills the cross-node same-bank alias); W slab and
// att vectors in LDS (reads are broadcast / 2-way — free).
// ---------------------------------------------------------------------------
template <int DIN, int COLS>
__global__ __launch_bounds__(256) void k_x(
    const float* __restrict__ h, const float* __restrict__ Wg,
    const float* __restrict__ atts, const float* __restrict__ attd,
    float* __restrict__ x, float* __restrict__ asd)
{
    constexpr int CPT = COLS / 8;      // cols per thread: 16 (L1) or 8 (L2)
    constexpr int HSTR = DIN + 4;      // padded LDS row stride (36 / 132)
    constexpr int TPH = 32 / CPT;      // threads per head: 2 (L1) or 4 (L2)
    __shared__ float Ws[DIN * COLS];
    __shared__ float hs[32 * HSTR];
    __shared__ float attS[COLS], attD[COLS];
    int t = threadIdx.x;
    int cbase = blockIdx.y * COLS;
    for (int i = t; i < DIN * COLS; i += 256) {
        int d = i / COLS, c = i % COLS;
        Ws[i] = Wg[d * 128 + cbase + c];
    }
    if (t < COLS) { attS[t] = atts[cbase + t]; attD[t] = attd[cbase + t]; }
    int n0 = blockIdx.x * 32;
    for (int i4 = t * 4; i4 < 32 * DIN; i4 += 1024) {
        int r = i4 / DIN, c = i4 % DIN;
        float4 v = *(const float4*)&h[(n0 + r) * DIN + c];
        *(float4*)&hs[r * HSTR + c] = v;
    }
    __syncthreads();
    int node = t >> 3, cq = t & 7, c0 = cq * CPT;
    float acc[CPT];
    #pragma unroll
    for (int j = 0; j < CPT; j++) acc[j] = 0.f;
    const float* hrow = &hs[node * HSTR];
    #pragma unroll 4
    for (int d = 0; d < DIN; d++) {
        float hv = hrow[d];
        #pragma unroll
        for (int j = 0; j < CPT; j++)
            acc[j] += hv * Ws[d * COLS + c0 + j];
    }
    int n = n0 + node;
    #pragma unroll
    for (int j = 0; j < CPT; j += 4)
        *(float4*)&x[n * 128 + cbase + c0 + j] =
            make_float4(acc[j], acc[j + 1], acc[j + 2], acc[j + 3]);
    float ps = 0.f, pd = 0.f;
    #pragma unroll
    for (int j = 0; j < CPT; j++) {
        ps += acc[j] * attS[c0 + j];
        pd += acc[j] * attD[c0 + j];
    }
    #pragma unroll
    for (int mk = 1; mk < TPH; mk <<= 1) {
        ps += __shfl_xor(ps, mk, 64);
        pd += __shfl_xor(pd, mk, 64);
    }
    if ((cq % TPH) == 0) {
        int hh = (cbase + c0) >> 5;
        asd[n * 8 + hh] = ps;
        asd[n * 8 + 4 + hh] = pd;
    }
}

// ---------------------------------------------------------------------------
// K7: per-edge attention logits alpha[E,4] = leaky(a_s[src]+a_d[dst]+RBF@U+aeb)
// ---------------------------------------------------------------------------
__global__ __launch_bounds__(256) void k_alpha(
    const int* __restrict__ ei, const float* __restrict__ ppos,
    const float* __restrict__ wpos, const float* __restrict__ gamma,
    const float* __restrict__ U, const float* __restrict__ aeb,
    const float* __restrict__ asd, float* __restrict__ alpha)
{
    __shared__ float Us[128];
    __shared__ float aebs[4];
    int t = threadIdx.x;
    if (t < 128) Us[t] = U[t];
    if (t < 4) aebs[t] = aeb[t];
    __syncthreads();
    int e = blockIdx.x * 256 + t;
    if (e >= NE) return;
    int sn = ei[e], dn = ei[NE + e];
    if ((unsigned)sn >= (unsigned)NN || (unsigned)dn >= (unsigned)NN) return;
    const float* ps = (sn < N_PRO) ? &ppos[sn * 3] : &wpos[(sn - N_PRO) * 3];
    const float* pd = (dn < N_PRO) ? &ppos[dn * 3] : &wpos[(dn - N_PRO) * 3];
    float dx = pd[0] - ps[0];
    float dy = pd[1] - ps[1];
    float dz = pd[2] - ps[2];
    float dist = sqrtf(dx * dx + dy * dy + dz * dz);
    float g = gamma[0];
    float ae0 = aebs[0], ae1 = aebs[1], ae2 = aebs[2], ae3 = aebs[3];
    const float step = 5.0f / 31.0f;
    #pragma unroll
    for (int k = 0; k < EDGE_K; k++) {
        float tt = dist - (float)k * step;
        float r = __expf(-g * tt * tt);
        ae0 += r * Us[k * 4 + 0];
        ae1 += r * Us[k * 4 + 1];
        ae2 += r * Us[k * 4 + 2];
        ae3 += r * Us[k * 4 + 3];
    }
    float4 as4 = *(const float4*)&asd[sn * 8];
    float4 ad4 = *(const float4*)&asd[dn * 8 + 4];
    float v0 = as4.x + ad4.x + ae0;
    float v1 = as4.y + ad4.y + ae1;
    float v2 = as4.z + ad4.z + ae2;
    float v3 = as4.w + ad4.w + ae3;
    v0 = v0 >= 0.f ? v0 : 0.2f * v0;
    v1 = v1 >= 0.f ? v1 : 0.2f * v1;
    v2 = v2 >= 0.f ? v2 : 0.2f * v2;
    v3 = v3 >= 0.f ? v3 : 0.2f * v3;
    *(float4*)&alpha[e * 4] = make_float4(v0, v1, v2, v3);
}

// ---------------------------------------------------------------------------
// K8: per-dst-node online-softmax aggregation. One wave per node; lane l owns
// channels 2l,2l+1 (head = l/16). Single pass, no float atomics.
// out = elu(acc/(l+1e-16) + b)
// ---------------------------------------------------------------------------
__global__ __launch_bounds__(256) void k_agg(
    const int* __restrict__ off, const int* __restrict__ eid,
    const int* __restrict__ esrc, const float* __restrict__ alpha,
    const float* __restrict__ x, const float* __restrict__ bias,
    float* __restrict__ hout)
{
    int t = threadIdx.x;
    int w = t >> 6, lane = t & 63;
    int n = blockIdx.x * 4 + w;
    if (n >= NN) return;
    int h = lane >> 4;
    int beg = off[n], end = off[n + 1];
    float m = -INFINITY, lsum = 0.f, acc0 = 0.f, acc1 = 0.f;
    const float2* x2 = (const float2*)x;
    for (int i = beg; i < end; i++) {
        int e = eid[i];
        int s = esrc[i];
        float a = alpha[e * 4 + h];
        float mn = fmaxf(m, a);
        float sc = __expf(m - mn);
        float we = __expf(a - mn);
        float2 xv = x2[s * 64 + lane];
        lsum = lsum * sc + we;
        acc0 = acc0 * sc + we * xv.x;
        acc1 = acc1 * sc + we * xv.y;
        m = mn;
    }
    float inv = 1.0f / (lsum + 1e-16f);
    float2 bb = *(const float2*)&bias[lane * 2];
    float o0 = acc0 * inv + bb.x;
    float o1 = acc1 * inv + bb.y;
    o0 = o0 > 0.f ? o0 : __expf(o0) - 1.0f;
    o1 = o1 > 0.f ? o1 : __expf(o1) - 1.0f;
    ((float2*)&hout[n * 128])[lane] = make_float2(o0, o1);
}

// ---------------------------------------------------------------------------
// K9: water MLP: out = relu(h@Wm1+bm1)@Wm2 + bm2. Wm1 staged in LDS in two
// 64-column halves per tile (32 KB buffer keeps block under the 64 KB cap).
// ---------------------------------------------------------------------------
__global__ __launch_bounds__(256) void k_mlp(
    const float* __restrict__ hh, const float* __restrict__ Wm1,
    const float* __restrict__ bm1, const float* __restrict__ Wm2,
    const float* __restrict__ bm2, float* __restrict__ out)
{
    __shared__ float W1s[128 * 64];
    __shared__ float hs[8 * 128];
    int t = threadIdx.x;
    int nsub = t >> 5, q = t & 31;
    float b1r[2][2], w2r[2][2][2];
    #pragma unroll
    for (int hf = 0; hf < 2; hf++)
        #pragma unroll
        for (int j = 0; j < 2; j++) {
            int c = hf * 64 + q * 2 + j;
            b1r[hf][j] = bm1[c];
            w2r[hf][j][0] = Wm2[c * 2 + 0];
            w2r[hf][j][1] = Wm2[c * 2 + 1];
        }
    float b20 = bm2[0], b21 = bm2[1];
    const int NT = N_WAT / 8;
    for (int tile = blockIdx.x; tile < NT; tile += gridDim.x) {
        __syncthreads();
        for (int i = t; i < 8 * 128; i += 256)
            hs[i] = hh[(N_PRO + tile * 8 + (i >> 7)) * 128 + (i & 127)];
        float p0 = 0.f, p1 = 0.f;
        const float* hrow = &hs[nsub * 128];
        #pragma unroll
        for (int hf = 0; hf < 2; hf++) {
            __syncthreads();
            for (int i = t; i < 128 * 64; i += 256)
                W1s[i] = Wm1[(i >> 6) * 128 + hf * 64 + (i & 63)];
            __syncthreads();
            float a0 = 0.f, a1 = 0.f;
            #pragma unroll 8
            for (int d = 0; d < 128; d++) {
                float hv = hrow[d];
                float2 w = *(const float2*)&W1s[d * 64 + q * 2];
                a0 += hv * w.x;
                a1 += hv * w.y;
            }
            a0 = fmaxf(a0 + b1r[hf][0], 0.f);
            a1 = fmaxf(a1 + b1r[hf][1], 0.f);
            p0 += a0 * w2r[hf][0][0] + a1 * w2r[hf][1][0];
            p1 += a0 * w2r[hf][0][1] + a1 * w2r[hf][1][1];
        }
        #pragma unroll
        for (int mk = 1; mk < 32; mk <<= 1) {
            p0 += __shfl_xor(p0, mk, 64);
            p1 += __shfl_xor(p1, mk, 64);
        }
        if (q == 0) {
            int r = tile * 8 + nsub;
            out[r * 2 + 0] = p0 + b20;
            out[r * 2 + 1] = p1 + b21;
        }
    }
}

// ---------------------------------------------------------------------------
extern "C" void kernel_launch(void* const* d_in, const int* in_sizes, int n_in,
                              void* d_out, int out_size, void* d_ws, size_t ws_size,
                              hipStream_t stream)
{
    const float* ppos   = (const float*)d_in[0];
    const float* wpos   = (const float*)d_in[1];
    const float* pfeat  = (const float*)d_in[2];
    const int*   ei     = (const int*)d_in[3];
    const float* gamma  = (const float*)d_in[4];
    const float* Wf     = (const float*)d_in[5];
    const float* bfv    = (const float*)d_in[6];
    const float* We     = (const float*)d_in[7];
    const float* be     = (const float*)d_in[8];
    const float* W1     = (const float*)d_in[9];
    const float* atts1  = (const float*)d_in[10];
    const float* attd1  = (const float*)d_in[11];
    const float* Wedge1 = (const float*)d_in[12];
    const float* atte1  = (const float*)d_in[13];
    const float* b1     = (const float*)d_in[14];
    const float* W2     = (const float*)d_in[15];
    const float* atts2  = (const float*)d_in[16];
    const float* attd2  = (const float*)d_in[17];
    const float* Wedge2 = (const float*)d_in[18];
    const float* atte2  = (const float*)d_in[19];
    const float* b2     = (const float*)d_in[20];
    const float* Wm1    = (const float*)d_in[21];
    const float* bm1    = (const float*)d_in[22];
    const float* Wm2    = (const float*)d_in[23];
    const float* bm2    = (const float*)d_in[24];
    float* out = (float*)d_out;

    char* ws = (char*)d_ws;
    size_t o = 0;
    auto alloc = [&](size_t bytes) -> char* {
        char* p = ws + o;
        o += (bytes + 255) & ~(size_t)255;
        return p;
    };
    float* h0      = (float*)alloc((size_t)NN * 32 * 4);
    float* x       = (float*)alloc((size_t)NN * 128 * 4);
    float* hbuf    = (float*)alloc((size_t)NN * 128 * 4);
    float* asd     = (float*)alloc((size_t)NN * 8 * 4);
    float* alpha   = (float*)alloc((size_t)NE * 4 * 4);
    int*   deg     = (int*)alloc((size_t)(NN + 1) * 4);
    int*   offp    = (int*)alloc((size_t)(NN + 1) * 4);
    int*   cur     = (int*)alloc((size_t)NN * 4);
    int*   eid     = (int*)alloc((size_t)NE * 4);
    int*   esrc    = (int*)alloc((size_t)NE * 4);
    int*   part    = (int*)alloc((size_t)NSEG * 4);
    int*   partoff = (int*)alloc((size_t)(128 + 1) * 4);
    float* smallw  = (float*)alloc(4096);

    hipMemsetAsync(deg, 0, (NN + 1) * 4, stream);
    k_small<<<1, 256, 0, stream>>>(We, be, Wedge1, atte1, Wedge2, atte2, Wf, bfv, smallw);
    k_h0<<<(NN * 32) / 256, 256, 0, stream>>>(pfeat, Wf, bfv, smallw, h0);
    k_count<<<(NE + 255) / 256, 256, 0, stream>>>(ei, deg);
    k_scan1<<<NSEG, 256, 0, stream>>>(deg, offp, cur, part);
    k_scan2<<<1, 128, 0, stream>>>(part, partoff, offp);
    k_scan3<<<NSEG, 256, 0, stream>>>(partoff, offp, cur);
    k_fill<<<(NE + 255) / 256, 256, 0, stream>>>(ei, cur, eid, esrc);
    // layer 1
    k_x<32, 128><<<dim3(NN / 32, 1), 256, 0, stream>>>(h0, W1, atts1, attd1, x, asd);
    k_alpha<<<(NE + 255) / 256, 256, 0, stream>>>(ei, ppos, wpos, gamma, smallw + 0, smallw + 128, asd, alpha);
    k_agg<<<NN / 4, 256, 0, stream>>>(offp, eid, esrc, alpha, x, b1, hbuf);
    // layer 2
    k_x<128, 64><<<dim3(NN / 32, 2), 256, 0, stream>>>(hbuf, W2, atts2, attd2, x, asd);
    k_alpha<<<(NE + 255) / 256, 256, 0, stream>>>(ei, ppos, wpos, gamma, smallw + 132, smallw + 260, asd, alpha);
    k_agg<<<NN / 4, 256, 0, stream>>>(offp, eid, esrc, alpha, x, b2, hbuf);
    // MLP on water nodes
    k_mlp<<<2048, 256, 0, stream>>>(hbuf, Wm1, bm1, Wm2, bm2, out);
}

// Round 5
// 598.156 us; speedup vs baseline: 1.6497x; 1.2040x over previous
//
#include <hip/hip_runtime.h>
#include <hip/hip_fp16.h>
#include <stdint.h>

#define N_PRO 60000
#define N_WAT 40000
#define NN    100000
#define NE    1000000
#define IN_DIM 21
#define HID    32
#define HEADS  4
#define HC     128
#define EDGE_K 32
#define NSEG   ((NN + 1023) / 1024)   // 98 segments for the hierarchical scan

// ---------------------------------------------------------------------------
// K1: tiny fused weights. V_l[d][h] = sum_c Wedge_l[d, h*32+c] * atte_l[h,c]
// U_l[32,4] = We @ V_l ; aeb_l[4] = be . V_l ; h0w[32] = Wf[20,:] + bf
// smallw floats: [0..127]=U1, [128..131]=aeb1, [132..259]=U2, [260..263]=aeb2,
// [264..295]=h0w
// ---------------------------------------------------------------------------
__global__ __launch_bounds__(256) void k_small(
    const float* We, const float* be,
    const float* Wedge1, const float* atte1,
    const float* Wedge2, const float* atte2,
    const float* Wf, const float* bfv, float* smallw)
{
    __shared__ float V[2][128];
    int t = threadIdx.x;
    {
        int l = t >> 7, dh = t & 127, d = dh >> 2, h = dh & 3;
        const float* Wg = l ? Wedge2 : Wedge1;
        const float* ae = l ? atte2 : atte1;
        float s = 0.f;
        for (int c = 0; c < HID; c++)
            s += Wg[d * HC + h * HID + c] * ae[h * HID + c];
        V[l][dh] = s;
    }
    __syncthreads();
    {
        int l = t >> 7, kh = t & 127, k = kh >> 2, h = kh & 3;
        float s = 0.f;
        for (int d = 0; d < 32; d++)
            s += We[k * 32 + d] * V[l][d * 4 + h];
        smallw[(l ? 132 : 0) + kh] = s;
    }
    if (t < 8) {
        int l = t >> 2, h = t & 3;
        float s = 0.f;
        for (int d = 0; d < 32; d++)
            s += be[d] * V[l][d * 4 + h];
        smallw[(l ? 260 : 128) + h] = s;
    }
    if (t >= 32 && t < 64) {
        int c = t - 32;
        smallw[264 + c] = Wf[20 * 32 + c] + bfv[c];
    }
}

// ---------------------------------------------------------------------------
// K2: h0 = feats @ Wf + bf  (water rows are the precomputed constant row)
// ---------------------------------------------------------------------------
__global__ __launch_bounds__(256) void k_h0(
    const float* __restrict__ pf, const float* __restrict__ Wf,
    const float* __restrict__ bfv, const float* __restrict__ smallw,
    float* __restrict__ h0)
{
    __shared__ float Wfs[IN_DIM * 32];
    __shared__ float bfs[32];
    __shared__ float h0w[32];
    int t = threadIdx.x;
    for (int i = t; i < IN_DIM * 32; i += 256) Wfs[i] = Wf[i];
    if (t < 32) { bfs[t] = bfv[t]; h0w[t] = smallw[264 + t]; }
    __syncthreads();
    int id = blockIdx.x * 256 + t;
    int n = id >> 5, c = id & 31;
    if (n >= NN) return;
    float v;
    if (n < N_PRO) {
        float s = bfs[c];
        for (int k = 0; k < IN_DIM; k++)
            s += pf[n * IN_DIM + k] * Wfs[k * 32 + c];
        v = s;
    } else {
        v = h0w[c];
    }
    h0[n * 32 + c] = v;
}

// ---------------------------------------------------------------------------
// CSR build over dst: count -> hierarchical scan (3 passes) -> fill
// ---------------------------------------------------------------------------
__global__ __launch_bounds__(256) void k_count(const int* ei, int* deg) {
    int e = blockIdx.x * 256 + threadIdx.x;
    if (e >= NE) return;
    int d = ei[NE + e];
    int s = ei[e];
    if ((unsigned)d < (unsigned)NN && (unsigned)s < (unsigned)NN)
        atomicAdd(&deg[d], 1);
}

// pass 1: per-1024-segment local exclusive scan; segment total -> part[b]
__global__ __launch_bounds__(256) void k_scan1(
    const int* __restrict__ deg, int* __restrict__ off,
    int* __restrict__ cur, int* __restrict__ part)
{
    __shared__ int s[256];
    int t = threadIdx.x;
    int base = blockIdx.x * 1024 + t * 4;
    int d0 = 0, d1 = 0, d2 = 0, d3 = 0;
    if (base + 3 < NN) {
        int4 v = *(const int4*)&deg[base];
        d0 = v.x; d1 = v.y; d2 = v.z; d3 = v.w;
    } else {
        if (base + 0 < NN) d0 = deg[base + 0];
        if (base + 1 < NN) d1 = deg[base + 1];
        if (base + 2 < NN) d2 = deg[base + 2];
    }
    int tsum = d0 + d1 + d2 + d3;
    s[t] = tsum;
    __syncthreads();
    #pragma unroll
    for (int o = 1; o < 256; o <<= 1) {
        int v = (t >= o) ? s[t - o] : 0;
        __syncthreads();
        s[t] += v;
        __syncthreads();
    }
    int ex = s[t] - tsum;
    if (base + 0 < NN) { int v = ex;                 off[base + 0] = v; cur[base + 0] = v; }
    if (base + 1 < NN) { int v = ex + d0;            off[base + 1] = v; cur[base + 1] = v; }
    if (base + 2 < NN) { int v = ex + d0 + d1;       off[base + 2] = v; cur[base + 2] = v; }
    if (base + 3 < NN) { int v = ex + d0 + d1 + d2;  off[base + 3] = v; cur[base + 3] = v; }
    if (t == 255) part[blockIdx.x] = s[255];
}

// pass 2: scan the 98 segment totals (single small block); writes off[NN]
__global__ __launch_bounds__(128) void k_scan2(
    const int* __restrict__ part, int* __restrict__ partoff, int* __restrict__ off)
{
    __shared__ int s[128];
    int t = threadIdx.x;
    int v = (t < NSEG) ? part[t] : 0;
    s[t] = v;
    __syncthreads();
    #pragma unroll
    for (int o = 1; o < 128; o <<= 1) {
        int x = (t >= o) ? s[t - o] : 0;
        __syncthreads();
        s[t] += x;
        __syncthreads();
    }
    partoff[t] = s[t] - v;   // exclusive prefix
    if (t == 127) off[NN] = s[127];
}

// pass 3: add segment base to each element of off/cur
__global__ __launch_bounds__(256) void k_scan3(
    const int* __restrict__ partoff, int* __restrict__ off, int* __restrict__ cur)
{
    int b = blockIdx.x;
    int add = partoff[b];
    if (add == 0) return;   // first segment(s) unchanged
    int base = b * 1024 + threadIdx.x * 4;
    #pragma unroll
    for (int j = 0; j < 4; j++) {
        int i = base + j;
        if (i < NN) { off[i] += add; cur[i] += add; }
    }
}

// fill CSR: per slot store src and dst (edge id no longer needed — alpha is
// computed directly in CSR order)
__global__ __launch_bounds__(256) void k_fill(const int* ei, int* cur, int* esrc, int* edst) {
    int e = blockIdx.x * 256 + threadIdx.x;
    if (e >= NE) return;
    int d = ei[NE + e];
    int srcn = ei[e];
    if ((unsigned)d >= (unsigned)NN || (unsigned)srcn >= (unsigned)NN) return;
    int p = atomicAdd(&cur[d], 1);
    esrc[p] = srcn;
    edst[p] = d;
}

// ---------------------------------------------------------------------------
// K6: x = h @ W (+ attention logits a_s, a_d).  x stored as fp16 (halves the
// k_agg gather traffic). One 32-node tile per block, single barrier.
// ---------------------------------------------------------------------------
template <int DIN, int COLS>
__global__ __launch_bounds__(256) void k_x(
    const float* __restrict__ h, const float* __restrict__ Wg,
    const float* __restrict__ atts, const float* __restrict__ attd,
    __half* __restrict__ x16, float* __restrict__ asd)
{
    constexpr int CPT = COLS / 8;      // cols per thread: 16 (L1) or 8 (L2)
    constexpr int HSTR = DIN + 4;      // padded LDS row stride
    constexpr int TPH = 32 / CPT;      // threads per head
    __shared__ float Ws[DIN * COLS];
    __shared__ float hs[32 * HSTR];
    __shared__ float attS[COLS], attD[COLS];
    int t = threadIdx.x;
    int cbase = blockIdx.y * COLS;
    for (int i = t; i < DIN * COLS; i += 256) {
        int d = i / COLS, c = i % COLS;
        Ws[i] = Wg[d * 128 + cbase + c];
    }
    if (t < COLS) { attS[t] = atts[cbase + t]; attD[t] = attd[cbase + t]; }
    int n0 = blockIdx.x * 32;
    for (int i4 = t * 4; i4 < 32 * DIN; i4 += 1024) {
        int r = i4 / DIN, c = i4 % DIN;
        float4 v = *(const float4*)&h[(n0 + r) * DIN + c];
        *(float4*)&hs[r * HSTR + c] = v;
    }
    __syncthreads();
    int node = t >> 3, cq = t & 7, c0 = cq * CPT;
    float acc[CPT];
    #pragma unroll
    for (int j = 0; j < CPT; j++) acc[j] = 0.f;
    const float* hrow = &hs[node * HSTR];
    #pragma unroll 4
    for (int d = 0; d < DIN; d++) {
        float hv = hrow[d];
        #pragma unroll
        for (int j = 0; j < CPT; j++)
            acc[j] += hv * Ws[d * COLS + c0 + j];
    }
    int n = n0 + node;
    #pragma unroll
    for (int j = 0; j < CPT; j += 2) {
        __half2 hv = __floats2half2_rn(acc[j], acc[j + 1]);
        *(__half2*)&x16[(size_t)n * 128 + cbase + c0 + j] = hv;
    }
    float ps = 0.f, pd = 0.f;
    #pragma unroll
    for (int j = 0; j < CPT; j++) {
        ps += acc[j] * attS[c0 + j];
        pd += acc[j] * attD[c0 + j];
    }
    #pragma unroll
    for (int mk = 1; mk < TPH; mk <<= 1) {
        ps += __shfl_xor(ps, mk, 64);
        pd += __shfl_xor(pd, mk, 64);
    }
    if ((cq % TPH) == 0) {
        int hh = (cbase + c0) >> 5;
        asd[n * 8 + hh] = ps;
        asd[n * 8 + 4 + hh] = pd;
    }
}

// ---------------------------------------------------------------------------
// K7: attention logits in CSR slot order: alpha[i,4] for slot i with
// src=esrc[i], dst=edst[i]. Sequential reads/writes (no edge-id indirection).
// LAYER==2 skips slots below off[N_PRO] (protein dst — never consumed).
// ---------------------------------------------------------------------------
template <int LAYER>
__global__ __launch_bounds__(256) void k_alpha(
    const int* __restrict__ esrc, const int* __restrict__ edst,
    const int* __restrict__ wlim,
    const float* __restrict__ ppos, const float* __restrict__ wpos,
    const float* __restrict__ gamma,
    const float* __restrict__ U, const float* __restrict__ aeb,
    const float* __restrict__ asd, float* __restrict__ alpha)
{
    __shared__ float Us[128];
    __shared__ float aebs[4];
    int t = threadIdx.x;
    if (t < 128) Us[t] = U[t];
    if (t < 4) aebs[t] = aeb[t];
    __syncthreads();
    int i = blockIdx.x * 256 + t;
    if (i >= NE) return;
    if (LAYER == 2 && i < wlim[0]) return;
    int sn = esrc[i], dn = edst[i];
    const float* ps = (sn < N_PRO) ? &ppos[sn * 3] : &wpos[(sn - N_PRO) * 3];
    const float* pd = (dn < N_PRO) ? &ppos[dn * 3] : &wpos[(dn - N_PRO) * 3];
    float dx = pd[0] - ps[0];
    float dy = pd[1] - ps[1];
    float dz = pd[2] - ps[2];
    float dist = sqrtf(dx * dx + dy * dy + dz * dz);
    float g = gamma[0];
    float ae0 = aebs[0], ae1 = aebs[1], ae2 = aebs[2], ae3 = aebs[3];
    const float step = 5.0f / 31.0f;
    #pragma unroll
    for (int k = 0; k < EDGE_K; k++) {
        float tt = dist - (float)k * step;
        float r = __expf(-g * tt * tt);
        ae0 += r * Us[k * 4 + 0];
        ae1 += r * Us[k * 4 + 1];
        ae2 += r * Us[k * 4 + 2];
        ae3 += r * Us[k * 4 + 3];
    }
    float4 as4 = *(const float4*)&asd[sn * 8];
    float4 ad4 = *(const float4*)&asd[dn * 8 + 4];
    float v0 = as4.x + ad4.x + ae0;
    float v1 = as4.y + ad4.y + ae1;
    float v2 = as4.z + ad4.z + ae2;
    float v3 = as4.w + ad4.w + ae3;
    v0 = v0 >= 0.f ? v0 : 0.2f * v0;
    v1 = v1 >= 0.f ? v1 : 0.2f * v1;
    v2 = v2 >= 0.f ? v2 : 0.2f * v2;
    v3 = v3 >= 0.f ? v3 : 0.2f * v3;
    *(float4*)&alpha[i * 4] = make_float4(v0, v1, v2, v3);
}

// ---------------------------------------------------------------------------
// K8: per-dst-node online-softmax aggregation. One wave per node; lane l owns
// channels 2l,2l+1 (head = l/16). alpha read sequentially (CSR order);
// x gathered as fp16 pairs (4 B/lane). WATER_ONLY=1 starts at node N_PRO.
// ---------------------------------------------------------------------------
template <int WATER_ONLY>
__global__ __launch_bounds__(256) void k_agg(
    const int* __restrict__ off, const int* __restrict__ esrc,
    const float* __restrict__ alpha, const __half* __restrict__ x16,
    const float* __restrict__ bias, float* __restrict__ hout)
{
    int t = threadIdx.x;
    int w = t >> 6, lane = t & 63;
    int n = (WATER_ONLY ? N_PRO : 0) + blockIdx.x * 4 + w;
    if (n >= NN) return;
    int h = lane >> 4;
    int beg = off[n], end = off[n + 1];
    float m = -INFINITY, lsum = 0.f, acc0 = 0.f, acc1 = 0.f;
    const __half2* x2 = (const __half2*)x16;
    for (int i = beg; i < end; i++) {
        int s = esrc[i];
        float a = alpha[i * 4 + h];
        float mn = fmaxf(m, a);
        float sc = __expf(m - mn);
        float we = __expf(a - mn);
        float2 xv = __half22float2(x2[(size_t)s * 64 + lane]);
        lsum = lsum * sc + we;
        acc0 = acc0 * sc + we * xv.x;
        acc1 = acc1 * sc + we * xv.y;
        m = mn;
    }
    float inv = 1.0f / (lsum + 1e-16f);
    float2 bb = *(const float2*)&bias[lane * 2];
    float o0 = acc0 * inv + bb.x;
    float o1 = acc1 * inv + bb.y;
    o0 = o0 > 0.f ? o0 : __expf(o0) - 1.0f;
    o1 = o1 > 0.f ? o1 : __expf(o1) - 1.0f;
    ((float2*)&hout[n * 128])[lane] = make_float2(o0, o1);
}

// ---------------------------------------------------------------------------
// K9: water MLP: out = relu(h@Wm1+bm1)@Wm2 + bm2. Wm1 staged in LDS in two
// 64-column halves per tile (32 KB buffer keeps block under the 64 KB cap).
// ---------------------------------------------------------------------------
__global__ __launch_bounds__(256) void k_mlp(
    const float* __restrict__ hh, const float* __restrict__ Wm1,
    const float* __restrict__ bm1, const float* __restrict__ Wm2,
    const float* __restrict__ bm2, float* __restrict__ out)
{
    __shared__ float W1s[128 * 64];
    __shared__ float hs[8 * 128];
    int t = threadIdx.x;
    int nsub = t >> 5, q = t & 31;
    float b1r[2][2], w2r[2][2][2];
    #pragma unroll
    for (int hf = 0; hf < 2; hf++)
        #pragma unroll
        for (int j = 0; j < 2; j++) {
            int c = hf * 64 + q * 2 + j;
            b1r[hf][j] = bm1[c];
            w2r[hf][j][0] = Wm2[c * 2 + 0];
            w2r[hf][j][1] = Wm2[c * 2 + 1];
        }
    float b20 = bm2[0], b21 = bm2[1];
    const int NT = N_WAT / 8;
    for (int tile = blockIdx.x; tile < NT; tile += gridDim.x) {
        __syncthreads();
        for (int i = t; i < 8 * 128; i += 256)
            hs[i] = hh[(N_PRO + tile * 8 + (i >> 7)) * 128 + (i & 127)];
        float p0 = 0.f, p1 = 0.f;
        const float* hrow = &hs[nsub * 128];
        #pragma unroll
        for (int hf = 0; hf < 2; hf++) {
            __syncthreads();
            for (int i = t; i < 128 * 64; i += 256)
                W1s[i] = Wm1[(i >> 6) * 128 + hf * 64 + (i & 63)];
            __syncthreads();
            float a0 = 0.f, a1 = 0.f;
            #pragma unroll 8
            for (int d = 0; d < 128; d++) {
                float hv = hrow[d];
                float2 w = *(const float2*)&W1s[d * 64 + q * 2];
                a0 += hv * w.x;
                a1 += hv * w.y;
            }
            a0 = fmaxf(a0 + b1r[hf][0], 0.f);
            a1 = fmaxf(a1 + b1r[hf][1], 0.f);
            p0 += a0 * w2r[hf][0][0] + a1 * w2r[hf][1][0];
            p1 += a0 * w2r[hf][0][1] + a1 * w2r[hf][1][1];
        }
        #pragma unroll
        for (int mk = 1; mk < 32; mk <<= 1) {
            p0 += __shfl_xor(p0, mk, 64);
            p1 += __shfl_xor(p1, mk, 64);
        }
        if (q == 0) {
            int r = tile * 8 + nsub;
            out[r * 2 + 0] = p0 + b20;
            out[r * 2 + 1] = p1 + b21;
        }
    }
}

// ---------------------------------------------------------------------------
extern "C" void kernel_launch(void* const* d_in, const int* in_sizes, int n_in,
                              void* d_out, int out_size, void* d_ws, size_t ws_size,
                              hipStream_t stream)
{
    const float* ppos   = (const float*)d_in[0];
    const float* wpos   = (const float*)d_in[1];
    const float* pfeat  = (const float*)d_in[2];
    const int*   ei     = (const int*)d_in[3];
    const float* gamma  = (const float*)d_in[4];
    const float* Wf     = (const float*)d_in[5];
    const float* bfv    = (const float*)d_in[6];
    const float* We     = (const float*)d_in[7];
    const float* be     = (const float*)d_in[8];
    const float* W1     = (const float*)d_in[9];
    const float* atts1  = (const float*)d_in[10];
    const float* attd1  = (const float*)d_in[11];
    const float* Wedge1 = (const float*)d_in[12];
    const float* atte1  = (const float*)d_in[13];
    const float* b1     = (const float*)d_in[14];
    const float* W2     = (const float*)d_in[15];
    const float* atts2  = (const float*)d_in[16];
    const float* attd2  = (const float*)d_in[17];
    const float* Wedge2 = (const float*)d_in[18];
    const float* atte2  = (const float*)d_in[19];
    const float* b2     = (const float*)d_in[20];
    const float* Wm1    = (const float*)d_in[21];
    const float* bm1    = (const float*)d_in[22];
    const float* Wm2    = (const float*)d_in[23];
    const float* bm2    = (const float*)d_in[24];
    float* out = (float*)d_out;

    char* ws = (char*)d_ws;
    size_t o = 0;
    auto alloc = [&](size_t bytes) -> char* {
        char* p = ws + o;
        o += (bytes + 255) & ~(size_t)255;
        return p;
    };
    float*  h0      = (float*)alloc((size_t)NN * 32 * 4);
    __half* x16     = (__half*)alloc((size_t)NN * 128 * 2);
    float*  hbuf    = (float*)alloc((size_t)NN * 128 * 4);
    float*  asd     = (float*)alloc((size_t)NN * 8 * 4);
    float*  alpha   = (float*)alloc((size_t)NE * 4 * 4);
    int*    deg     = (int*)alloc((size_t)(NN + 1) * 4);
    int*    offp    = (int*)alloc((size_t)(NN + 1) * 4);
    int*    cur     = (int*)alloc((size_t)NN * 4);
    int*    esrc    = (int*)alloc((size_t)NE * 4);
    int*    edst    = (int*)alloc((size_t)NE * 4);
    int*    part    = (int*)alloc((size_t)NSEG * 4);
    int*    partoff = (int*)alloc((size_t)(128 + 1) * 4);
    float*  smallw  = (float*)alloc(4096);

    hipMemsetAsync(deg, 0, (NN + 1) * 4, stream);
    k_small<<<1, 256, 0, stream>>>(We, be, Wedge1, atte1, Wedge2, atte2, Wf, bfv, smallw);
    k_h0<<<(NN * 32) / 256, 256, 0, stream>>>(pfeat, Wf, bfv, smallw, h0);
    k_count<<<(NE + 255) / 256, 256, 0, stream>>>(ei, deg);
    k_scan1<<<NSEG, 256, 0, stream>>>(deg, offp, cur, part);
    k_scan2<<<1, 128, 0, stream>>>(part, partoff, offp);
    k_scan3<<<NSEG, 256, 0, stream>>>(partoff, offp, cur);
    k_fill<<<(NE + 255) / 256, 256, 0, stream>>>(ei, cur, esrc, edst);
    // layer 1
    k_x<32, 128><<<dim3(NN / 32, 1), 256, 0, stream>>>(h0, W1, atts1, attd1, x16, asd);
    k_alpha<1><<<(NE + 255) / 256, 256, 0, stream>>>(esrc, edst, offp + N_PRO, ppos, wpos, gamma, smallw + 0, smallw + 128, asd, alpha);
    k_agg<0><<<NN / 4, 256, 0, stream>>>(offp, esrc, alpha, x16, b1, hbuf);
    // layer 2 (only water destinations are ever consumed downstream)
    k_x<128, 64><<<dim3(NN / 32, 2), 256, 0, stream>>>(hbuf, W2, atts2, attd2, x16, asd);
    k_alpha<2><<<(NE + 255) / 256, 256, 0, stream>>>(esrc, edst, offp + N_PRO, ppos, wpos, gamma, smallw + 132, smallw + 260, asd, alpha);
    k_agg<1><<<N_WAT / 4, 256, 0, stream>>>(offp, esrc, alpha, x16, b2, hbuf);
    // MLP on water nodes
    k_mlp<<<2048, 256, 0, stream>>>(hbuf, Wm1, bm1, Wm2, bm2, out);
}

// Round 6
// 557.380 us; speedup vs baseline: 1.7704x; 1.0732x over previous
//
#include <hip/hip_runtime.h>
#include <hip/hip_fp16.h>
#include <stdint.h>

#define N_PRO 60000
#define N_WAT 40000
#define NN    100000
#define NNP   100032            // padded to a multiple of 64 for k_x tiles
#define NE    1000000
#define IN_DIM 21
#define HID    32
#define HEADS  4
#define HC     128
#define EDGE_K 32
#define NSEG   ((NN + 1023) / 1024)   // 98 segments for the hierarchical scan

// ---------------------------------------------------------------------------
// K1: tiny fused weights. V_l[d][h] = sum_c Wedge_l[d, h*32+c] * atte_l[h,c]
// U_l[32,4] = We @ V_l ; aeb_l[4] = be . V_l ; h0w[32] = Wf[20,:] + bf
// smallw floats: [0..127]=U1, [128..131]=aeb1, [132..259]=U2, [260..263]=aeb2,
// [264..295]=h0w
// ---------------------------------------------------------------------------
__global__ __launch_bounds__(256) void k_small(
    const float* We, const float* be,
    const float* Wedge1, const float* atte1,
    const float* Wedge2, const float* atte2,
    const float* Wf, const float* bfv, float* smallw)
{
    __shared__ float V[2][128];
    int t = threadIdx.x;
    {
        int l = t >> 7, dh = t & 127, d = dh >> 2, h = dh & 3;
        const float* Wg = l ? Wedge2 : Wedge1;
        const float* ae = l ? atte2 : atte1;
        float s = 0.f;
        for (int c = 0; c < HID; c++)
            s += Wg[d * HC + h * HID + c] * ae[h * HID + c];
        V[l][dh] = s;
    }
    __syncthreads();
    {
        int l = t >> 7, kh = t & 127, k = kh >> 2, h = kh & 3;
        float s = 0.f;
        for (int d = 0; d < 32; d++)
            s += We[k * 32 + d] * V[l][d * 4 + h];
        smallw[(l ? 132 : 0) + kh] = s;
    }
    if (t < 8) {
        int l = t >> 2, h = t & 3;
        float s = 0.f;
        for (int d = 0; d < 32; d++)
            s += be[d] * V[l][d * 4 + h];
        smallw[(l ? 260 : 128) + h] = s;
    }
    if (t >= 32 && t < 64) {
        int c = t - 32;
        smallw[264 + c] = Wf[20 * 32 + c] + bfv[c];
    }
}

// ---------------------------------------------------------------------------
// K2: h0 = feats @ Wf + bf  (water rows are the precomputed constant row)
// ---------------------------------------------------------------------------
__global__ __launch_bounds__(256) void k_h0(
    const float* __restrict__ pf, const float* __restrict__ Wf,
    const float* __restrict__ bfv, const float* __restrict__ smallw,
    float* __restrict__ h0)
{
    __shared__ float Wfs[IN_DIM * 32];
    __shared__ float bfs[32];
    __shared__ float h0w[32];
    int t = threadIdx.x;
    for (int i = t; i < IN_DIM * 32; i += 256) Wfs[i] = Wf[i];
    if (t < 32) { bfs[t] = bfv[t]; h0w[t] = smallw[264 + t]; }
    __syncthreads();
    int id = blockIdx.x * 256 + t;
    int n = id >> 5, c = id & 31;
    if (n >= NNP) return;
    float v;
    if (n < N_PRO) {
        float s = bfs[c];
        for (int k = 0; k < IN_DIM; k++)
            s += pf[n * IN_DIM + k] * Wfs[k * 32 + c];
        v = s;
    } else {
        v = h0w[c];   // also fills the 32 pad rows with a sane value
    }
    h0[n * 32 + c] = v;
}

// ---------------------------------------------------------------------------
// CSR build over dst: count -> hierarchical scan (3 passes) -> fill
// ---------------------------------------------------------------------------
__global__ __launch_bounds__(256) void k_count(const int* ei, int* deg) {
    int e = blockIdx.x * 256 + threadIdx.x;
    if (e >= NE) return;
    int d = ei[NE + e];
    int s = ei[e];
    if ((unsigned)d < (unsigned)NN && (unsigned)s < (unsigned)NN)
        atomicAdd(&deg[d], 1);
}

__global__ __launch_bounds__(256) void k_scan1(
    const int* __restrict__ deg, int* __restrict__ off,
    int* __restrict__ cur, int* __restrict__ part)
{
    __shared__ int s[256];
    int t = threadIdx.x;
    int base = blockIdx.x * 1024 + t * 4;
    int d0 = 0, d1 = 0, d2 = 0, d3 = 0;
    if (base + 3 < NN) {
        int4 v = *(const int4*)&deg[base];
        d0 = v.x; d1 = v.y; d2 = v.z; d3 = v.w;
    } else {
        if (base + 0 < NN) d0 = deg[base + 0];
        if (base + 1 < NN) d1 = deg[base + 1];
        if (base + 2 < NN) d2 = deg[base + 2];
    }
    int tsum = d0 + d1 + d2 + d3;
    s[t] = tsum;
    __syncthreads();
    #pragma unroll
    for (int o = 1; o < 256; o <<= 1) {
        int v = (t >= o) ? s[t - o] : 0;
        __syncthreads();
        s[t] += v;
        __syncthreads();
    }
    int ex = s[t] - tsum;
    if (base + 0 < NN) { int v = ex;                 off[base + 0] = v; cur[base + 0] = v; }
    if (base + 1 < NN) { int v = ex + d0;            off[base + 1] = v; cur[base + 1] = v; }
    if (base + 2 < NN) { int v = ex + d0 + d1;       off[base + 2] = v; cur[base + 2] = v; }
    if (base + 3 < NN) { int v = ex + d0 + d1 + d2;  off[base + 3] = v; cur[base + 3] = v; }
    if (t == 255) part[blockIdx.x] = s[255];
}

__global__ __launch_bounds__(128) void k_scan2(
    const int* __restrict__ part, int* __restrict__ partoff, int* __restrict__ off)
{
    __shared__ int s[128];
    int t = threadIdx.x;
    int v = (t < NSEG) ? part[t] : 0;
    s[t] = v;
    __syncthreads();
    #pragma unroll
    for (int o = 1; o < 128; o <<= 1) {
        int x = (t >= o) ? s[t - o] : 0;
        __syncthreads();
        s[t] += x;
        __syncthreads();
    }
    partoff[t] = s[t] - v;   // exclusive prefix
    if (t == 127) off[NN] = s[127];
}

__global__ __launch_bounds__(256) void k_scan3(
    const int* __restrict__ partoff, int* __restrict__ off, int* __restrict__ cur)
{
    int b = blockIdx.x;
    int add = partoff[b];
    if (add == 0) return;
    int base = b * 1024 + threadIdx.x * 4;
    #pragma unroll
    for (int j = 0; j < 4; j++) {
        int i = base + j;
        if (i < NN) { off[i] += add; cur[i] += add; }
    }
}

__global__ __launch_bounds__(256) void k_fill(const int* ei, int* cur, int* esrc, int* edst) {
    int e = blockIdx.x * 256 + threadIdx.x;
    if (e >= NE) return;
    int d = ei[NE + e];
    int srcn = ei[e];
    if ((unsigned)d >= (unsigned)NN || (unsigned)srcn >= (unsigned)NN) return;
    int p = atomicAdd(&cur[d], 1);
    esrc[p] = srcn;
    edst[p] = d;
}

// ---------------------------------------------------------------------------
// K6 v3: x = h @ W (+ attention logits a_s, a_d). Register-blocked outer
// product: 64-node tile per block; thread = NPT nodes x 4 cols; all LDS
// traffic float4 (ds_read_b128). W staged in <=16 KB d-chunks (L2: 2 halves).
// x stored fp16. L1: <32,128> y=1; L2: <128,64> y=2 (column slab).
// ---------------------------------------------------------------------------
template <int DIN, int COLS>
__global__ __launch_bounds__(256) void k_x(
    const float* __restrict__ h, const float* __restrict__ Wg,
    const float* __restrict__ atts, const float* __restrict__ attd,
    __half* __restrict__ x16, float* __restrict__ asd)
{
    constexpr int G    = COLS / 4;            // col-groups: 32 (L1) / 16 (L2)
    constexpr int NPT  = COLS / 16;           // nodes/thread: 8 (L1) / 4 (L2)
    constexpr int HSTR = DIN + 4;             // padded h row stride
    constexpr int DCH  = (DIN == 32) ? 32 : 64;  // W d-chunk (16 KB both)
    __shared__ float Ws[DCH * COLS];
    __shared__ float hs[64 * HSTR];
    __shared__ float attS[COLS], attD[COLS];
    int t = threadIdx.x;
    int cbase = blockIdx.y * COLS;
    int n0 = blockIdx.x * 64;
    // stage h tile (64 x DIN) as float4
    for (int i4 = t * 4; i4 < 64 * DIN; i4 += 1024) {
        int r = i4 / DIN, c = i4 % DIN;
        *(float4*)&hs[r * HSTR + c] = *(const float4*)&h[(size_t)(n0 + r) * DIN + c];
    }
    if (t < COLS) { attS[t] = atts[cbase + t]; attD[t] = attd[cbase + t]; }
    int cg = t % G, ng = t / G;
    float acc[NPT][4];
    #pragma unroll
    for (int nn = 0; nn < NPT; nn++)
        #pragma unroll
        for (int j = 0; j < 4; j++) acc[nn][j] = 0.f;
    for (int dpass = 0; dpass < DIN; dpass += DCH) {
        __syncthreads();   // hs ready (1st pass) / prior Ws consumed (2nd)
        for (int i = t; i < DCH * COLS; i += 256) {
            int d = i / COLS, c = i % COLS;
            Ws[i] = Wg[(size_t)(dpass + d) * 128 + cbase + c];
        }
        __syncthreads();
        for (int d0 = 0; d0 < DCH; d0 += 4) {
            float hreg[NPT][4];
            #pragma unroll
            for (int nn = 0; nn < NPT; nn++) {
                float4 hv = *(const float4*)&hs[(ng * NPT + nn) * HSTR + dpass + d0];
                hreg[nn][0] = hv.x; hreg[nn][1] = hv.y;
                hreg[nn][2] = hv.z; hreg[nn][3] = hv.w;
            }
            #pragma unroll
            for (int dd = 0; dd < 4; dd++) {
                float4 wv = *(const float4*)&Ws[(d0 + dd) * COLS + cg * 4];
                #pragma unroll
                for (int nn = 0; nn < NPT; nn++) {
                    float hv = hreg[nn][dd];
                    acc[nn][0] += hv * wv.x;
                    acc[nn][1] += hv * wv.y;
                    acc[nn][2] += hv * wv.z;
                    acc[nn][3] += hv * wv.w;
                }
            }
        }
    }
    // epilogue: fp16 x store + attention logit reduction
    int hh = (cbase + cg * 4) >> 5;
    #pragma unroll
    for (int nn = 0; nn < NPT; nn++) {
        int n = n0 + ng * NPT + nn;
        __half2 ha = __floats2half2_rn(acc[nn][0], acc[nn][1]);
        __half2 hb = __floats2half2_rn(acc[nn][2], acc[nn][3]);
        uint2 pk;
        pk.x = *(unsigned int*)&ha;
        pk.y = *(unsigned int*)&hb;
        *(uint2*)&x16[(size_t)n * 128 + cbase + cg * 4] = pk;
        float ps = acc[nn][0] * attS[cg * 4]     + acc[nn][1] * attS[cg * 4 + 1]
                 + acc[nn][2] * attS[cg * 4 + 2] + acc[nn][3] * attS[cg * 4 + 3];
        float pd = acc[nn][0] * attD[cg * 4]     + acc[nn][1] * attD[cg * 4 + 1]
                 + acc[nn][2] * attD[cg * 4 + 2] + acc[nn][3] * attD[cg * 4 + 3];
        // reduce across the 8 col-groups spanning one head (lanes cg&7)
        ps += __shfl_xor(ps, 1, 64); pd += __shfl_xor(pd, 1, 64);
        ps += __shfl_xor(ps, 2, 64); pd += __shfl_xor(pd, 2, 64);
        ps += __shfl_xor(ps, 4, 64); pd += __shfl_xor(pd, 4, 64);
        if ((cg & 7) == 0) {
            asd[(size_t)n * 8 + hh] = ps;
            asd[(size_t)n * 8 + 4 + hh] = pd;
        }
    }
}

// ---------------------------------------------------------------------------
// K7: attention logits in CSR slot order. LAYER==2 skips protein-dst slots.
// ---------------------------------------------------------------------------
template <int LAYER>
__global__ __launch_bounds__(256) void k_alpha(
    const int* __restrict__ esrc, const int* __restrict__ edst,
    const int* __restrict__ wlim,
    const float* __restrict__ ppos, const float* __restrict__ wpos,
    const float* __restrict__ gamma,
    const float* __restrict__ U, const float* __restrict__ aeb,
    const float* __restrict__ asd, float* __restrict__ alpha)
{
    __shared__ float Us[128];
    __shared__ float aebs[4];
    int t = threadIdx.x;
    if (t < 128) Us[t] = U[t];
    if (t < 4) aebs[t] = aeb[t];
    __syncthreads();
    int i = blockIdx.x * 256 + t;
    if (i >= NE) return;
    if (LAYER == 2 && i < wlim[0]) return;
    int sn = esrc[i], dn = edst[i];
    const float* ps = (sn < N_PRO) ? &ppos[sn * 3] : &wpos[(sn - N_PRO) * 3];
    const float* pd = (dn < N_PRO) ? &ppos[dn * 3] : &wpos[(dn - N_PRO) * 3];
    float dx = pd[0] - ps[0];
    float dy = pd[1] - ps[1];
    float dz = pd[2] - ps[2];
    float dist = sqrtf(dx * dx + dy * dy + dz * dz);
    float g = gamma[0];
    float ae0 = aebs[0], ae1 = aebs[1], ae2 = aebs[2], ae3 = aebs[3];
    const float step = 5.0f / 31.0f;
    #pragma unroll
    for (int k = 0; k < EDGE_K; k++) {
        float tt = dist - (float)k * step;
        float r = __expf(-g * tt * tt);
        ae0 += r * Us[k * 4 + 0];
        ae1 += r * Us[k * 4 + 1];
        ae2 += r * Us[k * 4 + 2];
        ae3 += r * Us[k * 4 + 3];
    }
    float4 as4 = *(const float4*)&asd[(size_t)sn * 8];
    float4 ad4 = *(const float4*)&asd[(size_t)dn * 8 + 4];
    float v0 = as4.x + ad4.x + ae0;
    float v1 = as4.y + ad4.y + ae1;
    float v2 = as4.z + ad4.z + ae2;
    float v3 = as4.w + ad4.w + ae3;
    v0 = v0 >= 0.f ? v0 : 0.2f * v0;
    v1 = v1 >= 0.f ? v1 : 0.2f * v1;
    v2 = v2 >= 0.f ? v2 : 0.2f * v2;
    v3 = v3 >= 0.f ? v3 : 0.2f * v3;
    *(float4*)&alpha[(size_t)i * 4] = make_float4(v0, v1, v2, v3);
}

// ---------------------------------------------------------------------------
// K8 v2: per-dst-node softmax aggregation, two-pass exact max (matches the
// reference's segment_max formulation). Pass 1: max over alpha (sequential,
// 4 independent chains, no gather). Pass 2: exp(a-m), unroll x2 with
// independent accumulators (two x-gathers in flight, no serial rescale).
// One wave per node; lane l owns channels 2l,2l+1 (head = l/16).
// ---------------------------------------------------------------------------
template <int WATER_ONLY>
__global__ __launch_bounds__(256) void k_agg(
    const int* __restrict__ off, const int* __restrict__ esrc,
    const float* __restrict__ alpha, const __half* __restrict__ x16,
    const float* __restrict__ bias, float* __restrict__ hout)
{
    int t = threadIdx.x;
    int w = t >> 6, lane = t & 63;
    int n = (WATER_ONLY ? N_PRO : 0) + blockIdx.x * 4 + w;
    if (n >= NN) return;
    int h = lane >> 4;
    int beg = off[n], end = off[n + 1];
    // pass 1: exact max
    float m;
    {
        float m0 = -INFINITY, m1 = -INFINITY, m2 = -INFINITY, m3 = -INFINITY;
        int i = beg;
        for (; i + 3 < end; i += 4) {
            m0 = fmaxf(m0, alpha[(size_t)(i + 0) * 4 + h]);
            m1 = fmaxf(m1, alpha[(size_t)(i + 1) * 4 + h]);
            m2 = fmaxf(m2, alpha[(size_t)(i + 2) * 4 + h]);
            m3 = fmaxf(m3, alpha[(size_t)(i + 3) * 4 + h]);
        }
        for (; i < end; i++) m0 = fmaxf(m0, alpha[(size_t)i * 4 + h]);
        m = fmaxf(fmaxf(m0, m1), fmaxf(m2, m3));
    }
    // pass 2: accumulate
    float lsum0 = 0.f, lsum1 = 0.f;
    float a00 = 0.f, a01 = 0.f, a10 = 0.f, a11 = 0.f;
    const __half2* x2 = (const __half2*)x16;
    int i = beg;
    for (; i + 1 < end; i += 2) {
        int s0 = esrc[i], s1 = esrc[i + 1];
        float al0 = alpha[(size_t)i * 4 + h];
        float al1 = alpha[(size_t)(i + 1) * 4 + h];
        float2 xv0 = __half22float2(x2[(size_t)s0 * 64 + lane]);
        float2 xv1 = __half22float2(x2[(size_t)s1 * 64 + lane]);
        float e0 = __expf(al0 - m), e1 = __expf(al1 - m);
        lsum0 += e0; lsum1 += e1;
        a00 += e0 * xv0.x; a01 += e0 * xv0.y;
        a10 += e1 * xv1.x; a11 += e1 * xv1.y;
    }
    if (i < end) {
        int s0 = esrc[i];
        float al0 = alpha[(size_t)i * 4 + h];
        float2 xv0 = __half22float2(x2[(size_t)s0 * 64 + lane]);
        float e0 = __expf(al0 - m);
        lsum0 += e0;
        a00 += e0 * xv0.x; a01 += e0 * xv0.y;
    }
    float lsum = lsum0 + lsum1;
    float acc0 = a00 + a10, acc1 = a01 + a11;
    float inv = 1.0f / (lsum + 1e-16f);
    float2 bb = *(const float2*)&bias[lane * 2];
    float o0 = acc0 * inv + bb.x;
    float o1 = acc1 * inv + bb.y;
    o0 = o0 > 0.f ? o0 : __expf(o0) - 1.0f;
    o1 = o1 > 0.f ? o1 : __expf(o1) - 1.0f;
    ((float2*)&hout[(size_t)n * 128])[lane] = make_float2(o0, o1);
}

// ---------------------------------------------------------------------------
// K9: water MLP: out = relu(h@Wm1+bm1)@Wm2 + bm2. Wm1 staged in LDS in two
// 64-column halves per tile.
// ---------------------------------------------------------------------------
__global__ __launch_bounds__(256) void k_mlp(
    const float* __restrict__ hh, const float* __restrict__ Wm1,
    const float* __restrict__ bm1, const float* __restrict__ Wm2,
    const float* __restrict__ bm2, float* __restrict__ out)
{
    __shared__ float W1s[128 * 64];
    __shared__ float hs[8 * 128];
    int t = threadIdx.x;
    int nsub = t >> 5, q = t & 31;
    float b1r[2][2], w2r[2][2][2];
    #pragma unroll
    for (int hf = 0; hf < 2; hf++)
        #pragma unroll
        for (int j = 0; j < 2; j++) {
            int c = hf * 64 + q * 2 + j;
            b1r[hf][j] = bm1[c];
            w2r[hf][j][0] = Wm2[c * 2 + 0];
            w2r[hf][j][1] = Wm2[c * 2 + 1];
        }
    float b20 = bm2[0], b21 = bm2[1];
    const int NT = N_WAT / 8;
    for (int tile = blockIdx.x; tile < NT; tile += gridDim.x) {
        __syncthreads();
        for (int i = t; i < 8 * 128; i += 256)
            hs[i] = hh[(size_t)(N_PRO + tile * 8 + (i >> 7)) * 128 + (i & 127)];
        float p0 = 0.f, p1 = 0.f;
        const float* hrow = &hs[nsub * 128];
        #pragma unroll
        for (int hf = 0; hf < 2; hf++) {
            __syncthreads();
            for (int i = t; i < 128 * 64; i += 256)
                W1s[i] = Wm1[(size_t)(i >> 6) * 128 + hf * 64 + (i & 63)];
            __syncthreads();
            float a0 = 0.f, a1 = 0.f;
            #pragma unroll 8
            for (int d = 0; d < 128; d++) {
                float hv = hrow[d];
                float2 w = *(const float2*)&W1s[d * 64 + q * 2];
                a0 += hv * w.x;
                a1 += hv * w.y;
            }
            a0 = fmaxf(a0 + b1r[hf][0], 0.f);
            a1 = fmaxf(a1 + b1r[hf][1], 0.f);
            p0 += a0 * w2r[hf][0][0] + a1 * w2r[hf][1][0];
            p1 += a0 * w2r[hf][0][1] + a1 * w2r[hf][1][1];
        }
        #pragma unroll
        for (int mk = 1; mk < 32; mk <<= 1) {
            p0 += __shfl_xor(p0, mk, 64);
            p1 += __shfl_xor(p1, mk, 64);
        }
        if (q == 0) {
            int r = tile * 8 + nsub;
            out[r * 2 + 0] = p0 + b20;
            out[r * 2 + 1] = p1 + b21;
        }
    }
}

// ---------------------------------------------------------------------------
extern "C" void kernel_launch(void* const* d_in, const int* in_sizes, int n_in,
                              void* d_out, int out_size, void* d_ws, size_t ws_size,
                              hipStream_t stream)
{
    const float* ppos   = (const float*)d_in[0];
    const float* wpos   = (const float*)d_in[1];
    const float* pfeat  = (const float*)d_in[2];
    const int*   ei     = (const int*)d_in[3];
    const float* gamma  = (const float*)d_in[4];
    const float* Wf     = (const float*)d_in[5];
    const float* bfv    = (const float*)d_in[6];
    const float* We     = (const float*)d_in[7];
    const float* be     = (const float*)d_in[8];
    const float* W1     = (const float*)d_in[9];
    const float* atts1  = (const float*)d_in[10];
    const float* attd1  = (const float*)d_in[11];
    const float* Wedge1 = (const float*)d_in[12];
    const float* atte1  = (const float*)d_in[13];
    const float* b1     = (const float*)d_in[14];
    const float* W2     = (const float*)d_in[15];
    const float* atts2  = (const float*)d_in[16];
    const float* attd2  = (const float*)d_in[17];
    const float* Wedge2 = (const float*)d_in[18];
    const float* atte2  = (const float*)d_in[19];
    const float* b2     = (const float*)d_in[20];
    const float* Wm1    = (const float*)d_in[21];
    const float* bm1    = (const float*)d_in[22];
    const float* Wm2    = (const float*)d_in[23];
    const float* bm2    = (const float*)d_in[24];
    float* out = (float*)d_out;

    char* ws = (char*)d_ws;
    size_t o = 0;
    auto alloc = [&](size_t bytes) -> char* {
        char* p = ws + o;
        o += (bytes + 255) & ~(size_t)255;
        return p;
    };
    float*  h0      = (float*)alloc((size_t)NNP * 32 * 4);
    __half* x16     = (__half*)alloc((size_t)NNP * 128 * 2);
    float*  hbuf    = (float*)alloc((size_t)NNP * 128 * 4);
    float*  asd     = (float*)alloc((size_t)NNP * 8 * 4);
    float*  alpha   = (float*)alloc((size_t)NE * 4 * 4);
    int*    deg     = (int*)alloc((size_t)(NN + 1) * 4);
    int*    offp    = (int*)alloc((size_t)(NN + 1) * 4);
    int*    cur     = (int*)alloc((size_t)NN * 4);
    int*    esrc    = (int*)alloc((size_t)NE * 4);
    int*    edst    = (int*)alloc((size_t)NE * 4);
    int*    part    = (int*)alloc((size_t)NSEG * 4);
    int*    partoff = (int*)alloc((size_t)(128 + 1) * 4);
    float*  smallw  = (float*)alloc(4096);

    hipMemsetAsync(deg, 0, (NN + 1) * 4, stream);
    k_small<<<1, 256, 0, stream>>>(We, be, Wedge1, atte1, Wedge2, atte2, Wf, bfv, smallw);
    k_h0<<<(NNP * 32) / 256, 256, 0, stream>>>(pfeat, Wf, bfv, smallw, h0);
    k_count<<<(NE + 255) / 256, 256, 0, stream>>>(ei, deg);
    k_scan1<<<NSEG, 256, 0, stream>>>(deg, offp, cur, part);
    k_scan2<<<1, 128, 0, stream>>>(part, partoff, offp);
    k_scan3<<<NSEG, 256, 0, stream>>>(partoff, offp, cur);
    k_fill<<<(NE + 255) / 256, 256, 0, stream>>>(ei, cur, esrc, edst);
    // layer 1
    k_x<32, 128><<<dim3(NNP / 64, 1), 256, 0, stream>>>(h0, W1, atts1, attd1, x16, asd);
    k_alpha<1><<<(NE + 255) / 256, 256, 0, stream>>>(esrc, edst, offp + N_PRO, ppos, wpos, gamma, smallw + 0, smallw + 128, asd, alpha);
    k_agg<0><<<NN / 4, 256, 0, stream>>>(offp, esrc, alpha, x16, b1, hbuf);
    // layer 2 (only water destinations are ever consumed downstream)
    k_x<128, 64><<<dim3(NNP / 64, 2), 256, 0, stream>>>(hbuf, W2, atts2, attd2, x16, asd);
    k_alpha<2><<<(NE + 255) / 256, 256, 0, stream>>>(esrc, edst, offp + N_PRO, ppos, wpos, gamma, smallw + 132, smallw + 260, asd, alpha);
    k_agg<1><<<N_WAT / 4, 256, 0, stream>>>(offp, esrc, alpha, x16, b2, hbuf);
    // MLP on water nodes
    k_mlp<<<2048, 256, 0, stream>>>(hbuf, Wm1, bm1, Wm2, bm2, out);
}

// Round 7
// 512.028 us; speedup vs baseline: 1.9272x; 1.0886x over previous
//
#include <hip/hip_runtime.h>
#include <hip/hip_fp16.h>
#include <stdint.h>

#define N_PRO 60000
#define N_WAT 40000
#define NN    100000
#define NNP   100032            // padded to a multiple of 64 for k_x tiles
#define NE    1000000
#define IN_DIM 21
#define HID    32
#define HEADS  4
#define HC     128
#define EDGE_K 32
#define NSEG   ((NN + 1023) / 1024)   // 98 segments for the hierarchical scan

// ---------------------------------------------------------------------------
// K1: tiny fused weights. V_l[d][h] = sum_c Wedge_l[d, h*32+c] * atte_l[h,c]
// U_l[32,4] = We @ V_l ; aeb_l[4] = be . V_l ; h0w[32] = Wf[20,:] + bf
// smallw floats: [0..127]=U1, [128..131]=aeb1, [132..259]=U2, [260..263]=aeb2,
// [264..295]=h0w
// ---------------------------------------------------------------------------
__global__ __launch_bounds__(256) void k_small(
    const float* We, const float* be,
    const float* Wedge1, const float* atte1,
    const float* Wedge2, const float* atte2,
    const float* Wf, const float* bfv, float* smallw)
{
    __shared__ float V[2][128];
    int t = threadIdx.x;
    {
        int l = t >> 7, dh = t & 127, d = dh >> 2, h = dh & 3;
        const float* Wg = l ? Wedge2 : Wedge1;
        const float* ae = l ? atte2 : atte1;
        float s = 0.f;
        for (int c = 0; c < HID; c++)
            s += Wg[d * HC + h * HID + c] * ae[h * HID + c];
        V[l][dh] = s;
    }
    __syncthreads();
    {
        int l = t >> 7, kh = t & 127, k = kh >> 2, h = kh & 3;
        float s = 0.f;
        for (int d = 0; d < 32; d++)
            s += We[k * 32 + d] * V[l][d * 4 + h];
        smallw[(l ? 132 : 0) + kh] = s;
    }
    if (t < 8) {
        int l = t >> 2, h = t & 3;
        float s = 0.f;
        for (int d = 0; d < 32; d++)
            s += be[d] * V[l][d * 4 + h];
        smallw[(l ? 260 : 128) + h] = s;
    }
    if (t >= 32 && t < 64) {
        int c = t - 32;
        smallw[264 + c] = Wf[20 * 32 + c] + bfv[c];
    }
}

// ---------------------------------------------------------------------------
// K2: h0 = feats @ Wf + bf  (fp16 output; water rows are a constant row)
// ---------------------------------------------------------------------------
__global__ __launch_bounds__(256) void k_h0(
    const float* __restrict__ pf, const float* __restrict__ Wf,
    const float* __restrict__ bfv, const float* __restrict__ smallw,
    __half* __restrict__ h0)
{
    __shared__ float Wfs[IN_DIM * 32];
    __shared__ float bfs[32];
    __shared__ float h0w[32];
    int t = threadIdx.x;
    for (int i = t; i < IN_DIM * 32; i += 256) Wfs[i] = Wf[i];
    if (t < 32) { bfs[t] = bfv[t]; h0w[t] = smallw[264 + t]; }
    __syncthreads();
    int id = blockIdx.x * 256 + t;
    int n = id >> 5, c = id & 31;
    if (n >= NNP) return;
    float v;
    if (n < N_PRO) {
        float s = bfs[c];
        for (int k = 0; k < IN_DIM; k++)
            s += pf[n * IN_DIM + k] * Wfs[k * 32 + c];
        v = s;
    } else {
        v = h0w[c];   // also fills the 32 pad rows with a sane value
    }
    h0[(size_t)n * 32 + c] = __float2half(v);
}

// ---------------------------------------------------------------------------
// CSR build over dst: count -> hierarchical scan (3 passes) -> fill
// ---------------------------------------------------------------------------
__global__ __launch_bounds__(256) void k_count(const int* ei, int* deg) {
    int e = blockIdx.x * 256 + threadIdx.x;
    if (e >= NE) return;
    int d = ei[NE + e];
    int s = ei[e];
    if ((unsigned)d < (unsigned)NN && (unsigned)s < (unsigned)NN)
        atomicAdd(&deg[d], 1);
}

__global__ __launch_bounds__(256) void k_scan1(
    const int* __restrict__ deg, int* __restrict__ off,
    int* __restrict__ cur, int* __restrict__ part)
{
    __shared__ int s[256];
    int t = threadIdx.x;
    int base = blockIdx.x * 1024 + t * 4;
    int d0 = 0, d1 = 0, d2 = 0, d3 = 0;
    if (base + 3 < NN) {
        int4 v = *(const int4*)&deg[base];
        d0 = v.x; d1 = v.y; d2 = v.z; d3 = v.w;
    } else {
        if (base + 0 < NN) d0 = deg[base + 0];
        if (base + 1 < NN) d1 = deg[base + 1];
        if (base + 2 < NN) d2 = deg[base + 2];
    }
    int tsum = d0 + d1 + d2 + d3;
    s[t] = tsum;
    __syncthreads();
    #pragma unroll
    for (int o = 1; o < 256; o <<= 1) {
        int v = (t >= o) ? s[t - o] : 0;
        __syncthreads();
        s[t] += v;
        __syncthreads();
    }
    int ex = s[t] - tsum;
    if (base + 0 < NN) { int v = ex;                 off[base + 0] = v; cur[base + 0] = v; }
    if (base + 1 < NN) { int v = ex + d0;            off[base + 1] = v; cur[base + 1] = v; }
    if (base + 2 < NN) { int v = ex + d0 + d1;       off[base + 2] = v; cur[base + 2] = v; }
    if (base + 3 < NN) { int v = ex + d0 + d1 + d2;  off[base + 3] = v; cur[base + 3] = v; }
    if (t == 255) part[blockIdx.x] = s[255];
}

__global__ __launch_bounds__(128) void k_scan2(
    const int* __restrict__ part, int* __restrict__ partoff, int* __restrict__ off)
{
    __shared__ int s[128];
    int t = threadIdx.x;
    int v = (t < NSEG) ? part[t] : 0;
    s[t] = v;
    __syncthreads();
    #pragma unroll
    for (int o = 1; o < 128; o <<= 1) {
        int x = (t >= o) ? s[t - o] : 0;
        __syncthreads();
        s[t] += x;
        __syncthreads();
    }
    partoff[t] = s[t] - v;   // exclusive prefix
    if (t == 127) off[NN] = s[127];
}

__global__ __launch_bounds__(256) void k_scan3(
    const int* __restrict__ partoff, int* __restrict__ off, int* __restrict__ cur)
{
    int b = blockIdx.x;
    int add = partoff[b];
    if (add == 0) return;
    int base = b * 1024 + threadIdx.x * 4;
    #pragma unroll
    for (int j = 0; j < 4; j++) {
        int i = base + j;
        if (i < NN) { off[i] += add; cur[i] += add; }
    }
}

// fill CSR: packed {src,dst} record + per-slot distance (layer-invariant,
// computed exactly once here; both k_alpha passes then read it sequentially)
__global__ __launch_bounds__(256) void k_fill(
    const int* __restrict__ ei, int* __restrict__ cur,
    int2* __restrict__ e2, float* __restrict__ dist,
    const float* __restrict__ ppos, const float* __restrict__ wpos)
{
    int e = blockIdx.x * 256 + threadIdx.x;
    if (e >= NE) return;
    int d = ei[NE + e];
    int s = ei[e];
    if ((unsigned)d >= (unsigned)NN || (unsigned)s >= (unsigned)NN) return;
    const float* ps = (s < N_PRO) ? &ppos[s * 3] : &wpos[(s - N_PRO) * 3];
    const float* pd = (d < N_PRO) ? &ppos[d * 3] : &wpos[(d - N_PRO) * 3];
    float dx = pd[0] - ps[0];
    float dy = pd[1] - ps[1];
    float dz = pd[2] - ps[2];
    float dd = sqrtf(dx * dx + dy * dy + dz * dz);
    int p = atomicAdd(&cur[d], 1);
    e2[p] = make_int2(s, d);
    dist[p] = dd;
}

// ---------------------------------------------------------------------------
// K6: x = h @ W (+ attention logits a_s, a_d). h input fp16, staged to LDS as
// fp32. Register-blocked outer product, 64-node tile, all-float4 LDS traffic.
// ---------------------------------------------------------------------------
template <int DIN, int COLS>
__global__ __launch_bounds__(256) void k_x(
    const __half* __restrict__ h, const float* __restrict__ Wg,
    const float* __restrict__ atts, const float* __restrict__ attd,
    __half* __restrict__ x16, float* __restrict__ asd)
{
    constexpr int G    = COLS / 4;            // col-groups: 32 (L1) / 16 (L2)
    constexpr int NPT  = COLS / 16;           // nodes/thread: 8 (L1) / 4 (L2)
    constexpr int HSTR = DIN + 4;             // padded h row stride
    constexpr int DCH  = (DIN == 32) ? 32 : 64;  // W d-chunk (16 KB both)
    __shared__ float Ws[DCH * COLS];
    __shared__ float hs[64 * HSTR];
    __shared__ float attS[COLS], attD[COLS];
    int t = threadIdx.x;
    int cbase = blockIdx.y * COLS;
    int n0 = blockIdx.x * 64;
    // stage h tile (64 x DIN fp16 -> fp32 LDS), 8 halves per step
    for (int i8 = t * 8; i8 < 64 * DIN; i8 += 2048) {
        int r = i8 / DIN, c = i8 % DIN;
        uint4 raw = *(const uint4*)&h[(size_t)(n0 + r) * DIN + c];
        const __half2* hp = (const __half2*)&raw;
        float2 f0 = __half22float2(hp[0]);
        float2 f1 = __half22float2(hp[1]);
        float2 f2 = __half22float2(hp[2]);
        float2 f3 = __half22float2(hp[3]);
        *(float4*)&hs[r * HSTR + c]     = make_float4(f0.x, f0.y, f1.x, f1.y);
        *(float4*)&hs[r * HSTR + c + 4] = make_float4(f2.x, f2.y, f3.x, f3.y);
    }
    if (t < COLS) { attS[t] = atts[cbase + t]; attD[t] = attd[cbase + t]; }
    int cg = t % G, ng = t / G;
    float acc[NPT][4];
    #pragma unroll
    for (int nn = 0; nn < NPT; nn++)
        #pragma unroll
        for (int j = 0; j < 4; j++) acc[nn][j] = 0.f;
    for (int dpass = 0; dpass < DIN; dpass += DCH) {
        __syncthreads();   // hs ready (1st pass) / prior Ws consumed (2nd)
        for (int i = t; i < DCH * COLS; i += 256) {
            int d = i / COLS, c = i % COLS;
            Ws[i] = Wg[(size_t)(dpass + d) * 128 + cbase + c];
        }
        __syncthreads();
        for (int d0 = 0; d0 < DCH; d0 += 4) {
            float hreg[NPT][4];
            #pragma unroll
            for (int nn = 0; nn < NPT; nn++) {
                float4 hv = *(const float4*)&hs[(ng * NPT + nn) * HSTR + dpass + d0];
                hreg[nn][0] = hv.x; hreg[nn][1] = hv.y;
                hreg[nn][2] = hv.z; hreg[nn][3] = hv.w;
            }
            #pragma unroll
            for (int dd = 0; dd < 4; dd++) {
                float4 wv = *(const float4*)&Ws[(d0 + dd) * COLS + cg * 4];
                #pragma unroll
                for (int nn = 0; nn < NPT; nn++) {
                    float hv = hreg[nn][dd];
                    acc[nn][0] += hv * wv.x;
                    acc[nn][1] += hv * wv.y;
                    acc[nn][2] += hv * wv.z;
                    acc[nn][3] += hv * wv.w;
                }
            }
        }
    }
    // epilogue: fp16 x store + attention logit reduction
    int hh = (cbase + cg * 4) >> 5;
    #pragma unroll
    for (int nn = 0; nn < NPT; nn++) {
        int n = n0 + ng * NPT + nn;
        __half2 ha = __floats2half2_rn(acc[nn][0], acc[nn][1]);
        __half2 hb = __floats2half2_rn(acc[nn][2], acc[nn][3]);
        uint2 pk;
        pk.x = *(unsigned int*)&ha;
        pk.y = *(unsigned int*)&hb;
        *(uint2*)&x16[(size_t)n * 128 + cbase + cg * 4] = pk;
        float ps = acc[nn][0] * attS[cg * 4]     + acc[nn][1] * attS[cg * 4 + 1]
                 + acc[nn][2] * attS[cg * 4 + 2] + acc[nn][3] * attS[cg * 4 + 3];
        float pd = acc[nn][0] * attD[cg * 4]     + acc[nn][1] * attD[cg * 4 + 1]
                 + acc[nn][2] * attD[cg * 4 + 2] + acc[nn][3] * attD[cg * 4 + 3];
        ps += __shfl_xor(ps, 1, 64); pd += __shfl_xor(pd, 1, 64);
        ps += __shfl_xor(ps, 2, 64); pd += __shfl_xor(pd, 2, 64);
        ps += __shfl_xor(ps, 4, 64); pd += __shfl_xor(pd, 4, 64);
        if ((cg & 7) == 0) {
            asd[(size_t)n * 8 + hh] = ps;
            asd[(size_t)n * 8 + 4 + hh] = pd;
        }
    }
}

// ---------------------------------------------------------------------------
// K7: attention logits in CSR slot order; dist precomputed (no pos gathers).
// LAYER==2 skips protein-dst slots.
// ---------------------------------------------------------------------------
template <int LAYER>
__global__ __launch_bounds__(256) void k_alpha(
    const int2* __restrict__ e2, const float* __restrict__ dist,
    const int* __restrict__ wlim, const float* __restrict__ gamma,
    const float* __restrict__ U, const float* __restrict__ aeb,
    const float* __restrict__ asd, float* __restrict__ alpha)
{
    __shared__ float Us[128];
    __shared__ float aebs[4];
    int t = threadIdx.x;
    if (t < 128) Us[t] = U[t];
    if (t < 4) aebs[t] = aeb[t];
    __syncthreads();
    int i = blockIdx.x * 256 + t;
    if (i >= NE) return;
    if (LAYER == 2 && i < wlim[0]) return;
    int2 sd = e2[i];
    float dd = dist[i];
    float g = gamma[0];
    float ae0 = aebs[0], ae1 = aebs[1], ae2 = aebs[2], ae3 = aebs[3];
    const float step = 5.0f / 31.0f;
    #pragma unroll
    for (int k = 0; k < EDGE_K; k++) {
        float tt = dd - (float)k * step;
        float r = __expf(-g * tt * tt);
        ae0 += r * Us[k * 4 + 0];
        ae1 += r * Us[k * 4 + 1];
        ae2 += r * Us[k * 4 + 2];
        ae3 += r * Us[k * 4 + 3];
    }
    float4 as4 = *(const float4*)&asd[(size_t)sd.x * 8];
    float4 ad4 = *(const float4*)&asd[(size_t)sd.y * 8 + 4];
    float v0 = as4.x + ad4.x + ae0;
    float v1 = as4.y + ad4.y + ae1;
    float v2 = as4.z + ad4.z + ae2;
    float v3 = as4.w + ad4.w + ae3;
    v0 = v0 >= 0.f ? v0 : 0.2f * v0;
    v1 = v1 >= 0.f ? v1 : 0.2f * v1;
    v2 = v2 >= 0.f ? v2 : 0.2f * v2;
    v3 = v3 >= 0.f ? v3 : 0.2f * v3;
    *(float4*)&alpha[(size_t)i * 4] = make_float4(v0, v1, v2, v3);
}

// ---------------------------------------------------------------------------
// K8 v3: single-pass softmax aggregation WITHOUT max subtraction — softmax is
// shift-invariant, logits here are O(+-15) so exp() is safe in fp32, and the
// result matches the reference's max-subtracted form to fp rounding.
// One wave per node; lane l owns channels 2l,2l+1 (head = l/16); x fp16;
// output written fp16. Unroll x2, independent accumulators.
// ---------------------------------------------------------------------------
template <int WATER_ONLY>
__global__ __launch_bounds__(256) void k_agg(
    const int* __restrict__ off, const int2* __restrict__ e2,
    const float* __restrict__ alpha, const __half* __restrict__ x16,
    const float* __restrict__ bias, __half* __restrict__ hout)
{
    int t = threadIdx.x;
    int w = t >> 6, lane = t & 63;
    int n = (WATER_ONLY ? N_PRO : 0) + blockIdx.x * 4 + w;
    if (n >= NN) return;
    int h = lane >> 4;
    int beg = off[n], end = off[n + 1];
    float lsum0 = 0.f, lsum1 = 0.f;
    float a00 = 0.f, a01 = 0.f, a10 = 0.f, a11 = 0.f;
    const __half2* x2 = (const __half2*)x16;
    int i = beg;
    for (; i + 1 < end; i += 2) {
        int s0 = e2[i].x, s1 = e2[i + 1].x;
        float al0 = alpha[(unsigned)i * 4u + h];
        float al1 = alpha[(unsigned)(i + 1) * 4u + h];
        float2 xv0 = __half22float2(x2[(unsigned)s0 * 64u + lane]);
        float2 xv1 = __half22float2(x2[(unsigned)s1 * 64u + lane]);
        float e0 = __expf(al0), e1 = __expf(al1);
        lsum0 += e0; lsum1 += e1;
        a00 += e0 * xv0.x; a01 += e0 * xv0.y;
        a10 += e1 * xv1.x; a11 += e1 * xv1.y;
    }
    if (i < end) {
        int s0 = e2[i].x;
        float al0 = alpha[(unsigned)i * 4u + h];
        float2 xv0 = __half22float2(x2[(unsigned)s0 * 64u + lane]);
        float e0 = __expf(al0);
        lsum0 += e0;
        a00 += e0 * xv0.x; a01 += e0 * xv0.y;
    }
    float lsum = lsum0 + lsum1;
    float acc0 = a00 + a10, acc1 = a01 + a11;
    float inv = 1.0f / (lsum + 1e-16f);
    float2 bb = *(const float2*)&bias[lane * 2];
    float o0 = acc0 * inv + bb.x;
    float o1 = acc1 * inv + bb.y;
    o0 = o0 > 0.f ? o0 : __expf(o0) - 1.0f;
    o1 = o1 > 0.f ? o1 : __expf(o1) - 1.0f;
    *(__half2*)&hout[(size_t)n * 128 + lane * 2] = __floats2half2_rn(o0, o1);
}

// ---------------------------------------------------------------------------
// K9: water MLP: out = relu(h@Wm1+bm1)@Wm2 + bm2. h input fp16; Wm1 staged
// in LDS in two 64-column halves per tile.
// ---------------------------------------------------------------------------
__global__ __launch_bounds__(256) void k_mlp(
    const __half* __restrict__ hh, const float* __restrict__ Wm1,
    const float* __restrict__ bm1, const float* __restrict__ Wm2,
    const float* __restrict__ bm2, float* __restrict__ out)
{
    __shared__ float W1s[128 * 64];
    __shared__ float hs[8 * 128];
    int t = threadIdx.x;
    int nsub = t >> 5, q = t & 31;
    float b1r[2][2], w2r[2][2][2];
    #pragma unroll
    for (int hf = 0; hf < 2; hf++)
        #pragma unroll
        for (int j = 0; j < 2; j++) {
            int c = hf * 64 + q * 2 + j;
            b1r[hf][j] = bm1[c];
            w2r[hf][j][0] = Wm2[c * 2 + 0];
            w2r[hf][j][1] = Wm2[c * 2 + 1];
        }
    float b20 = bm2[0], b21 = bm2[1];
    const int NT = N_WAT / 8;
    for (int tile = blockIdx.x; tile < NT; tile += gridDim.x) {
        __syncthreads();
        for (int i8 = t * 8; i8 < 8 * 128; i8 += 2048) {
            int r = i8 >> 7, c = i8 & 127;
            uint4 raw = *(const uint4*)&hh[(size_t)(N_PRO + tile * 8 + r) * 128 + c];
            const __half2* hp = (const __half2*)&raw;
            float2 f0 = __half22float2(hp[0]);
            float2 f1 = __half22float2(hp[1]);
            float2 f2 = __half22float2(hp[2]);
            float2 f3 = __half22float2(hp[3]);
            *(float4*)&hs[r * 128 + c]     = make_float4(f0.x, f0.y, f1.x, f1.y);
            *(float4*)&hs[r * 128 + c + 4] = make_float4(f2.x, f2.y, f3.x, f3.y);
        }
        float p0 = 0.f, p1 = 0.f;
        const float* hrow = &hs[nsub * 128];
        #pragma unroll
        for (int hf = 0; hf < 2; hf++) {
            __syncthreads();
            for (int i = t; i < 128 * 64; i += 256)
                W1s[i] = Wm1[(size_t)(i >> 6) * 128 + hf * 64 + (i & 63)];
            __syncthreads();
            float a0 = 0.f, a1 = 0.f;
            #pragma unroll 8
            for (int d = 0; d < 128; d++) {
                float hv = hrow[d];
                float2 w = *(const float2*)&W1s[d * 64 + q * 2];
                a0 += hv * w.x;
                a1 += hv * w.y;
            }
            a0 = fmaxf(a0 + b1r[hf][0], 0.f);
            a1 = fmaxf(a1 + b1r[hf][1], 0.f);
            p0 += a0 * w2r[hf][0][0] + a1 * w2r[hf][1][0];
            p1 += a0 * w2r[hf][0][1] + a1 * w2r[hf][1][1];
        }
        #pragma unroll
        for (int mk = 1; mk < 32; mk <<= 1) {
            p0 += __shfl_xor(p0, mk, 64);
            p1 += __shfl_xor(p1, mk, 64);
        }
        if (q == 0) {
            int r = tile * 8 + nsub;
            out[r * 2 + 0] = p0 + b20;
            out[r * 2 + 1] = p1 + b21;
        }
    }
}

// ---------------------------------------------------------------------------
extern "C" void kernel_launch(void* const* d_in, const int* in_sizes, int n_in,
                              void* d_out, int out_size, void* d_ws, size_t ws_size,
                              hipStream_t stream)
{
    const float* ppos   = (const float*)d_in[0];
    const float* wpos   = (const float*)d_in[1];
    const float* pfeat  = (const float*)d_in[2];
    const int*   ei     = (const int*)d_in[3];
    const float* gamma  = (const float*)d_in[4];
    const float* Wf     = (const float*)d_in[5];
    const float* bfv    = (const float*)d_in[6];
    const float* We     = (const float*)d_in[7];
    const float* be     = (const float*)d_in[8];
    const float* W1     = (const float*)d_in[9];
    const float* atts1  = (const float*)d_in[10];
    const float* attd1  = (const float*)d_in[11];
    const float* Wedge1 = (const float*)d_in[12];
    const float* atte1  = (const float*)d_in[13];
    const float* b1     = (const float*)d_in[14];
    const float* W2     = (const float*)d_in[15];
    const float* atts2  = (const float*)d_in[16];
    const float* attd2  = (const float*)d_in[17];
    const float* Wedge2 = (const float*)d_in[18];
    const float* atte2  = (const float*)d_in[19];
    const float* b2     = (const float*)d_in[20];
    const float* Wm1    = (const float*)d_in[21];
    const float* bm1    = (const float*)d_in[22];
    const float* Wm2    = (const float*)d_in[23];
    const float* bm2    = (const float*)d_in[24];
    float* out = (float*)d_out;

    char* ws = (char*)d_ws;
    size_t o = 0;
    auto alloc = [&](size_t bytes) -> char* {
        char* p = ws + o;
        o += (bytes + 255) & ~(size_t)255;
        return p;
    };
    __half* h0      = (__half*)alloc((size_t)NNP * 32 * 2);
    __half* x16     = (__half*)alloc((size_t)NNP * 128 * 2);
    __half* hbuf    = (__half*)alloc((size_t)NNP * 128 * 2);
    float*  asd     = (float*)alloc((size_t)NNP * 8 * 4);
    float*  alpha   = (float*)alloc((size_t)NE * 4 * 4);
    int*    deg     = (int*)alloc((size_t)(NN + 1) * 4);
    int*    offp    = (int*)alloc((size_t)(NN + 1) * 4);
    int*    cur     = (int*)alloc((size_t)NN * 4);
    int2*   e2      = (int2*)alloc((size_t)NE * 8);
    float*  dist    = (float*)alloc((size_t)NE * 4);
    int*    part    = (int*)alloc((size_t)NSEG * 4);
    int*    partoff = (int*)alloc((size_t)(128 + 1) * 4);
    float*  smallw  = (float*)alloc(4096);

    hipMemsetAsync(deg, 0, (NN + 1) * 4, stream);
    k_small<<<1, 256, 0, stream>>>(We, be, Wedge1, atte1, Wedge2, atte2, Wf, bfv, smallw);
    k_h0<<<(NNP * 32) / 256, 256, 0, stream>>>(pfeat, Wf, bfv, smallw, h0);
    k_count<<<(NE + 255) / 256, 256, 0, stream>>>(ei, deg);
    k_scan1<<<NSEG, 256, 0, stream>>>(deg, offp, cur, part);
    k_scan2<<<1, 128, 0, stream>>>(part, partoff, offp);
    k_scan3<<<NSEG, 256, 0, stream>>>(partoff, offp, cur);
    k_fill<<<(NE + 255) / 256, 256, 0, stream>>>(ei, cur, e2, dist, ppos, wpos);
    // layer 1
    k_x<32, 128><<<dim3(NNP / 64, 1), 256, 0, stream>>>(h0, W1, atts1, attd1, x16, asd);
    k_alpha<1><<<(NE + 255) / 256, 256, 0, stream>>>(e2, dist, offp + N_PRO, gamma, smallw + 0, smallw + 128, asd, alpha);
    k_agg<0><<<NN / 4, 256, 0, stream>>>(offp, e2, alpha, x16, b1, hbuf);
    // layer 2 (only water destinations are ever consumed downstream)
    k_x<128, 64><<<dim3(NNP / 64, 2), 256, 0, stream>>>(hbuf, W2, atts2, attd2, x16, asd);
    k_alpha<2><<<(NE + 255) / 256, 256, 0, stream>>>(e2, dist, offp + N_PRO, gamma, smallw + 132, smallw + 260, asd, alpha);
    k_agg<1><<<N_WAT / 4, 256, 0, stream>>>(offp, e2, alpha, x16, b2, hbuf);
    // MLP on water nodes
    k_mlp<<<2048, 256, 0, stream>>>(hbuf, Wm1, bm1, Wm2, bm2, out);
}

// Round 9
// 506.700 us; speedup vs baseline: 1.9474x; 1.0105x over previous
//
#include <hip/hip_runtime.h>
#include <hip/hip_fp16.h>
#include <stdint.h>

#define N_PRO 60000
#define N_WAT 40000
#define NN    100000
#define NNP   100032            // padded to a multiple of 64 for k_x tiles
#define NE    1000000
#define IN_DIM 21
#define HID    32
#define HEADS  4
#define HC     128
#define EDGE_K 32
#define NSEG   ((NN + 1023) / 1024)   // 98 segments for the hierarchical scan

// ---------------------------------------------------------------------------
// K1: tiny fused weights.
// smallw floats: [0..127]=U1, [128..131]=aeb1, [132..259]=U2, [260..263]=aeb2,
// [264..295]=h0w, [296..423]=va_s1 (4 heads x 32), [424..551]=va_d1
// va_s1[h][c] = sum_j W1[c, h*32+j] * atts1[h,j]  (folds k_x-L1's logit GEMM)
// ---------------------------------------------------------------------------
__global__ __launch_bounds__(256) void k_small(
    const float* We, const float* be,
    const float* Wedge1, const float* atte1,
    const float* Wedge2, const float* atte2,
    const float* Wf, const float* bfv,
    const float* W1, const float* atts1, const float* attd1,
    float* smallw)
{
    __shared__ float V[2][128];
    int t = threadIdx.x;
    {
        int l = t >> 7, dh = t & 127, d = dh >> 2, h = dh & 3;
        const float* Wg = l ? Wedge2 : Wedge1;
        const float* ae = l ? atte2 : atte1;
        float s = 0.f;
        for (int c = 0; c < HID; c++)
            s += Wg[d * HC + h * HID + c] * ae[h * HID + c];
        V[l][dh] = s;
    }
    __syncthreads();
    {
        int l = t >> 7, kh = t & 127, k = kh >> 2, h = kh & 3;
        float s = 0.f;
        for (int d = 0; d < 32; d++)
            s += We[k * 32 + d] * V[l][d * 4 + h];
        smallw[(l ? 132 : 0) + kh] = s;
    }
    if (t < 8) {
        int l = t >> 2, h = t & 3;
        float s = 0.f;
        for (int d = 0; d < 32; d++)
            s += be[d] * V[l][d * 4 + h];
        smallw[(l ? 260 : 128) + h] = s;
    }
    if (t >= 32 && t < 64) {
        int c = t - 32;
        smallw[264 + c] = Wf[20 * 32 + c] + bfv[c];
    }
    // va_s1 / va_d1
    {
        int side = t >> 7;                 // 0: src-att, 1: dst-att
        int h = (t >> 5) & 3, c = t & 31;
        const float* av = side ? attd1 : atts1;
        float s = 0.f;
        for (int j = 0; j < 32; j++)
            s += W1[c * 128 + h * 32 + j] * av[h * 32 + j];
        smallw[(side ? 424 : 296) + (t & 127)] = s;
    }
}

// ---------------------------------------------------------------------------
// K2: h0 = feats @ Wf + bf (fp16) AND layer-1 logits asd[n,8] via va vectors
// (a_s[n,h] = sum_c h0[n,c]*va_s1[h,c]) — replaces the whole k_x-L1 GEMM.
// Block: 256 threads = 8 nodes x 32 channels; butterfly over 32-lane halves.
// ---------------------------------------------------------------------------
__global__ __launch_bounds__(256) void k_h0(
    const float* __restrict__ pf, const float* __restrict__ Wf,
    const float* __restrict__ bfv, const float* __restrict__ smallw,
    __half* __restrict__ h0, float* __restrict__ asd)
{
    __shared__ float Wfs[IN_DIM * 32];
    __shared__ float bfs[32];
    __shared__ float h0w[32];
    __shared__ float vas[128], vad[128];
    int t = threadIdx.x;
    for (int i = t; i < IN_DIM * 32; i += 256) Wfs[i] = Wf[i];
    if (t < 32) { bfs[t] = bfv[t]; h0w[t] = smallw[264 + t]; }
    // FIX (round 8 bug): stage BOTH 128-float va arrays fully.
    if (t < 128) vas[t] = smallw[296 + t];
    else         vad[t - 128] = smallw[424 + (t - 128)];
    __syncthreads();
    int id = blockIdx.x * 256 + t;
    int n = id >> 5, c = id & 31;
    if (n >= NNP) return;
    float v;
    if (n < N_PRO) {
        float s = bfs[c];
        for (int k = 0; k < IN_DIM; k++)
            s += pf[n * IN_DIM + k] * Wfs[k * 32 + c];
        v = s;
    } else {
        v = h0w[c];
    }
    h0[(size_t)n * 32 + c] = __float2half(v);
    // logits: 8 dot products of length 32, butterfly within the 32-lane half
    float ps[4], pd[4];
    #pragma unroll
    for (int h = 0; h < 4; h++) {
        ps[h] = v * vas[h * 32 + c];
        pd[h] = v * vad[h * 32 + c];
    }
    #pragma unroll
    for (int m = 1; m < 32; m <<= 1) {
        #pragma unroll
        for (int h = 0; h < 4; h++) {
            ps[h] += __shfl_xor(ps[h], m, 64);
            pd[h] += __shfl_xor(pd[h], m, 64);
        }
    }
    if ((t & 31) == 0) {
        *(float4*)&asd[(size_t)n * 8]     = make_float4(ps[0], ps[1], ps[2], ps[3]);
        *(float4*)&asd[(size_t)n * 8 + 4] = make_float4(pd[0], pd[1], pd[2], pd[3]);
    }
}

// ---------------------------------------------------------------------------
// CSR build over dst: count -> hierarchical scan (3 passes) -> fill
// ---------------------------------------------------------------------------
__global__ __launch_bounds__(256) void k_count(const int* ei, int* deg) {
    int e = blockIdx.x * 256 + threadIdx.x;
    if (e >= NE) return;
    int d = ei[NE + e];
    int s = ei[e];
    if ((unsigned)d < (unsigned)NN && (unsigned)s < (unsigned)NN)
        atomicAdd(&deg[d], 1);
}

__global__ __launch_bounds__(256) void k_scan1(
    const int* __restrict__ deg, int* __restrict__ off,
    int* __restrict__ cur, int* __restrict__ part)
{
    __shared__ int s[256];
    int t = threadIdx.x;
    int base = blockIdx.x * 1024 + t * 4;
    int d0 = 0, d1 = 0, d2 = 0, d3 = 0;
    if (base + 3 < NN) {
        int4 v = *(const int4*)&deg[base];
        d0 = v.x; d1 = v.y; d2 = v.z; d3 = v.w;
    } else {
        if (base + 0 < NN) d0 = deg[base + 0];
        if (base + 1 < NN) d1 = deg[base + 1];
        if (base + 2 < NN) d2 = deg[base + 2];
    }
    int tsum = d0 + d1 + d2 + d3;
    s[t] = tsum;
    __syncthreads();
    #pragma unroll
    for (int o = 1; o < 256; o <<= 1) {
        int v = (t >= o) ? s[t - o] : 0;
        __syncthreads();
        s[t] += v;
        __syncthreads();
    }
    int ex = s[t] - tsum;
    if (base + 0 < NN) { int v = ex;                 off[base + 0] = v; cur[base + 0] = v; }
    if (base + 1 < NN) { int v = ex + d0;            off[base + 1] = v; cur[base + 1] = v; }
    if (base + 2 < NN) { int v = ex + d0 + d1;       off[base + 2] = v; cur[base + 2] = v; }
    if (base + 3 < NN) { int v = ex + d0 + d1 + d2;  off[base + 3] = v; cur[base + 3] = v; }
    if (t == 255) part[blockIdx.x] = s[255];
}

__global__ __launch_bounds__(128) void k_scan2(
    const int* __restrict__ part, int* __restrict__ partoff, int* __restrict__ off)
{
    __shared__ int s[128];
    int t = threadIdx.x;
    int v = (t < NSEG) ? part[t] : 0;
    s[t] = v;
    __syncthreads();
    #pragma unroll
    for (int o = 1; o < 128; o <<= 1) {
        int x = (t >= o) ? s[t - o] : 0;
        __syncthreads();
        s[t] += x;
        __syncthreads();
    }
    partoff[t] = s[t] - v;   // exclusive prefix
    if (t == 127) off[NN] = s[127];
}

__global__ __launch_bounds__(256) void k_scan3(
    const int* __restrict__ partoff, int* __restrict__ off, int* __restrict__ cur)
{
    int b = blockIdx.x;
    int add = partoff[b];
    if (add == 0) return;
    int base = b * 1024 + threadIdx.x * 4;
    #pragma unroll
    for (int j = 0; j < 4; j++) {
        int i = base + j;
        if (i < NN) { off[i] += add; cur[i] += add; }
    }
}

// fill CSR: packed {src,dst} + per-slot distance (layer-invariant)
__global__ __launch_bounds__(256) void k_fill(
    const int* __restrict__ ei, int* __restrict__ cur,
    int2* __restrict__ e2, float* __restrict__ dist,
    const float* __restrict__ ppos, const float* __restrict__ wpos)
{
    int e = blockIdx.x * 256 + threadIdx.x;
    if (e >= NE) return;
    int d = ei[NE + e];
    int s = ei[e];
    if ((unsigned)d >= (unsigned)NN || (unsigned)s >= (unsigned)NN) return;
    const float* ps = (s < N_PRO) ? &ppos[s * 3] : &wpos[(s - N_PRO) * 3];
    const float* pd = (d < N_PRO) ? &ppos[d * 3] : &wpos[(d - N_PRO) * 3];
    float dx = pd[0] - ps[0];
    float dy = pd[1] - ps[1];
    float dz = pd[2] - ps[2];
    float dd = sqrtf(dx * dx + dy * dy + dz * dz);
    int p = atomicAdd(&cur[d], 1);
    e2[p] = make_int2(s, d);
    dist[p] = dd;
}

// ---------------------------------------------------------------------------
// K6: x = h @ W (+ logits). Layer-2 only now. Register-blocked outer product.
// ---------------------------------------------------------------------------
template <int DIN, int COLS>
__global__ __launch_bounds__(256) void k_x(
    const __half* __restrict__ h, const float* __restrict__ Wg,
    const float* __restrict__ atts, const float* __restrict__ attd,
    __half* __restrict__ x16, float* __restrict__ asd)
{
    constexpr int G    = COLS / 4;
    constexpr int NPT  = COLS / 16;
    constexpr int HSTR = DIN + 4;
    constexpr int DCH  = (DIN == 32) ? 32 : 64;
    __shared__ float Ws[DCH * COLS];
    __shared__ float hs[64 * HSTR];
    __shared__ float attS[COLS], attD[COLS];
    int t = threadIdx.x;
    int cbase = blockIdx.y * COLS;
    int n0 = blockIdx.x * 64;
    for (int i8 = t * 8; i8 < 64 * DIN; i8 += 2048) {
        int r = i8 / DIN, c = i8 % DIN;
        uint4 raw = *(const uint4*)&h[(size_t)(n0 + r) * DIN + c];
        const __half2* hp = (const __half2*)&raw;
        float2 f0 = __half22float2(hp[0]);
        float2 f1 = __half22float2(hp[1]);
        float2 f2 = __half22float2(hp[2]);
        float2 f3 = __half22float2(hp[3]);
        *(float4*)&hs[r * HSTR + c]     = make_float4(f0.x, f0.y, f1.x, f1.y);
        *(float4*)&hs[r * HSTR + c + 4] = make_float4(f2.x, f2.y, f3.x, f3.y);
    }
    if (t < COLS) { attS[t] = atts[cbase + t]; attD[t] = attd[cbase + t]; }
    int cg = t % G, ng = t / G;
    float acc[NPT][4];
    #pragma unroll
    for (int nn = 0; nn < NPT; nn++)
        #pragma unroll
        for (int j = 0; j < 4; j++) acc[nn][j] = 0.f;
    for (int dpass = 0; dpass < DIN; dpass += DCH) {
        __syncthreads();
        for (int i = t; i < DCH * COLS; i += 256) {
            int d = i / COLS, c = i % COLS;
            Ws[i] = Wg[(size_t)(dpass + d) * 128 + cbase + c];
        }
        __syncthreads();
        for (int d0 = 0; d0 < DCH; d0 += 4) {
            float hreg[NPT][4];
            #pragma unroll
            for (int nn = 0; nn < NPT; nn++) {
                float4 hv = *(const float4*)&hs[(ng * NPT + nn) * HSTR + dpass + d0];
                hreg[nn][0] = hv.x; hreg[nn][1] = hv.y;
                hreg[nn][2] = hv.z; hreg[nn][3] = hv.w;
            }
            #pragma unroll
            for (int dd = 0; dd < 4; dd++) {
                float4 wv = *(const float4*)&Ws[(d0 + dd) * COLS + cg * 4];
                #pragma unroll
                for (int nn = 0; nn < NPT; nn++) {
                    float hv = hreg[nn][dd];
                    acc[nn][0] += hv * wv.x;
                    acc[nn][1] += hv * wv.y;
                    acc[nn][2] += hv * wv.z;
                    acc[nn][3] += hv * wv.w;
                }
            }
        }
    }
    int hh = (cbase + cg * 4) >> 5;
    #pragma unroll
    for (int nn = 0; nn < NPT; nn++) {
        int n = n0 + ng * NPT + nn;
        __half2 ha = __floats2half2_rn(acc[nn][0], acc[nn][1]);
        __half2 hb = __floats2half2_rn(acc[nn][2], acc[nn][3]);
        uint2 pk;
        pk.x = *(unsigned int*)&ha;
        pk.y = *(unsigned int*)&hb;
        *(uint2*)&x16[(size_t)n * 128 + cbase + cg * 4] = pk;
        float ps = acc[nn][0] * attS[cg * 4]     + acc[nn][1] * attS[cg * 4 + 1]
                 + acc[nn][2] * attS[cg * 4 + 2] + acc[nn][3] * attS[cg * 4 + 3];
        float pd = acc[nn][0] * attD[cg * 4]     + acc[nn][1] * attD[cg * 4 + 1]
                 + acc[nn][2] * attD[cg * 4 + 2] + acc[nn][3] * attD[cg * 4 + 3];
        ps += __shfl_xor(ps, 1, 64); pd += __shfl_xor(pd, 1, 64);
        ps += __shfl_xor(ps, 2, 64); pd += __shfl_xor(pd, 2, 64);
        ps += __shfl_xor(ps, 4, 64); pd += __shfl_xor(pd, 4, 64);
        if ((cg & 7) == 0) {
            asd[(size_t)n * 8 + hh] = ps;
            asd[(size_t)n * 8 + 4 + hh] = pd;
        }
    }
}

// ---------------------------------------------------------------------------
// K7: attention logits in CSR slot order; dist precomputed.
// LAYER==2 skips protein-dst slots.
// ---------------------------------------------------------------------------
template <int LAYER>
__global__ __launch_bounds__(256) void k_alpha(
    const int2* __restrict__ e2, const float* __restrict__ dist,
    const int* __restrict__ wlim, const float* __restrict__ gamma,
    const float* __restrict__ U, const float* __restrict__ aeb,
    const float* __restrict__ asd, float* __restrict__ alpha)
{
    __shared__ float Us[128];
    __shared__ float aebs[4];
    int t = threadIdx.x;
    if (t < 128) Us[t] = U[t];
    if (t < 4) aebs[t] = aeb[t];
    __syncthreads();
    int i = blockIdx.x * 256 + t;
    if (i >= NE) return;
    if (LAYER == 2 && i < wlim[0]) return;
    int2 sd = e2[i];
    float dd = dist[i];
    float g = gamma[0];
    float ae0 = aebs[0], ae1 = aebs[1], ae2 = aebs[2], ae3 = aebs[3];
    const float step = 5.0f / 31.0f;
    #pragma unroll
    for (int k = 0; k < EDGE_K; k++) {
        float tt = dd - (float)k * step;
        float r = __expf(-g * tt * tt);
        ae0 += r * Us[k * 4 + 0];
        ae1 += r * Us[k * 4 + 1];
        ae2 += r * Us[k * 4 + 2];
        ae3 += r * Us[k * 4 + 3];
    }
    float4 as4 = *(const float4*)&asd[(size_t)sd.x * 8];
    float4 ad4 = *(const float4*)&asd[(size_t)sd.y * 8 + 4];
    float v0 = as4.x + ad4.x + ae0;
    float v1 = as4.y + ad4.y + ae1;
    float v2 = as4.z + ad4.z + ae2;
    float v3 = as4.w + ad4.w + ae3;
    v0 = v0 >= 0.f ? v0 : 0.2f * v0;
    v1 = v1 >= 0.f ? v1 : 0.2f * v1;
    v2 = v2 >= 0.f ? v2 : 0.2f * v2;
    v3 = v3 >= 0.f ? v3 : 0.2f * v3;
    *(float4*)&alpha[(size_t)i * 4] = make_float4(v0, v1, v2, v3);
}

// ---------------------------------------------------------------------------
// K8a: layer-1 aggregation over RAW h0 (64 B/edge gather, L2-resident 6.4 MB)
// then per-node W1 GEMM epilogue: out = elu((z/den)@W1 + b1) -> hbuf fp16.
// z distributed 2 ch/lane (head = lane>>4, c-pair = lane&15); W1 in LDS;
// z broadcast via shfl (no LDS alias hazards). Grid-stride over node groups.
// ---------------------------------------------------------------------------
__global__ __launch_bounds__(256) void k_agg1(
    const int* __restrict__ off, const int2* __restrict__ e2,
    const float* __restrict__ alpha, const __half* __restrict__ h016,
    const float* __restrict__ W1g, const float* __restrict__ b1,
    __half* __restrict__ hbuf)
{
    __shared__ float Ws[32 * 128];
    int t = threadIdx.x;
    for (int i = t; i < 32 * 128; i += 256) Ws[i] = W1g[i];
    int w = t >> 6, lane = t & 63;
    int h = lane >> 4, k16 = lane & 15;
    int j0 = h * 32 + 2 * k16;
    float2 bb = *(const float2*)&b1[j0];
    int slbase = lane & 48;
    const __half2* x2 = (const __half2*)h016;
    __syncthreads();
    for (int g = blockIdx.x; g < NN / 4; g += gridDim.x) {
        int n = g * 4 + w;
        int beg = off[n], end = off[n + 1];
        float lsum0 = 0.f, lsum1 = 0.f;
        float a00 = 0.f, a01 = 0.f, a10 = 0.f, a11 = 0.f;
        int i = beg;
        for (; i + 1 < end; i += 2) {
            int s0 = e2[i].x, s1 = e2[i + 1].x;
            float al0 = alpha[(unsigned)i * 4u + h];
            float al1 = alpha[(unsigned)(i + 1) * 4u + h];
            float2 xv0 = __half22float2(x2[(unsigned)s0 * 16u + k16]);
            float2 xv1 = __half22float2(x2[(unsigned)s1 * 16u + k16]);
            float e0 = __expf(al0), e1 = __expf(al1);
            lsum0 += e0; lsum1 += e1;
            a00 += e0 * xv0.x; a01 += e0 * xv0.y;
            a10 += e1 * xv1.x; a11 += e1 * xv1.y;
        }
        if (i < end) {
            int s0 = e2[i].x;
            float al0 = alpha[(unsigned)i * 4u + h];
            float2 xv0 = __half22float2(x2[(unsigned)s0 * 16u + k16]);
            float e0 = __expf(al0);
            lsum0 += e0;
            a00 += e0 * xv0.x; a01 += e0 * xv0.y;
        }
        float inv = 1.0f / (lsum0 + lsum1 + 1e-16f);
        float z0 = (a00 + a10) * inv;
        float z1 = (a01 + a11) * inv;
        // epilogue: out[j0], out[j0+1] = sum_c z[h][c] * W1[c, j0(+1)]
        float r0 = bb.x, r1 = bb.y;
        #pragma unroll
        for (int k = 0; k < 16; k++) {
            int sl = slbase | k;
            float zc0 = __shfl(z0, sl, 64);   // z[h][2k]
            float zc1 = __shfl(z1, sl, 64);   // z[h][2k+1]
            float2 w0 = *(const float2*)&Ws[(2 * k) * 128 + j0];
            float2 w1 = *(const float2*)&Ws[(2 * k + 1) * 128 + j0];
            r0 += zc0 * w0.x + zc1 * w1.x;
            r1 += zc0 * w0.y + zc1 * w1.y;
        }
        r0 = r0 > 0.f ? r0 : __expf(r0) - 1.0f;
        r1 = r1 > 0.f ? r1 : __expf(r1) - 1.0f;
        *(__half2*)&hbuf[(size_t)n * 128 + j0] = __floats2half2_rn(r0, r1);
    }
}

// ---------------------------------------------------------------------------
// K8b: layer-2 aggregation over pre-GEMMed x16 (water dst only), as before.
// ---------------------------------------------------------------------------
__global__ __launch_bounds__(256) void k_agg2(
    const int* __restrict__ off, const int2* __restrict__ e2,
    const float* __restrict__ alpha, const __half* __restrict__ x16,
    const float* __restrict__ bias, __half* __restrict__ hout)
{
    int t = threadIdx.x;
    int w = t >> 6, lane = t & 63;
    int n = N_PRO + blockIdx.x * 4 + w;
    if (n >= NN) return;
    int h = lane >> 4;
    int beg = off[n], end = off[n + 1];
    float lsum0 = 0.f, lsum1 = 0.f;
    float a00 = 0.f, a01 = 0.f, a10 = 0.f, a11 = 0.f;
    const __half2* x2 = (const __half2*)x16;
    int i = beg;
    for (; i + 1 < end; i += 2) {
        int s0 = e2[i].x, s1 = e2[i + 1].x;
        float al0 = alpha[(unsigned)i * 4u + h];
        float al1 = alpha[(unsigned)(i + 1) * 4u + h];
        float2 xv0 = __half22float2(x2[(unsigned)s0 * 64u + lane]);
        float2 xv1 = __half22float2(x2[(unsigned)s1 * 64u + lane]);
        float e0 = __expf(al0), e1 = __expf(al1);
        lsum0 += e0; lsum1 += e1;
        a00 += e0 * xv0.x; a01 += e0 * xv0.y;
        a10 += e1 * xv1.x; a11 += e1 * xv1.y;
    }
    if (i < end) {
        int s0 = e2[i].x;
        float al0 = alpha[(unsigned)i * 4u + h];
        float2 xv0 = __half22float2(x2[(unsigned)s0 * 64u + lane]);
        float e0 = __expf(al0);
        lsum0 += e0;
        a00 += e0 * xv0.x; a01 += e0 * xv0.y;
    }
    float lsum = lsum0 + lsum1;
    float acc0 = a00 + a10, acc1 = a01 + a11;
    float inv = 1.0f / (lsum + 1e-16f);
    float2 bbv = *(const float2*)&bias[lane * 2];
    float o0 = acc0 * inv + bbv.x;
    float o1 = acc1 * inv + bbv.y;
    o0 = o0 > 0.f ? o0 : __expf(o0) - 1.0f;
    o1 = o1 > 0.f ? o1 : __expf(o1) - 1.0f;
    *(__half2*)&hout[(size_t)n * 128 + lane * 2] = __floats2half2_rn(o0, o1);
}

// ---------------------------------------------------------------------------
// K9 v2: water MLP. 32-node tile/block (grid 1250), hs padded to stride 132
// (kills the 8-way bank conflict), float4 register blocking: thread =
// (g = t>>5 -> nodes g,g+8,g+16,g+24) x (q = t&31 -> 2 cols per 64-col half).
// ---------------------------------------------------------------------------
__global__ __launch_bounds__(256) void k_mlp(
    const __half* __restrict__ hh, const float* __restrict__ Wm1,
    const float* __restrict__ bm1, const float* __restrict__ Wm2,
    const float* __restrict__ bm2, float* __restrict__ out)
{
    __shared__ float W1s[128 * 64];
    __shared__ float hs[32 * 132];
    int t = threadIdx.x;
    int g = t >> 5, q = t & 31;
    float b1r[2][2], w2r[2][2][2];
    #pragma unroll
    for (int hf = 0; hf < 2; hf++)
        #pragma unroll
        for (int j = 0; j < 2; j++) {
            int c = hf * 64 + q * 2 + j;
            b1r[hf][j] = bm1[c];
            w2r[hf][j][0] = Wm2[c * 2 + 0];
            w2r[hf][j][1] = Wm2[c * 2 + 1];
        }
    float b20 = bm2[0], b21 = bm2[1];
    int tile = blockIdx.x;
    // stage h tile: 32 rows x 128 ch fp16 -> fp32, padded stride 132
    {
        int r = t >> 3, c0 = (t & 7) * 16;
        const __half* src = &hh[(size_t)(N_PRO + tile * 32 + r) * 128 + c0];
        uint4 raw0 = *(const uint4*)src;
        uint4 raw1 = *(const uint4*)(src + 8);
        const __half2* hp0 = (const __half2*)&raw0;
        const __half2* hp1 = (const __half2*)&raw1;
        #pragma unroll
        for (int j = 0; j < 4; j++) {
            float2 fa = __half22float2(j < 2 ? hp0[2 * j] : hp1[2 * (j - 2)]);
            float2 fb = __half22float2(j < 2 ? hp0[2 * j + 1] : hp1[2 * (j - 2) + 1]);
            *(float4*)&hs[r * 132 + c0 + 4 * j] = make_float4(fa.x, fa.y, fb.x, fb.y);
        }
    }
    float p0[4] = {0.f, 0.f, 0.f, 0.f}, p1[4] = {0.f, 0.f, 0.f, 0.f};
    #pragma unroll
    for (int hf = 0; hf < 2; hf++) {
        __syncthreads();
        for (int i = t; i < 128 * 64; i += 256)
            W1s[i] = Wm1[(size_t)(i >> 6) * 128 + hf * 64 + (i & 63)];
        __syncthreads();
        float a[4][2];
        #pragma unroll
        for (int i = 0; i < 4; i++) { a[i][0] = 0.f; a[i][1] = 0.f; }
        for (int d0 = 0; d0 < 128; d0 += 4) {
            float4 hv[4];
            #pragma unroll
            for (int i = 0; i < 4; i++)
                hv[i] = *(const float4*)&hs[(g + 8 * i) * 132 + d0];
            #pragma unroll
            for (int dd = 0; dd < 4; dd++) {
                float2 wv = *(const float2*)&W1s[(d0 + dd) * 64 + q * 2];
                #pragma unroll
                for (int i = 0; i < 4; i++) {
                    float hvv = (&hv[i].x)[dd];
                    a[i][0] += hvv * wv.x;
                    a[i][1] += hvv * wv.y;
                }
            }
        }
        #pragma unroll
        for (int i = 0; i < 4; i++) {
            float a0 = fmaxf(a[i][0] + b1r[hf][0], 0.f);
            float a1 = fmaxf(a[i][1] + b1r[hf][1], 0.f);
            p0[i] += a0 * w2r[hf][0][0] + a1 * w2r[hf][1][0];
            p1[i] += a0 * w2r[hf][0][1] + a1 * w2r[hf][1][1];
        }
    }
    #pragma unroll
    for (int m = 1; m < 32; m <<= 1) {
        #pragma unroll
        for (int i = 0; i < 4; i++) {
            p0[i] += __shfl_xor(p0[i], m, 64);
            p1[i] += __shfl_xor(p1[i], m, 64);
        }
    }
    if (q == 0) {
        #pragma unroll
        for (int i = 0; i < 4; i++) {
            int n = tile * 32 + g + 8 * i;
            *(float2*)&out[n * 2] = make_float2(p0[i] + b20, p1[i] + b21);
        }
    }
}

// ---------------------------------------------------------------------------
extern "C" void kernel_launch(void* const* d_in, const int* in_sizes, int n_in,
                              void* d_out, int out_size, void* d_ws, size_t ws_size,
                              hipStream_t stream)
{
    const float* ppos   = (const float*)d_in[0];
    const float* wpos   = (const float*)d_in[1];
    const float* pfeat  = (const float*)d_in[2];
    const int*   ei     = (const int*)d_in[3];
    const float* gamma  = (const float*)d_in[4];
    const float* Wf     = (const float*)d_in[5];
    const float* bfv    = (const float*)d_in[6];
    const float* We     = (const float*)d_in[7];
    const float* be     = (const float*)d_in[8];
    const float* W1     = (const float*)d_in[9];
    const float* atts1  = (const float*)d_in[10];
    const float* attd1  = (const float*)d_in[11];
    const float* Wedge1 = (const float*)d_in[12];
    const float* atte1  = (const float*)d_in[13];
    const float* b1     = (const float*)d_in[14];
    const float* W2     = (const float*)d_in[15];
    const float* atts2  = (const float*)d_in[16];
    const float* attd2  = (const float*)d_in[17];
    const float* Wedge2 = (const float*)d_in[18];
    const float* atte2  = (const float*)d_in[19];
    const float* b2     = (const float*)d_in[20];
    const float* Wm1    = (const float*)d_in[21];
    const float* bm1    = (const float*)d_in[22];
    const float* Wm2    = (const float*)d_in[23];
    const float* bm2    = (const float*)d_in[24];
    float* out = (float*)d_out;

    char* ws = (char*)d_ws;
    size_t o = 0;
    auto alloc = [&](size_t bytes) -> char* {
        char* p = ws + o;
        o += (bytes + 255) & ~(size_t)255;
        return p;
    };
    __half* h0      = (__half*)alloc((size_t)NNP * 32 * 2);
    __half* x16     = (__half*)alloc((size_t)NNP * 128 * 2);
    __half* hbuf    = (__half*)alloc((size_t)NNP * 128 * 2);
    float*  asd     = (float*)alloc((size_t)NNP * 8 * 4);
    float*  alpha   = (float*)alloc((size_t)NE * 4 * 4);
    int*    deg     = (int*)alloc((size_t)(NN + 1) * 4);
    int*    offp    = (int*)alloc((size_t)(NN + 1) * 4);
    int*    cur     = (int*)alloc((size_t)NN * 4);
    int2*   e2      = (int2*)alloc((size_t)NE * 8);
    float*  dist    = (float*)alloc((size_t)NE * 4);
    int*    part    = (int*)alloc((size_t)NSEG * 4);
    int*    partoff = (int*)alloc((size_t)(128 + 1) * 4);
    float*  smallw  = (float*)alloc(4096);

    hipMemsetAsync(deg, 0, (NN + 1) * 4, stream);
    k_small<<<1, 256, 0, stream>>>(We, be, Wedge1, atte1, Wedge2, atte2, Wf, bfv,
                                   W1, atts1, attd1, smallw);
    k_h0<<<(NNP * 32) / 256, 256, 0, stream>>>(pfeat, Wf, bfv, smallw, h0, asd);
    k_count<<<(NE + 255) / 256, 256, 0, stream>>>(ei, deg);
    k_scan1<<<NSEG, 256, 0, stream>>>(deg, offp, cur, part);
    k_scan2<<<1, 128, 0, stream>>>(part, partoff, offp);
    k_scan3<<<NSEG, 256, 0, stream>>>(partoff, offp, cur);
    k_fill<<<(NE + 255) / 256, 256, 0, stream>>>(ei, cur, e2, dist, ppos, wpos);
    // layer 1: aggregate raw h0, W1 applied per node in the epilogue
    k_alpha<1><<<(NE + 255) / 256, 256, 0, stream>>>(e2, dist, offp + N_PRO, gamma, smallw + 0, smallw + 128, asd, alpha);
    k_agg1<<<4096, 256, 0, stream>>>(offp, e2, alpha, h0, W1, b1, hbuf);
    // layer 2 (water destinations only)
    k_x<128, 64><<<dim3(NNP / 64, 2), 256, 0, stream>>>(hbuf, W2, atts2, attd2, x16, asd);
    k_alpha<2><<<(NE + 255) / 256, 256, 0, stream>>>(e2, dist, offp + N_PRO, gamma, smallw + 132, smallw + 260, asd, alpha);
    k_agg2<<<N_WAT / 4, 256, 0, stream>>>(offp, e2, alpha, x16, b2, hbuf);
    // MLP on water nodes
    k_mlp<<<N_WAT / 32, 256, 0, stream>>>(hbuf, Wm1, bm1, Wm2, bm2, out);
}

// Round 10
// 451.927 us; speedup vs baseline: 2.1835x; 1.1212x over previous
//
#include <hip/hip_runtime.h>
#include <hip/hip_fp16.h>
#include <stdint.h>

#define N_PRO 60000
#define N_WAT 40000
#define NN    100000
#define NNP   100032            // padded to a multiple of 64 for tiles
#define NE    1000000
#define IN_DIM 21
#define HID    32
#define HEADS  4
#define HC     128
#define EDGE_K 32
#define NSEG   ((NN + 1023) / 1024)

// ---------------------------------------------------------------------------
// K1: tiny fused weights.
// smallw floats: [0..127]=U1, [128..131]=aeb1, [132..259]=U2, [260..263]=aeb2,
// [264..295]=h0w, [296..423]=va_s1, [424..551]=va_d1
// ---------------------------------------------------------------------------
__global__ __launch_bounds__(256) void k_small(
    const float* We, const float* be,
    const float* Wedge1, const float* atte1,
    const float* Wedge2, const float* atte2,
    const float* Wf, const float* bfv,
    const float* W1, const float* atts1, const float* attd1,
    float* smallw)
{
    __shared__ float V[2][128];
    int t = threadIdx.x;
    {
        int l = t >> 7, dh = t & 127, d = dh >> 2, h = dh & 3;
        const float* Wg = l ? Wedge2 : Wedge1;
        const float* ae = l ? atte2 : atte1;
        float s = 0.f;
        for (int c = 0; c < HID; c++)
            s += Wg[d * HC + h * HID + c] * ae[h * HID + c];
        V[l][dh] = s;
    }
    __syncthreads();
    {
        int l = t >> 7, kh = t & 127, k = kh >> 2, h = kh & 3;
        float s = 0.f;
        for (int d = 0; d < 32; d++)
            s += We[k * 32 + d] * V[l][d * 4 + h];
        smallw[(l ? 132 : 0) + kh] = s;
    }
    if (t < 8) {
        int l = t >> 2, h = t & 3;
        float s = 0.f;
        for (int d = 0; d < 32; d++)
            s += be[d] * V[l][d * 4 + h];
        smallw[(l ? 260 : 128) + h] = s;
    }
    if (t >= 32 && t < 64) {
        int c = t - 32;
        smallw[264 + c] = Wf[20 * 32 + c] + bfv[c];
    }
    {
        int side = t >> 7;
        int h = (t >> 5) & 3, c = t & 31;
        const float* av = side ? attd1 : atts1;
        float s = 0.f;
        for (int j = 0; j < 32; j++)
            s += W1[c * 128 + h * 32 + j] * av[h * 32 + j];
        smallw[(side ? 424 : 296) + (t & 127)] = s;
    }
}

// ---------------------------------------------------------------------------
// K2: h0 = feats @ Wf + bf (fp16) AND layer-1 logits asd[n,8] via va vectors.
// ---------------------------------------------------------------------------
__global__ __launch_bounds__(256) void k_h0(
    const float* __restrict__ pf, const float* __restrict__ Wf,
    const float* __restrict__ bfv, const float* __restrict__ smallw,
    __half* __restrict__ h0, float* __restrict__ asd)
{
    __shared__ float Wfs[IN_DIM * 32];
    __shared__ float bfs[32];
    __shared__ float h0w[32];
    __shared__ float vas[128], vad[128];
    int t = threadIdx.x;
    for (int i = t; i < IN_DIM * 32; i += 256) Wfs[i] = Wf[i];
    if (t < 32) { bfs[t] = bfv[t]; h0w[t] = smallw[264 + t]; }
    if (t < 128) vas[t] = smallw[296 + t];
    else         vad[t - 128] = smallw[424 + (t - 128)];
    __syncthreads();
    int id = blockIdx.x * 256 + t;
    int n = id >> 5, c = id & 31;
    if (n >= NNP) return;
    float v;
    if (n < N_PRO) {
        float s = bfs[c];
        for (int k = 0; k < IN_DIM; k++)
            s += pf[n * IN_DIM + k] * Wfs[k * 32 + c];
        v = s;
    } else {
        v = h0w[c];
    }
    h0[(size_t)n * 32 + c] = __float2half(v);
    float ps[4], pd[4];
    #pragma unroll
    for (int h = 0; h < 4; h++) {
        ps[h] = v * vas[h * 32 + c];
        pd[h] = v * vad[h * 32 + c];
    }
    #pragma unroll
    for (int m = 1; m < 32; m <<= 1) {
        #pragma unroll
        for (int h = 0; h < 4; h++) {
            ps[h] += __shfl_xor(ps[h], m, 64);
            pd[h] += __shfl_xor(pd[h], m, 64);
        }
    }
    if ((t & 31) == 0) {
        *(float4*)&asd[(size_t)n * 8]     = make_float4(ps[0], ps[1], ps[2], ps[3]);
        *(float4*)&asd[(size_t)n * 8 + 4] = make_float4(pd[0], pd[1], pd[2], pd[3]);
    }
}

// ---------------------------------------------------------------------------
// CSR build over dst
// ---------------------------------------------------------------------------
__global__ __launch_bounds__(256) void k_count(const int* ei, int* deg) {
    int e = blockIdx.x * 256 + threadIdx.x;
    if (e >= NE) return;
    int d = ei[NE + e];
    int s = ei[e];
    if ((unsigned)d < (unsigned)NN && (unsigned)s < (unsigned)NN)
        atomicAdd(&deg[d], 1);
}

__global__ __launch_bounds__(256) void k_scan1(
    const int* __restrict__ deg, int* __restrict__ off,
    int* __restrict__ cur, int* __restrict__ part)
{
    __shared__ int s[256];
    int t = threadIdx.x;
    int base = blockIdx.x * 1024 + t * 4;
    int d0 = 0, d1 = 0, d2 = 0, d3 = 0;
    if (base + 3 < NN) {
        int4 v = *(const int4*)&deg[base];
        d0 = v.x; d1 = v.y; d2 = v.z; d3 = v.w;
    } else {
        if (base + 0 < NN) d0 = deg[base + 0];
        if (base + 1 < NN) d1 = deg[base + 1];
        if (base + 2 < NN) d2 = deg[base + 2];
    }
    int tsum = d0 + d1 + d2 + d3;
    s[t] = tsum;
    __syncthreads();
    #pragma unroll
    for (int o = 1; o < 256; o <<= 1) {
        int v = (t >= o) ? s[t - o] : 0;
        __syncthreads();
        s[t] += v;
        __syncthreads();
    }
    int ex = s[t] - tsum;
    if (base + 0 < NN) { int v = ex;                 off[base + 0] = v; cur[base + 0] = v; }
    if (base + 1 < NN) { int v = ex + d0;            off[base + 1] = v; cur[base + 1] = v; }
    if (base + 2 < NN) { int v = ex + d0 + d1;       off[base + 2] = v; cur[base + 2] = v; }
    if (base + 3 < NN) { int v = ex + d0 + d1 + d2;  off[base + 3] = v; cur[base + 3] = v; }
    if (t == 255) part[blockIdx.x] = s[255];
}

__global__ __launch_bounds__(128) void k_scan2(
    const int* __restrict__ part, int* __restrict__ partoff, int* __restrict__ off)
{
    __shared__ int s[128];
    int t = threadIdx.x;
    int v = (t < NSEG) ? part[t] : 0;
    s[t] = v;
    __syncthreads();
    #pragma unroll
    for (int o = 1; o < 128; o <<= 1) {
        int x = (t >= o) ? s[t - o] : 0;
        __syncthreads();
        s[t] += x;
        __syncthreads();
    }
    partoff[t] = s[t] - v;
    if (t == 127) off[NN] = s[127];
}

__global__ __launch_bounds__(256) void k_scan3(
    const int* __restrict__ partoff, int* __restrict__ off, int* __restrict__ cur)
{
    int b = blockIdx.x;
    int add = partoff[b];
    if (add == 0) return;
    int base = b * 1024 + threadIdx.x * 4;
    #pragma unroll
    for (int j = 0; j < 4; j++) {
        int i = base + j;
        if (i < NN) { off[i] += add; cur[i] += add; }
    }
}

__global__ __launch_bounds__(256) void k_fill(
    const int* __restrict__ ei, int* __restrict__ cur,
    int2* __restrict__ e2, float* __restrict__ dist,
    const float* __restrict__ ppos, const float* __restrict__ wpos)
{
    int e = blockIdx.x * 256 + threadIdx.x;
    if (e >= NE) return;
    int d = ei[NE + e];
    int s = ei[e];
    if ((unsigned)d >= (unsigned)NN || (unsigned)s >= (unsigned)NN) return;
    const float* ps = (s < N_PRO) ? &ppos[s * 3] : &wpos[(s - N_PRO) * 3];
    const float* pd = (d < N_PRO) ? &ppos[d * 3] : &wpos[(d - N_PRO) * 3];
    float dx = pd[0] - ps[0];
    float dy = pd[1] - ps[1];
    float dz = pd[2] - ps[2];
    float dd = sqrtf(dx * dx + dy * dy + dz * dz);
    int p = atomicAdd(&cur[d], 1);
    e2[p] = make_int2(s, d);
    dist[p] = dd;
}

// ---------------------------------------------------------------------------
// K6: x = h @ W (+ logits). Layer-2 only. Register-blocked outer product.
// ---------------------------------------------------------------------------
template <int DIN, int COLS>
__global__ __launch_bounds__(256) void k_x(
    const __half* __restrict__ h, const float* __restrict__ Wg,
    const float* __restrict__ atts, const float* __restrict__ attd,
    __half* __restrict__ x16, float* __restrict__ asd)
{
    constexpr int G    = COLS / 4;
    constexpr int NPT  = COLS / 16;
    constexpr int HSTR = DIN + 4;
    constexpr int DCH  = (DIN == 32) ? 32 : 64;
    __shared__ float Ws[DCH * COLS];
    __shared__ float hs[64 * HSTR];
    __shared__ float attS[COLS], attD[COLS];
    int t = threadIdx.x;
    int cbase = blockIdx.y * COLS;
    int n0 = blockIdx.x * 64;
    for (int i8 = t * 8; i8 < 64 * DIN; i8 += 2048) {
        int r = i8 / DIN, c = i8 % DIN;
        uint4 raw = *(const uint4*)&h[(size_t)(n0 + r) * DIN + c];
        const __half2* hp = (const __half2*)&raw;
        float2 f0 = __half22float2(hp[0]);
        float2 f1 = __half22float2(hp[1]);
        float2 f2 = __half22float2(hp[2]);
        float2 f3 = __half22float2(hp[3]);
        *(float4*)&hs[r * HSTR + c]     = make_float4(f0.x, f0.y, f1.x, f1.y);
        *(float4*)&hs[r * HSTR + c + 4] = make_float4(f2.x, f2.y, f3.x, f3.y);
    }
    if (t < COLS) { attS[t] = atts[cbase + t]; attD[t] = attd[cbase + t]; }
    int cg = t % G, ng = t / G;
    float acc[NPT][4];
    #pragma unroll
    for (int nn = 0; nn < NPT; nn++)
        #pragma unroll
        for (int j = 0; j < 4; j++) acc[nn][j] = 0.f;
    for (int dpass = 0; dpass < DIN; dpass += DCH) {
        __syncthreads();
        for (int i = t; i < DCH * COLS; i += 256) {
            int d = i / COLS, c = i % COLS;
            Ws[i] = Wg[(size_t)(dpass + d) * 128 + cbase + c];
        }
        __syncthreads();
        for (int d0 = 0; d0 < DCH; d0 += 4) {
            float hreg[NPT][4];
            #pragma unroll
            for (int nn = 0; nn < NPT; nn++) {
                float4 hv = *(const float4*)&hs[(ng * NPT + nn) * HSTR + dpass + d0];
                hreg[nn][0] = hv.x; hreg[nn][1] = hv.y;
                hreg[nn][2] = hv.z; hreg[nn][3] = hv.w;
            }
            #pragma unroll
            for (int dd = 0; dd < 4; dd++) {
                float4 wv = *(const float4*)&Ws[(d0 + dd) * COLS + cg * 4];
                #pragma unroll
                for (int nn = 0; nn < NPT; nn++) {
                    float hv = hreg[nn][dd];
                    acc[nn][0] += hv * wv.x;
                    acc[nn][1] += hv * wv.y;
                    acc[nn][2] += hv * wv.z;
                    acc[nn][3] += hv * wv.w;
                }
            }
        }
    }
    int hh = (cbase + cg * 4) >> 5;
    #pragma unroll
    for (int nn = 0; nn < NPT; nn++) {
        int n = n0 + ng * NPT + nn;
        __half2 ha = __floats2half2_rn(acc[nn][0], acc[nn][1]);
        __half2 hb = __floats2half2_rn(acc[nn][2], acc[nn][3]);
        uint2 pk;
        pk.x = *(unsigned int*)&ha;
        pk.y = *(unsigned int*)&hb;
        *(uint2*)&x16[(size_t)n * 128 + cbase + cg * 4] = pk;
        float ps = acc[nn][0] * attS[cg * 4]     + acc[nn][1] * attS[cg * 4 + 1]
                 + acc[nn][2] * attS[cg * 4 + 2] + acc[nn][3] * attS[cg * 4 + 3];
        float pd = acc[nn][0] * attD[cg * 4]     + acc[nn][1] * attD[cg * 4 + 1]
                 + acc[nn][2] * attD[cg * 4 + 2] + acc[nn][3] * attD[cg * 4 + 3];
        ps += __shfl_xor(ps, 1, 64); pd += __shfl_xor(pd, 1, 64);
        ps += __shfl_xor(ps, 2, 64); pd += __shfl_xor(pd, 2, 64);
        ps += __shfl_xor(ps, 4, 64); pd += __shfl_xor(pd, 4, 64);
        if ((cg & 7) == 0) {
            asd[(size_t)n * 8 + hh] = ps;
            asd[(size_t)n * 8 + 4 + hh] = pd;
        }
    }
}

// ---------------------------------------------------------------------------
// K7: attention logits in CSR slot order; dist precomputed.
// ---------------------------------------------------------------------------
template <int LAYER>
__global__ __launch_bounds__(256) void k_alpha(
    const int2* __restrict__ e2, const float* __restrict__ dist,
    const int* __restrict__ wlim, const float* __restrict__ gamma,
    const float* __restrict__ U, const float* __restrict__ aeb,
    const float* __restrict__ asd, float* __restrict__ alpha)
{
    __shared__ float Us[128];
    __shared__ float aebs[4];
    int t = threadIdx.x;
    if (t < 128) Us[t] = U[t];
    if (t < 4) aebs[t] = aeb[t];
    __syncthreads();
    int i = blockIdx.x * 256 + t;
    if (i >= NE) return;
    if (LAYER == 2 && i < wlim[0]) return;
    int2 sd = e2[i];
    float dd = dist[i];
    float g = gamma[0];
    float ae0 = aebs[0], ae1 = aebs[1], ae2 = aebs[2], ae3 = aebs[3];
    const float step = 5.0f / 31.0f;
    #pragma unroll
    for (int k = 0; k < EDGE_K; k++) {
        float tt = dd - (float)k * step;
        float r = __expf(-g * tt * tt);
        ae0 += r * Us[k * 4 + 0];
        ae1 += r * Us[k * 4 + 1];
        ae2 += r * Us[k * 4 + 2];
        ae3 += r * Us[k * 4 + 3];
    }
    float4 as4 = *(const float4*)&asd[(size_t)sd.x * 8];
    float4 ad4 = *(const float4*)&asd[(size_t)sd.y * 8 + 4];
    float v0 = as4.x + ad4.x + ae0;
    float v1 = as4.y + ad4.y + ae1;
    float v2 = as4.z + ad4.z + ae2;
    float v3 = as4.w + ad4.w + ae3;
    v0 = v0 >= 0.f ? v0 : 0.2f * v0;
    v1 = v1 >= 0.f ? v1 : 0.2f * v1;
    v2 = v2 >= 0.f ? v2 : 0.2f * v2;
    v3 = v3 >= 0.f ? v3 : 0.2f * v3;
    *(float4*)&alpha[(size_t)i * 4] = make_float4(v0, v1, v2, v3);
}

// ---------------------------------------------------------------------------
// K8a v2: layer-1 softmax-aggregation of RAW h0 into z[N,4,32] fp16.
// Lean loop (round-7 shape): no LDS, low VGPR, unroll x4 (4 gathers in
// flight). z[n, h*32 + 2*k16 (+1)] lives at lane*2 — contiguous half2 store.
// W1 is applied later by k_z (dense GEMM) — un-fuses round 9's serial
// epilogue that killed memory-level parallelism.
// ---------------------------------------------------------------------------
__global__ __launch_bounds__(256) void k_aggz(
    const int* __restrict__ off, const int2* __restrict__ e2,
    const float* __restrict__ alpha, const __half* __restrict__ h016,
    __half* __restrict__ zbuf)
{
    int t = threadIdx.x;
    int w = t >> 6, lane = t & 63;
    int n = blockIdx.x * 4 + w;
    if (n >= NN) return;
    int h = lane >> 4, k16 = lane & 15;
    int beg = off[n], end = off[n + 1];
    const __half2* x2 = (const __half2*)h016;
    float lsum0 = 0.f, lsum1 = 0.f;
    float a00 = 0.f, a01 = 0.f, a10 = 0.f, a11 = 0.f;
    int i = beg;
    for (; i + 3 < end; i += 4) {
        int s0 = e2[i].x, s1 = e2[i + 1].x, s2 = e2[i + 2].x, s3 = e2[i + 3].x;
        float al0 = alpha[(unsigned)i * 4u + h];
        float al1 = alpha[(unsigned)(i + 1) * 4u + h];
        float al2 = alpha[(unsigned)(i + 2) * 4u + h];
        float al3 = alpha[(unsigned)(i + 3) * 4u + h];
        float2 xv0 = __half22float2(x2[(unsigned)s0 * 16u + k16]);
        float2 xv1 = __half22float2(x2[(unsigned)s1 * 16u + k16]);
        float2 xv2 = __half22float2(x2[(unsigned)s2 * 16u + k16]);
        float2 xv3 = __half22float2(x2[(unsigned)s3 * 16u + k16]);
        float e0 = __expf(al0), e1 = __expf(al1);
        float e2v = __expf(al2), e3 = __expf(al3);
        lsum0 += e0 + e2v; lsum1 += e1 + e3;
        a00 += e0 * xv0.x + e2v * xv2.x;
        a01 += e0 * xv0.y + e2v * xv2.y;
        a10 += e1 * xv1.x + e3 * xv3.x;
        a11 += e1 * xv1.y + e3 * xv3.y;
    }
    for (; i < end; i++) {
        int s0 = e2[i].x;
        float al0 = alpha[(unsigned)i * 4u + h];
        float2 xv0 = __half22float2(x2[(unsigned)s0 * 16u + k16]);
        float e0 = __expf(al0);
        lsum0 += e0;
        a00 += e0 * xv0.x; a01 += e0 * xv0.y;
    }
    float inv = 1.0f / (lsum0 + lsum1 + 1e-16f);
    *(__half2*)&zbuf[(size_t)n * 128 + lane * 2] =
        __floats2half2_rn((a00 + a10) * inv, (a01 + a11) * inv);
}

// ---------------------------------------------------------------------------
// K8a2 (k_z): hbuf = elu(z @blockdiag(W1) + b1). z[n,h,c]; out col j (head
// h=j>>5) = sum_c z[n,h,c]*W1[c,j]. 64-node tile; thread = 8 nodes x 4 cols;
// per-head LDS offset h*40 puts the 4 head-slices on disjoint bank groups.
// ---------------------------------------------------------------------------
__global__ __launch_bounds__(256) void k_z(
    const __half* __restrict__ zbuf, const float* __restrict__ W1g,
    const float* __restrict__ b1, __half* __restrict__ hbuf)
{
    constexpr int ZSTR = 152;          // 4 heads x 40 (=133 used), mod-32 safe
    __shared__ float Ws[32 * 128];
    __shared__ float hs[64 * ZSTR];
    int t = threadIdx.x;
    int n0 = blockIdx.x * 64;
    for (int i8 = t * 8; i8 < 64 * 128; i8 += 2048) {
        int r = i8 >> 7, c = i8 & 127;
        int hh = c >> 5, cc = c & 31;
        uint4 raw = *(const uint4*)&zbuf[(size_t)(n0 + r) * 128 + c];
        const __half2* hp = (const __half2*)&raw;
        float2 f0 = __half22float2(hp[0]);
        float2 f1 = __half22float2(hp[1]);
        float2 f2 = __half22float2(hp[2]);
        float2 f3 = __half22float2(hp[3]);
        float* dst = &hs[r * ZSTR + hh * 40 + cc];
        *(float4*)dst       = make_float4(f0.x, f0.y, f1.x, f1.y);
        *(float4*)(dst + 4) = make_float4(f2.x, f2.y, f3.x, f3.y);
    }
    for (int i = t; i < 32 * 128; i += 256) Ws[i] = W1g[i];
    __syncthreads();
    int cg = t & 31, ng = t >> 5;      // 32 col-groups x 8 node-groups
    int h = cg >> 3, c0 = cg * 4;
    float4 bb = *(const float4*)&b1[c0];
    float acc[8][4];
    #pragma unroll
    for (int nn = 0; nn < 8; nn++)
        #pragma unroll
        for (int j = 0; j < 4; j++) acc[nn][j] = 0.f;
    for (int d0 = 0; d0 < 32; d0 += 4) {
        float hreg[8][4];
        #pragma unroll
        for (int nn = 0; nn < 8; nn++) {
            float4 hv = *(const float4*)&hs[(ng * 8 + nn) * ZSTR + h * 40 + d0];
            hreg[nn][0] = hv.x; hreg[nn][1] = hv.y;
            hreg[nn][2] = hv.z; hreg[nn][3] = hv.w;
        }
        #pragma unroll
        for (int dd = 0; dd < 4; dd++) {
            float4 wv = *(const float4*)&Ws[(d0 + dd) * 128 + c0];
            #pragma unroll
            for (int nn = 0; nn < 8; nn++) {
                float hv = hreg[nn][dd];
                acc[nn][0] += hv * wv.x;
                acc[nn][1] += hv * wv.y;
                acc[nn][2] += hv * wv.z;
                acc[nn][3] += hv * wv.w;
            }
        }
    }
    #pragma unroll
    for (int nn = 0; nn < 8; nn++) {
        int n = n0 + ng * 8 + nn;
        float r0 = acc[nn][0] + bb.x;
        float r1 = acc[nn][1] + bb.y;
        float r2 = acc[nn][2] + bb.z;
        float r3 = acc[nn][3] + bb.w;
        r0 = r0 > 0.f ? r0 : __expf(r0) - 1.0f;
        r1 = r1 > 0.f ? r1 : __expf(r1) - 1.0f;
        r2 = r2 > 0.f ? r2 : __expf(r2) - 1.0f;
        r3 = r3 > 0.f ? r3 : __expf(r3) - 1.0f;
        __half2 ha = __floats2half2_rn(r0, r1);
        __half2 hb = __floats2half2_rn(r2, r3);
        uint2 pk;
        pk.x = *(unsigned int*)&ha;
        pk.y = *(unsigned int*)&hb;
        *(uint2*)&hbuf[(size_t)n * 128 + c0] = pk;
    }
}

// ---------------------------------------------------------------------------
// K8b: layer-2 aggregation over pre-GEMMed x16 (water dst only), unroll x4.
// ---------------------------------------------------------------------------
__global__ __launch_bounds__(256) void k_agg2(
    const int* __restrict__ off, const int2* __restrict__ e2,
    const float* __restrict__ alpha, const __half* __restrict__ x16,
    const float* __restrict__ bias, __half* __restrict__ hout)
{
    int t = threadIdx.x;
    int w = t >> 6, lane = t & 63;
    int n = N_PRO + blockIdx.x * 4 + w;
    if (n >= NN) return;
    int h = lane >> 4;
    int beg = off[n], end = off[n + 1];
    float lsum0 = 0.f, lsum1 = 0.f;
    float a00 = 0.f, a01 = 0.f, a10 = 0.f, a11 = 0.f;
    const __half2* x2 = (const __half2*)x16;
    int i = beg;
    for (; i + 3 < end; i += 4) {
        int s0 = e2[i].x, s1 = e2[i + 1].x, s2 = e2[i + 2].x, s3 = e2[i + 3].x;
        float al0 = alpha[(unsigned)i * 4u + h];
        float al1 = alpha[(unsigned)(i + 1) * 4u + h];
        float al2 = alpha[(unsigned)(i + 2) * 4u + h];
        float al3 = alpha[(unsigned)(i + 3) * 4u + h];
        float2 xv0 = __half22float2(x2[(unsigned)s0 * 64u + lane]);
        float2 xv1 = __half22float2(x2[(unsigned)s1 * 64u + lane]);
        float2 xv2 = __half22float2(x2[(unsigned)s2 * 64u + lane]);
        float2 xv3 = __half22float2(x2[(unsigned)s3 * 64u + lane]);
        float e0 = __expf(al0), e1 = __expf(al1);
        float e2v = __expf(al2), e3 = __expf(al3);
        lsum0 += e0 + e2v; lsum1 += e1 + e3;
        a00 += e0 * xv0.x + e2v * xv2.x;
        a01 += e0 * xv0.y + e2v * xv2.y;
        a10 += e1 * xv1.x + e3 * xv3.x;
        a11 += e1 * xv1.y + e3 * xv3.y;
    }
    for (; i < end; i++) {
        int s0 = e2[i].x;
        float al0 = alpha[(unsigned)i * 4u + h];
        float2 xv0 = __half22float2(x2[(unsigned)s0 * 64u + lane]);
        float e0 = __expf(al0);
        lsum0 += e0;
        a00 += e0 * xv0.x; a01 += e0 * xv0.y;
    }
    float lsum = lsum0 + lsum1;
    float acc0 = a00 + a10, acc1 = a01 + a11;
    float inv = 1.0f / (lsum + 1e-16f);
    float2 bbv = *(const float2*)&bias[lane * 2];
    float o0 = acc0 * inv + bbv.x;
    float o1 = acc1 * inv + bbv.y;
    o0 = o0 > 0.f ? o0 : __expf(o0) - 1.0f;
    o1 = o1 > 0.f ? o1 : __expf(o1) - 1.0f;
    *(__half2*)&hout[(size_t)n * 128 + lane * 2] = __floats2half2_rn(o0, o1);
}

// ---------------------------------------------------------------------------
// K9: water MLP. 32-node tile/block, padded stride 132, register-blocked.
// ---------------------------------------------------------------------------
__global__ __launch_bounds__(256) void k_mlp(
    const __half* __restrict__ hh, const float* __restrict__ Wm1,
    const float* __restrict__ bm1, const float* __restrict__ Wm2,
    const float* __restrict__ bm2, float* __restrict__ out)
{
    __shared__ float W1s[128 * 64];
    __shared__ float hs[32 * 132];
    int t = threadIdx.x;
    int g = t >> 5, q = t & 31;
    float b1r[2][2], w2r[2][2][2];
    #pragma unroll
    for (int hf = 0; hf < 2; hf++)
        #pragma unroll
        for (int j = 0; j < 2; j++) {
            int c = hf * 64 + q * 2 + j;
            b1r[hf][j] = bm1[c];
            w2r[hf][j][0] = Wm2[c * 2 + 0];
            w2r[hf][j][1] = Wm2[c * 2 + 1];
        }
    float b20 = bm2[0], b21 = bm2[1];
    int tile = blockIdx.x;
    {
        int r = t >> 3, c0 = (t & 7) * 16;
        const __half* src = &hh[(size_t)(N_PRO + tile * 32 + r) * 128 + c0];
        uint4 raw0 = *(const uint4*)src;
        uint4 raw1 = *(const uint4*)(src + 8);
        const __half2* hp0 = (const __half2*)&raw0;
        const __half2* hp1 = (const __half2*)&raw1;
        #pragma unroll
        for (int j = 0; j < 4; j++) {
            float2 fa = __half22float2(j < 2 ? hp0[2 * j] : hp1[2 * (j - 2)]);
            float2 fb = __half22float2(j < 2 ? hp0[2 * j + 1] : hp1[2 * (j - 2) + 1]);
            *(float4*)&hs[r * 132 + c0 + 4 * j] = make_float4(fa.x, fa.y, fb.x, fb.y);
        }
    }
    float p0[4] = {0.f, 0.f, 0.f, 0.f}, p1[4] = {0.f, 0.f, 0.f, 0.f};
    #pragma unroll
    for (int hf = 0; hf < 2; hf++) {
        __syncthreads();
        for (int i = t; i < 128 * 64; i += 256)
            W1s[i] = Wm1[(size_t)(i >> 6) * 128 + hf * 64 + (i & 63)];
        __syncthreads();
        float a[4][2];
        #pragma unroll
        for (int i = 0; i < 4; i++) { a[i][0] = 0.f; a[i][1] = 0.f; }
        for (int d0 = 0; d0 < 128; d0 += 4) {
            float4 hv[4];
            #pragma unroll
            for (int i = 0; i < 4; i++)
                hv[i] = *(const float4*)&hs[(g + 8 * i) * 132 + d0];
            #pragma unroll
            for (int dd = 0; dd < 4; dd++) {
                float2 wv = *(const float2*)&W1s[(d0 + dd) * 64 + q * 2];
                #pragma unroll
                for (int i = 0; i < 4; i++) {
                    float hvv = (&hv[i].x)[dd];
                    a[i][0] += hvv * wv.x;
                    a[i][1] += hvv * wv.y;
                }
            }
        }
        #pragma unroll
        for (int i = 0; i < 4; i++) {
            float a0 = fmaxf(a[i][0] + b1r[hf][0], 0.f);
            float a1 = fmaxf(a[i][1] + b1r[hf][1], 0.f);
            p0[i] += a0 * w2r[hf][0][0] + a1 * w2r[hf][1][0];
            p1[i] += a0 * w2r[hf][0][1] + a1 * w2r[hf][1][1];
        }
    }
    #pragma unroll
    for (int m = 1; m < 32; m <<= 1) {
        #pragma unroll
        for (int i = 0; i < 4; i++) {
            p0[i] += __shfl_xor(p0[i], m, 64);
            p1[i] += __shfl_xor(p1[i], m, 64);
        }
    }
    if (q == 0) {
        #pragma unroll
        for (int i = 0; i < 4; i++) {
            int n = tile * 32 + g + 8 * i;
            *(float2*)&out[n * 2] = make_float2(p0[i] + b20, p1[i] + b21);
        }
    }
}

// ---------------------------------------------------------------------------
extern "C" void kernel_launch(void* const* d_in, const int* in_sizes, int n_in,
                              void* d_out, int out_size, void* d_ws, size_t ws_size,
                              hipStream_t stream)
{
    const float* ppos   = (const float*)d_in[0];
    const float* wpos   = (const float*)d_in[1];
    const float* pfeat  = (const float*)d_in[2];
    const int*   ei     = (const int*)d_in[3];
    const float* gamma  = (const float*)d_in[4];
    const float* Wf     = (const float*)d_in[5];
    const float* bfv    = (const float*)d_in[6];
    const float* We     = (const float*)d_in[7];
    const float* be     = (const float*)d_in[8];
    const float* W1     = (const float*)d_in[9];
    const float* atts1  = (const float*)d_in[10];
    const float* attd1  = (const float*)d_in[11];
    const float* Wedge1 = (const float*)d_in[12];
    const float* atte1  = (const float*)d_in[13];
    const float* b1     = (const float*)d_in[14];
    const float* W2     = (const float*)d_in[15];
    const float* atts2  = (const float*)d_in[16];
    const float* attd2  = (const float*)d_in[17];
    const float* Wedge2 = (const float*)d_in[18];
    const float* atte2  = (const float*)d_in[19];
    const float* b2     = (const float*)d_in[20];
    const float* Wm1    = (const float*)d_in[21];
    const float* bm1    = (const float*)d_in[22];
    const float* Wm2    = (const float*)d_in[23];
    const float* bm2    = (const float*)d_in[24];
    float* out = (float*)d_out;

    char* ws = (char*)d_ws;
    size_t o = 0;
    auto alloc = [&](size_t bytes) -> char* {
        char* p = ws + o;
        o += (bytes + 255) & ~(size_t)255;
        return p;
    };
    __half* h0      = (__half*)alloc((size_t)NNP * 32 * 2);
    __half* x16     = (__half*)alloc((size_t)NNP * 128 * 2);   // also zbuf
    __half* hbuf    = (__half*)alloc((size_t)NNP * 128 * 2);
    float*  asd     = (float*)alloc((size_t)NNP * 8 * 4);
    float*  alpha   = (float*)alloc((size_t)NE * 4 * 4);
    int*    deg     = (int*)alloc((size_t)(NN + 1) * 4);
    int*    offp    = (int*)alloc((size_t)(NN + 1) * 4);
    int*    cur     = (int*)alloc((size_t)NN * 4);
    int2*   e2      = (int2*)alloc((size_t)NE * 8);
    float*  dist    = (float*)alloc((size_t)NE * 4);
    int*    part    = (int*)alloc((size_t)NSEG * 4);
    int*    partoff = (int*)alloc((size_t)(128 + 1) * 4);
    float*  smallw  = (float*)alloc(4096);

    hipMemsetAsync(deg, 0, (NN + 1) * 4, stream);
    k_small<<<1, 256, 0, stream>>>(We, be, Wedge1, atte1, Wedge2, atte2, Wf, bfv,
                                   W1, atts1, attd1, smallw);
    k_h0<<<(NNP * 32) / 256, 256, 0, stream>>>(pfeat, Wf, bfv, smallw, h0, asd);
    k_count<<<(NE + 255) / 256, 256, 0, stream>>>(ei, deg);
    k_scan1<<<NSEG, 256, 0, stream>>>(deg, offp, cur, part);
    k_scan2<<<1, 128, 0, stream>>>(part, partoff, offp);
    k_scan3<<<NSEG, 256, 0, stream>>>(partoff, offp, cur);
    k_fill<<<(NE + 255) / 256, 256, 0, stream>>>(ei, cur, e2, dist, ppos, wpos);
    // layer 1: lean aggregation of raw h0 -> z (in x16 buffer), then dense
    // block-diag W1 GEMM + ELU
    k_alpha<1><<<(NE + 255) / 256, 256, 0, stream>>>(e2, dist, offp + N_PRO, gamma, smallw + 0, smallw + 128, asd, alpha);
    k_aggz<<<NN / 4, 256, 0, stream>>>(offp, e2, alpha, h0, x16);
    k_z<<<NNP / 64, 256, 0, stream>>>(x16, W1, b1, hbuf);
    // layer 2 (water destinations only)
    k_x<128, 64><<<dim3(NNP / 64, 2), 256, 0, stream>>>(hbuf, W2, atts2, attd2, x16, asd);
    k_alpha<2><<<(NE + 255) / 256, 256, 0, stream>>>(e2, dist, offp + N_PRO, gamma, smallw + 132, smallw + 260, asd, alpha);
    k_agg2<<<N_WAT / 4, 256, 0, stream>>>(offp, e2, alpha, x16, b2, hbuf);
    // MLP on water nodes
    k_mlp<<<N_WAT / 32, 256, 0, stream>>>(hbuf, Wm1, bm1, Wm2, bm2, out);
}